// Round 1
// baseline (2044.016 us; speedup 1.0000x reference)
//
#include <hip/hip_runtime.h>
#include <math.h>

#define N_NODES 50000
#define N_EDGES 400000
#define E_TOT   (N_EDGES + N_NODES)
#define NPB_RED 512

__device__ __forceinline__ float lrelu02(float x) { return x > 0.f ? x : 0.2f * x; }

// ---------------- GAT layer 1: per-node linear + attention features ----------------
__global__ void k_node1(const float* __restrict__ x, const float* __restrict__ W1,
                        const float* __restrict__ attS, const float* __restrict__ attD,
                        float* __restrict__ h1, float* __restrict__ as1, float* __restrict__ ad1) {
  __shared__ float sW[64 * 13];
  __shared__ float sAs[64], sAd[64];
  int t = threadIdx.x;
  for (int i = t; i < 64 * 13; i += blockDim.x) sW[i] = W1[i];
  if (t < 64) { sAs[t] = attS[t]; sAd[t] = attD[t]; }
  __syncthreads();
  int n = blockIdx.x * blockDim.x + t;
  if (n >= N_NODES) return;
  float xr[13];
#pragma unroll
  for (int c = 0; c < 13; c++) xr[c] = x[n * 13 + c];
  float hv[64];
#pragma unroll
  for (int o = 0; o < 64; o++) {
    float acc = 0.f;
#pragma unroll
    for (int c = 0; c < 13; c++) acc = fmaf(xr[c], sW[o * 13 + c], acc);
    hv[o] = acc;
    h1[n * 64 + o] = acc;
  }
#pragma unroll
  for (int hh = 0; hh < 8; hh++) {
    float s = 0.f, d = 0.f;
#pragma unroll
    for (int c = 0; c < 8; c++) {
      s = fmaf(hv[hh * 8 + c], sAs[hh * 8 + c], s);
      d = fmaf(hv[hh * 8 + c], sAd[hh * 8 + c], d);
    }
    as1[n * 8 + hh] = s;
    ad1[n * 8 + hh] = d;
  }
}

// ---------------- GAT layer 1: edge pass (wave per edge, lane = channel) ----------------
__global__ void k_edge1(const int* __restrict__ srcA, const int* __restrict__ dstA,
                        const float* __restrict__ h1, const float* __restrict__ as1,
                        const float* __restrict__ ad1,
                        float* __restrict__ out1, float* __restrict__ den1) {
  int gid = blockIdx.x * blockDim.x + threadIdx.x;
  int e = gid >> 6, l = gid & 63;
  if (e >= E_TOT) return;
  int src, dst;
  if (e < N_EDGES) { src = srcA[e]; dst = dstA[e]; } else { src = dst = e - N_EDGES; }
  int h = l >> 3;
  float ex = expf(lrelu02(as1[src * 8 + h] + ad1[dst * 8 + h]));
  atomicAdd(&out1[dst * 64 + l], ex * h1[src * 64 + l]);
  if (l < 8) {
    float ex2 = expf(lrelu02(as1[src * 8 + l] + ad1[dst * 8 + l]));
    atomicAdd(&den1[dst * 8 + l], ex2);
  }
}

// ---------------- normalize + bias + ELU + GAT2 linear + attention features ----------------
__global__ void __launch_bounds__(256)
k_node2(const float* __restrict__ out1, const float* __restrict__ den1,
        const float* __restrict__ b1, const float* __restrict__ W2,
        const float* __restrict__ attS2, const float* __restrict__ attD2,
        float* __restrict__ g, float* __restrict__ as2, float* __restrict__ ad2) {
  __shared__ float sW[64 * 64];
  __shared__ float sA[64], sD[64], sB[64];
  int t = threadIdx.x;
  for (int i = t; i < 64 * 64; i += blockDim.x) sW[i] = W2[i];
  if (t < 64) { sA[t] = attS2[t]; sD[t] = attD2[t]; sB[t] = b1[t]; }
  __syncthreads();
  int n = blockIdx.x * blockDim.x + t;
  if (n >= N_NODES) return;
  float h2[64];
#pragma unroll
  for (int c = 0; c < 64; c++) {
    float v = out1[n * 64 + c] / den1[n * 8 + (c >> 3)] + sB[c];
    h2[c] = v > 0.f ? v : expm1f(v);
  }
  float s2 = 0.f, d2 = 0.f;
  for (int o = 0; o < 64; o++) {
    float acc = 0.f;
#pragma unroll
    for (int c = 0; c < 64; c++) acc = fmaf(h2[c], sW[o * 64 + c], acc);
    g[n * 64 + o] = acc;
    s2 = fmaf(acc, sA[o], s2);
    d2 = fmaf(acc, sD[o], d2);
  }
  as2[n] = s2;
  ad2[n] = d2;
}

// ---------------- GAT layer 2: edge pass (wave per edge, lane = channel) ----------------
__global__ void k_edge2(const int* __restrict__ srcA, const int* __restrict__ dstA,
                        const float* __restrict__ g, const float* __restrict__ as2,
                        const float* __restrict__ ad2,
                        float* __restrict__ out2, float* __restrict__ den2) {
  int gid = blockIdx.x * blockDim.x + threadIdx.x;
  int e = gid >> 6, l = gid & 63;
  if (e >= E_TOT) return;
  int src, dst;
  if (e < N_EDGES) { src = srcA[e]; dst = dstA[e]; } else { src = dst = e - N_EDGES; }
  float ex = expf(lrelu02(as2[src] + ad2[dst]));
  atomicAdd(&out2[dst * 64 + l], ex * g[src * 64 + l]);
  if (l == 0) atomicAdd(&den2[dst], ex);
}

// ---------------- per-frame mean over nodes ----------------
__global__ void k_reduce(const float* __restrict__ out2, const float* __restrict__ den2,
                         float* __restrict__ emb) {
  __shared__ float part[4][64];
  int c = threadIdx.x & 63, r = threadIdx.x >> 6;
  int start = blockIdx.x * NPB_RED;
  int end = start + NPB_RED;
  if (end > N_NODES) end = N_NODES;
  float acc = 0.f;
  for (int n = start + r; n < end; n += 4) acc += out2[n * 64 + c] / den2[n];
  part[r][c] = acc;
  __syncthreads();
  if (r == 0)
    atomicAdd(&emb[c], (part[0][c] + part[1][c] + part[2][c] + part[3][c]) * (1.0f / N_NODES));
}

// ---------------- tiny transformer (1,5,64) ×3 layers + head, single block ----------------
__global__ void k_transformer(const float* __restrict__ emb, const float* __restrict__ b2,
                              const float* __restrict__ Wqkv, const float* __restrict__ bqkv,
                              const float* __restrict__ Wo, const float* __restrict__ bo,
                              const float* __restrict__ ln1w, const float* __restrict__ ln1b,
                              const float* __restrict__ Wff1, const float* __restrict__ bff1,
                              const float* __restrict__ Wff2, const float* __restrict__ bff2,
                              const float* __restrict__ ln2w, const float* __restrict__ ln2b,
                              const float* __restrict__ Wh1, const float* __restrict__ bh1,
                              const float* __restrict__ Wh2, const float* __restrict__ bh2,
                              float* __restrict__ out) {
  __shared__ float seq[5][64];
  __shared__ float qkv[5][192];
  __shared__ float att[4][5][5];
  __shared__ float ob[5][64];
  __shared__ float ffb[5][128];
  __shared__ float tmp[5][64];
  __shared__ float mv[5][2];
  __shared__ float hid[32];
  int t = threadIdx.x;
  for (int i = t; i < 320; i += 256) seq[i >> 6][i & 63] = emb[i] + b2[i & 63];
  __syncthreads();
  for (int l = 0; l < 3; l++) {
    const float* Wq = Wqkv + l * 192 * 64; const float* bq = bqkv + l * 192;
    const float* Wol = Wo + l * 64 * 64;   const float* bol = bo + l * 64;
    const float* w1 = ln1w + l * 64;       const float* bb1 = ln1b + l * 64;
    const float* Wf1 = Wff1 + l * 128 * 64; const float* bf1 = bff1 + l * 128;
    const float* Wf2 = Wff2 + l * 64 * 128; const float* bf2 = bff2 + l * 64;
    const float* w2 = ln2w + l * 64;       const float* bb2 = ln2b + l * 64;

    for (int i = t; i < 960; i += 256) {
      int s = i / 192, j = i % 192;
      float acc = bq[j];
      for (int c = 0; c < 64; c++) acc = fmaf(seq[s][c], Wq[j * 64 + c], acc);
      qkv[s][j] = acc;
    }
    __syncthreads();
    if (t < 100) {
      int hh = t / 25, qs = (t / 5) % 5, ks = t % 5;
      float acc = 0.f;
      for (int d = 0; d < 16; d++) acc = fmaf(qkv[qs][hh * 16 + d], qkv[ks][64 + hh * 16 + d], acc);
      att[hh][qs][ks] = acc * 0.25f;
    }
    __syncthreads();
    if (t < 20) {
      int hh = t / 5, qs = t % 5;
      float m = att[hh][qs][0];
      for (int k2 = 1; k2 < 5; k2++) m = fmaxf(m, att[hh][qs][k2]);
      float ss = 0.f;
      for (int k2 = 0; k2 < 5; k2++) { float v = expf(att[hh][qs][k2] - m); att[hh][qs][k2] = v; ss += v; }
      float inv = 1.f / ss;
      for (int k2 = 0; k2 < 5; k2++) att[hh][qs][k2] *= inv;
    }
    __syncthreads();
    for (int i = t; i < 320; i += 256) {
      int s = i >> 6, j = i & 63, hh = j >> 4;
      float acc = 0.f;
      for (int k2 = 0; k2 < 5; k2++) acc = fmaf(att[hh][s][k2], qkv[k2][128 + j], acc);
      ob[s][j] = acc;
    }
    __syncthreads();
    for (int i = t; i < 320; i += 256) {
      int s = i >> 6, c = i & 63;
      float acc = bol[c];
      for (int j = 0; j < 64; j++) acc = fmaf(ob[s][j], Wol[c * 64 + j], acc);
      tmp[s][c] = seq[s][c] + acc;
    }
    __syncthreads();
    if (t < 5) {
      float m = 0.f;
      for (int c = 0; c < 64; c++) m += tmp[t][c];
      m *= (1.f / 64.f);
      float v = 0.f;
      for (int c = 0; c < 64; c++) { float d = tmp[t][c] - m; v = fmaf(d, d, v); }
      v *= (1.f / 64.f);
      mv[t][0] = m; mv[t][1] = 1.f / sqrtf(v + 1e-5f);
    }
    __syncthreads();
    for (int i = t; i < 320; i += 256) {
      int s = i >> 6, c = i & 63;
      seq[s][c] = (tmp[s][c] - mv[s][0]) * mv[s][1] * w1[c] + bb1[c];
    }
    __syncthreads();
    for (int i = t; i < 640; i += 256) {
      int s = i / 128, j = i % 128;
      float acc = bf1[j];
      for (int c = 0; c < 64; c++) acc = fmaf(seq[s][c], Wf1[j * 64 + c], acc);
      ffb[s][j] = fmaxf(acc, 0.f);
    }
    __syncthreads();
    for (int i = t; i < 320; i += 256) {
      int s = i >> 6, c = i & 63;
      float acc = bf2[c];
      for (int j = 0; j < 128; j++) acc = fmaf(ffb[s][j], Wf2[c * 128 + j], acc);
      tmp[s][c] = seq[s][c] + acc;
    }
    __syncthreads();
    if (t < 5) {
      float m = 0.f;
      for (int c = 0; c < 64; c++) m += tmp[t][c];
      m *= (1.f / 64.f);
      float v = 0.f;
      for (int c = 0; c < 64; c++) { float d = tmp[t][c] - m; v = fmaf(d, d, v); }
      v *= (1.f / 64.f);
      mv[t][0] = m; mv[t][1] = 1.f / sqrtf(v + 1e-5f);
    }
    __syncthreads();
    for (int i = t; i < 320; i += 256) {
      int s = i >> 6, c = i & 63;
      seq[s][c] = (tmp[s][c] - mv[s][0]) * mv[s][1] * w2[c] + bb2[c];
    }
    __syncthreads();
  }
  if (t < 32) {
    float acc = bh1[t];
    for (int c = 0; c < 64; c++) acc = fmaf(seq[4][c], Wh1[t * 64 + c], acc);
    hid[t] = fmaxf(acc, 0.f);
  }
  __syncthreads();
  if (t < 2) {
    float acc = bh2[t];
    for (int j = 0; j < 32; j++) acc = fmaf(hid[j], Wh2[t * 32 + j], acc);
    out[t] = acc;
  }
}

extern "C" void kernel_launch(void* const* d_in, const int* in_sizes, int n_in,
                              void* d_out, int out_size, void* d_ws, size_t ws_size,
                              hipStream_t stream) {
  const float* x     = (const float*)d_in[0];
  const int*   ei    = (const int*)d_in[1];
  const float* W1    = (const float*)d_in[2];
  const float* attS1 = (const float*)d_in[3];
  const float* attD1 = (const float*)d_in[4];
  const float* b1    = (const float*)d_in[5];
  const float* W2    = (const float*)d_in[6];
  const float* attS2 = (const float*)d_in[7];
  const float* attD2 = (const float*)d_in[8];
  const float* b2    = (const float*)d_in[9];
  const float* tWqkv = (const float*)d_in[10];
  const float* tbqkv = (const float*)d_in[11];
  const float* tWo   = (const float*)d_in[12];
  const float* tbo   = (const float*)d_in[13];
  const float* tln1w = (const float*)d_in[14];
  const float* tln1b = (const float*)d_in[15];
  const float* tWff1 = (const float*)d_in[16];
  const float* tbff1 = (const float*)d_in[17];
  const float* tWff2 = (const float*)d_in[18];
  const float* tbff2 = (const float*)d_in[19];
  const float* tln2w = (const float*)d_in[20];
  const float* tln2b = (const float*)d_in[21];
  const float* Wh1   = (const float*)d_in[22];
  const float* bh1   = (const float*)d_in[23];
  const float* Wh2   = (const float*)d_in[24];
  const float* bh2   = (const float*)d_in[25];
  float* out = (float*)d_out;

  float* ws  = (float*)d_ws;
  float* h1g = ws;                 // 3,200,000 floats: h1 (GAT1) then g (GAT2)
  float* as1 = h1g + 3200000;      // 400,000
  float* ad1 = as1 + 400000;       // 400,000
  float* den = ad1 + 400000;       // 400,000 (den1; reused as den2)
  float* acc = den + 400000;       // 3,200,000 (out1; reused as out2)
  float* as2 = acc + 3200000;      // 50,000
  float* ad2 = as2 + 50000;        // 50,000
  float* emb = ad2 + 50000;        // 320

  (void)hipMemsetAsync(emb, 0, 320 * sizeof(float), stream);

  const int nodeBlocks = (N_NODES + 255) / 256;
  const int edgeBlocks = (E_TOT * 64 + 255) / 256;

  for (int f = 0; f < 5; f++) {
    const float* xf  = x + (size_t)f * N_NODES * 13;
    const int* srcA  = ei + (size_t)f * 2 * N_EDGES;
    const int* dstA  = srcA + N_EDGES;

    k_node1<<<nodeBlocks, 256, 0, stream>>>(xf, W1, attS1, attD1, h1g, as1, ad1);
    (void)hipMemsetAsync(den, 0, 400000 * sizeof(float), stream);
    (void)hipMemsetAsync(acc, 0, 3200000 * sizeof(float), stream);
    k_edge1<<<edgeBlocks, 256, 0, stream>>>(srcA, dstA, h1g, as1, ad1, acc, den);
    k_node2<<<nodeBlocks, 256, 0, stream>>>(acc, den, b1, W2, attS2, attD2, h1g, as2, ad2);
    (void)hipMemsetAsync(den, 0, N_NODES * sizeof(float), stream);
    (void)hipMemsetAsync(acc, 0, 3200000 * sizeof(float), stream);
    k_edge2<<<edgeBlocks, 256, 0, stream>>>(srcA, dstA, h1g, as2, ad2, acc, den);
    k_reduce<<<(N_NODES + NPB_RED - 1) / NPB_RED, 256, 0, stream>>>(acc, den, emb + f * 64);
  }

  k_transformer<<<1, 256, 0, stream>>>(emb, b2, tWqkv, tbqkv, tWo, tbo, tln1w, tln1b,
                                       tWff1, tbff1, tWff2, tbff2, tln2w, tln2b,
                                       Wh1, bh1, Wh2, bh2, out);
}

// Round 2
// 1396.142 us; speedup vs baseline: 1.4640x; 1.4640x over previous
//
#include <hip/hip_runtime.h>
#include <math.h>

#define N_NODES 50000
#define N_EDGES 400000
#define NPB_RED 512
#define NB_NODE ((N_NODES + 255) / 256)   // 196 blocks of 256 over nodes

__device__ __forceinline__ float lrelu02(float x) { return x > 0.f ? x : 0.2f * x; }

// ---------------- GAT layer 1: per-node linear + attention features ----------------
__global__ void k_node1(const float* __restrict__ x, const float* __restrict__ W1,
                        const float* __restrict__ attS, const float* __restrict__ attD,
                        float* __restrict__ h1, float* __restrict__ as1, float* __restrict__ ad1) {
  __shared__ float sW[64 * 13];
  __shared__ float sAs[64], sAd[64];
  int t = threadIdx.x;
  for (int i = t; i < 64 * 13; i += blockDim.x) sW[i] = W1[i];
  if (t < 64) { sAs[t] = attS[t]; sAd[t] = attD[t]; }
  __syncthreads();
  int n = blockIdx.x * blockDim.x + t;
  if (n >= N_NODES) return;
  float xr[13];
#pragma unroll
  for (int c = 0; c < 13; c++) xr[c] = x[n * 13 + c];
  float hv[64];
#pragma unroll
  for (int o = 0; o < 64; o++) {
    float acc = 0.f;
#pragma unroll
    for (int c = 0; c < 13; c++) acc = fmaf(xr[c], sW[o * 13 + c], acc);
    hv[o] = acc;
    h1[n * 64 + o] = acc;
  }
#pragma unroll
  for (int hh = 0; hh < 8; hh++) {
    float s = 0.f, d = 0.f;
#pragma unroll
    for (int c = 0; c < 8; c++) {
      s = fmaf(hv[hh * 8 + c], sAs[hh * 8 + c], s);
      d = fmaf(hv[hh * 8 + c], sAd[hh * 8 + c], d);
    }
    as1[n * 8 + hh] = s;
    ad1[n * 8 + hh] = d;
  }
}

// ---------------- CSR build: histogram of real edges by dst ----------------
__global__ void k_hist(const int* __restrict__ dstA, int* __restrict__ deg) {
  int e = blockIdx.x * blockDim.x + threadIdx.x;
  if (e < N_EDGES) atomicAdd(&deg[dstA[e]], 1);
}

// ---------------- CSR build: per-block sums ----------------
__global__ void k_scan1(const int* __restrict__ deg, int* __restrict__ bsum) {
  __shared__ int part[256];
  int t = threadIdx.x;
  int i = blockIdx.x * 256 + t;
  part[t] = (i < N_NODES) ? deg[i] : 0;
  __syncthreads();
  for (int off = 128; off > 0; off >>= 1) {
    if (t < off) part[t] += part[t + off];
    __syncthreads();
  }
  if (t == 0) bsum[blockIdx.x] = part[0];
}

// ---------------- CSR build: scan of block sums (single block) ----------------
__global__ void k_scan2(const int* __restrict__ bsum, int* __restrict__ boff) {
  __shared__ int part[256];
  int t = threadIdx.x;
  part[t] = (t < NB_NODE) ? bsum[t] : 0;
  __syncthreads();
  for (int off = 1; off < 256; off <<= 1) {
    int v = (t >= off) ? part[t - off] : 0;
    __syncthreads();
    part[t] += v;
    __syncthreads();
  }
  if (t < NB_NODE) boff[t] = part[t] - bsum[t];  // exclusive
}

// ---------------- CSR build: intra-block scan -> rowptr & cursor ----------------
__global__ void k_scan3(const int* __restrict__ deg, const int* __restrict__ boff,
                        int* __restrict__ rowptr, int* __restrict__ cur) {
  __shared__ int part[256];
  int t = threadIdx.x;
  int i = blockIdx.x * 256 + t;
  int d = (i < N_NODES) ? deg[i] : 0;
  part[t] = d;
  __syncthreads();
  for (int off = 1; off < 256; off <<= 1) {
    int v = (t >= off) ? part[t - off] : 0;
    __syncthreads();
    part[t] += v;
    __syncthreads();
  }
  if (i < N_NODES) {
    int r = boff[blockIdx.x] + part[t] - d;  // exclusive prefix
    rowptr[i] = r;
    cur[i] = r;
  }
  if (blockIdx.x == 0 && t == 0) rowptr[N_NODES] = N_EDGES;
}

// ---------------- CSR build: scatter srcs by dst ----------------
__global__ void k_scatter(const int* __restrict__ srcA, const int* __restrict__ dstA,
                          int* __restrict__ cur, int* __restrict__ csr) {
  int e = blockIdx.x * blockDim.x + threadIdx.x;
  if (e >= N_EDGES) return;
  int pos = atomicAdd(&cur[dstA[e]], 1);
  csr[pos] = srcA[e];
}

// ---------------- GAT layer 1 aggregation: wave per dst, lane = channel ----------------
__global__ void k_agg1(const int* __restrict__ rowptr, const int* __restrict__ csr,
                       const float* __restrict__ h1, const float* __restrict__ as1,
                       const float* __restrict__ ad1, float* __restrict__ out1) {
  int gid = blockIdx.x * blockDim.x + threadIdx.x;
  int n = gid >> 6, l = gid & 63;
  if (n >= N_NODES) return;
  int h = l >> 3;
  float adv = ad1[n * 8 + h];
  // self loop
  float ex = expf(lrelu02(as1[n * 8 + h] + adv));
  float acc = ex * h1[n * 64 + l];
  float den = ex;
  int s0 = rowptr[n], s1 = rowptr[n + 1];
  for (int i = s0; i < s1; i++) {
    int src = csr[i];
    float e2 = expf(lrelu02(as1[src * 8 + h] + adv));
    acc = fmaf(e2, h1[src * 64 + l], acc);
    den += e2;
  }
  out1[n * 64 + l] = acc / den;
}

// ---------------- normalize out1 already done; bias + ELU + GAT2 linear + att feats ----
__global__ void __launch_bounds__(256)
k_node2(const float* __restrict__ out1, const float* __restrict__ b1,
        const float* __restrict__ W2, const float* __restrict__ attS2,
        const float* __restrict__ attD2, float* __restrict__ g,
        float* __restrict__ as2, float* __restrict__ ad2) {
  __shared__ float sW[64 * 64];
  __shared__ float sA[64], sD[64], sB[64];
  int t = threadIdx.x;
  for (int i = t; i < 64 * 64; i += blockDim.x) sW[i] = W2[i];
  if (t < 64) { sA[t] = attS2[t]; sD[t] = attD2[t]; sB[t] = b1[t]; }
  __syncthreads();
  int n = blockIdx.x * blockDim.x + t;
  if (n >= N_NODES) return;
  float h2[64];
#pragma unroll
  for (int c = 0; c < 64; c++) {
    float v = out1[n * 64 + c] + sB[c];
    h2[c] = v > 0.f ? v : expm1f(v);
  }
  float s2 = 0.f, d2 = 0.f;
  for (int o = 0; o < 64; o++) {
    float acc = 0.f;
#pragma unroll
    for (int c = 0; c < 64; c++) acc = fmaf(h2[c], sW[o * 64 + c], acc);
    g[n * 64 + o] = acc;
    s2 = fmaf(acc, sA[o], s2);
    d2 = fmaf(acc, sD[o], d2);
  }
  as2[n] = s2;
  ad2[n] = d2;
}

// ---------------- GAT layer 2 aggregation: wave per dst, lane = channel ----------------
__global__ void k_agg2(const int* __restrict__ rowptr, const int* __restrict__ csr,
                       const float* __restrict__ g, const float* __restrict__ as2,
                       const float* __restrict__ ad2, float* __restrict__ out2) {
  int gid = blockIdx.x * blockDim.x + threadIdx.x;
  int n = gid >> 6, l = gid & 63;
  if (n >= N_NODES) return;
  float adv = ad2[n];
  float ex = expf(lrelu02(as2[n] + adv));
  float acc = ex * g[n * 64 + l];
  float den = ex;
  int s0 = rowptr[n], s1 = rowptr[n + 1];
  for (int i = s0; i < s1; i++) {
    int src = csr[i];
    float e2 = expf(lrelu02(as2[src] + adv));
    acc = fmaf(e2, g[src * 64 + l], acc);
    den += e2;
  }
  out2[n * 64 + l] = acc / den;
}

// ---------------- per-frame mean over nodes (out2 already normalized) ----------------
__global__ void k_reduce(const float* __restrict__ out2, float* __restrict__ emb) {
  __shared__ float part[4][64];
  int c = threadIdx.x & 63, r = threadIdx.x >> 6;
  int start = blockIdx.x * NPB_RED;
  int end = start + NPB_RED;
  if (end > N_NODES) end = N_NODES;
  float acc = 0.f;
  for (int n = start + r; n < end; n += 4) acc += out2[n * 64 + c];
  part[r][c] = acc;
  __syncthreads();
  if (r == 0)
    atomicAdd(&emb[c], (part[0][c] + part[1][c] + part[2][c] + part[3][c]) * (1.0f / N_NODES));
}

// ---------------- tiny transformer (1,5,64) ×3 layers + head, single block ----------------
__global__ void k_transformer(const float* __restrict__ emb, const float* __restrict__ b2,
                              const float* __restrict__ Wqkv, const float* __restrict__ bqkv,
                              const float* __restrict__ Wo, const float* __restrict__ bo,
                              const float* __restrict__ ln1w, const float* __restrict__ ln1b,
                              const float* __restrict__ Wff1, const float* __restrict__ bff1,
                              const float* __restrict__ Wff2, const float* __restrict__ bff2,
                              const float* __restrict__ ln2w, const float* __restrict__ ln2b,
                              const float* __restrict__ Wh1, const float* __restrict__ bh1,
                              const float* __restrict__ Wh2, const float* __restrict__ bh2,
                              float* __restrict__ out) {
  __shared__ float seq[5][64];
  __shared__ float qkv[5][192];
  __shared__ float att[4][5][5];
  __shared__ float ob[5][64];
  __shared__ float ffb[5][128];
  __shared__ float tmp[5][64];
  __shared__ float mv[5][2];
  __shared__ float hid[32];
  int t = threadIdx.x;
  for (int i = t; i < 320; i += 256) seq[i >> 6][i & 63] = emb[i] + b2[i & 63];
  __syncthreads();
  for (int l = 0; l < 3; l++) {
    const float* Wq = Wqkv + l * 192 * 64; const float* bq = bqkv + l * 192;
    const float* Wol = Wo + l * 64 * 64;   const float* bol = bo + l * 64;
    const float* w1 = ln1w + l * 64;       const float* bb1 = ln1b + l * 64;
    const float* Wf1 = Wff1 + l * 128 * 64; const float* bf1 = bff1 + l * 128;
    const float* Wf2 = Wff2 + l * 64 * 128; const float* bf2 = bff2 + l * 64;
    const float* w2 = ln2w + l * 64;       const float* bb2 = ln2b + l * 64;

    for (int i = t; i < 960; i += 256) {
      int s = i / 192, j = i % 192;
      float acc = bq[j];
      for (int c = 0; c < 64; c++) acc = fmaf(seq[s][c], Wq[j * 64 + c], acc);
      qkv[s][j] = acc;
    }
    __syncthreads();
    if (t < 100) {
      int hh = t / 25, qs = (t / 5) % 5, ks = t % 5;
      float acc = 0.f;
      for (int d = 0; d < 16; d++) acc = fmaf(qkv[qs][hh * 16 + d], qkv[ks][64 + hh * 16 + d], acc);
      att[hh][qs][ks] = acc * 0.25f;
    }
    __syncthreads();
    if (t < 20) {
      int hh = t / 5, qs = t % 5;
      float m = att[hh][qs][0];
      for (int k2 = 1; k2 < 5; k2++) m = fmaxf(m, att[hh][qs][k2]);
      float ss = 0.f;
      for (int k2 = 0; k2 < 5; k2++) { float v = expf(att[hh][qs][k2] - m); att[hh][qs][k2] = v; ss += v; }
      float inv = 1.f / ss;
      for (int k2 = 0; k2 < 5; k2++) att[hh][qs][k2] *= inv;
    }
    __syncthreads();
    for (int i = t; i < 320; i += 256) {
      int s = i >> 6, j = i & 63, hh = j >> 4;
      float acc = 0.f;
      for (int k2 = 0; k2 < 5; k2++) acc = fmaf(att[hh][s][k2], qkv[k2][128 + j], acc);
      ob[s][j] = acc;
    }
    __syncthreads();
    for (int i = t; i < 320; i += 256) {
      int s = i >> 6, c = i & 63;
      float acc = bol[c];
      for (int j = 0; j < 64; j++) acc = fmaf(ob[s][j], Wol[c * 64 + j], acc);
      tmp[s][c] = seq[s][c] + acc;
    }
    __syncthreads();
    if (t < 5) {
      float m = 0.f;
      for (int c = 0; c < 64; c++) m += tmp[t][c];
      m *= (1.f / 64.f);
      float v = 0.f;
      for (int c = 0; c < 64; c++) { float d = tmp[t][c] - m; v = fmaf(d, d, v); }
      v *= (1.f / 64.f);
      mv[t][0] = m; mv[t][1] = 1.f / sqrtf(v + 1e-5f);
    }
    __syncthreads();
    for (int i = t; i < 320; i += 256) {
      int s = i >> 6, c = i & 63;
      seq[s][c] = (tmp[s][c] - mv[s][0]) * mv[s][1] * w1[c] + bb1[c];
    }
    __syncthreads();
    for (int i = t; i < 640; i += 256) {
      int s = i / 128, j = i % 128;
      float acc = bf1[j];
      for (int c = 0; c < 64; c++) acc = fmaf(seq[s][c], Wf1[j * 64 + c], acc);
      ffb[s][j] = fmaxf(acc, 0.f);
    }
    __syncthreads();
    for (int i = t; i < 320; i += 256) {
      int s = i >> 6, c = i & 63;
      float acc = bf2[c];
      for (int j = 0; j < 128; j++) acc = fmaf(ffb[s][j], Wf2[c * 128 + j], acc);
      tmp[s][c] = seq[s][c] + acc;
    }
    __syncthreads();
    if (t < 5) {
      float m = 0.f;
      for (int c = 0; c < 64; c++) m += tmp[t][c];
      m *= (1.f / 64.f);
      float v = 0.f;
      for (int c = 0; c < 64; c++) { float d = tmp[t][c] - m; v = fmaf(d, d, v); }
      v *= (1.f / 64.f);
      mv[t][0] = m; mv[t][1] = 1.f / sqrtf(v + 1e-5f);
    }
    __syncthreads();
    for (int i = t; i < 320; i += 256) {
      int s = i >> 6, c = i & 63;
      seq[s][c] = (tmp[s][c] - mv[s][0]) * mv[s][1] * w2[c] + bb2[c];
    }
    __syncthreads();
  }
  if (t < 32) {
    float acc = bh1[t];
    for (int c = 0; c < 64; c++) acc = fmaf(seq[4][c], Wh1[t * 64 + c], acc);
    hid[t] = fmaxf(acc, 0.f);
  }
  __syncthreads();
  if (t < 2) {
    float acc = bh2[t];
    for (int j = 0; j < 32; j++) acc = fmaf(hid[j], Wh2[t * 32 + j], acc);
    out[t] = acc;
  }
}

extern "C" void kernel_launch(void* const* d_in, const int* in_sizes, int n_in,
                              void* d_out, int out_size, void* d_ws, size_t ws_size,
                              hipStream_t stream) {
  const float* x     = (const float*)d_in[0];
  const int*   ei    = (const int*)d_in[1];
  const float* W1    = (const float*)d_in[2];
  const float* attS1 = (const float*)d_in[3];
  const float* attD1 = (const float*)d_in[4];
  const float* b1    = (const float*)d_in[5];
  const float* W2    = (const float*)d_in[6];
  const float* attS2 = (const float*)d_in[7];
  const float* attD2 = (const float*)d_in[8];
  const float* b2    = (const float*)d_in[9];
  const float* tWqkv = (const float*)d_in[10];
  const float* tbqkv = (const float*)d_in[11];
  const float* tWo   = (const float*)d_in[12];
  const float* tbo   = (const float*)d_in[13];
  const float* tln1w = (const float*)d_in[14];
  const float* tln1b = (const float*)d_in[15];
  const float* tWff1 = (const float*)d_in[16];
  const float* tbff1 = (const float*)d_in[17];
  const float* tWff2 = (const float*)d_in[18];
  const float* tbff2 = (const float*)d_in[19];
  const float* tln2w = (const float*)d_in[20];
  const float* tln2b = (const float*)d_in[21];
  const float* Wh1   = (const float*)d_in[22];
  const float* bh1   = (const float*)d_in[23];
  const float* Wh2   = (const float*)d_in[24];
  const float* bh2   = (const float*)d_in[25];
  float* out = (float*)d_out;

  float* ws  = (float*)d_ws;
  float* h1g = ws;                 // 3,200,000 floats: h1 (GAT1) then g (GAT2)
  float* as1 = h1g + 3200000;      // 400,000
  float* ad1 = as1 + 400000;       // 400,000
  float* acc = ad1 + 400000;       // 3,200,000 (out1; reused as out2)
  float* as2 = acc + 3200000;      // 50,000
  float* ad2 = as2 + 50000;        // 50,000
  float* emb = ad2 + 50000;        // 320
  int* deg    = (int*)(emb + 320); // 50,000
  int* rowptr = deg + 50000;       // 50,001
  int* cur    = rowptr + 50001;    // 50,000
  int* bsum   = cur + 50000;       // NB_NODE
  int* boff   = bsum + NB_NODE;    // NB_NODE
  int* csr    = boff + NB_NODE;    // 400,000

  (void)hipMemsetAsync(emb, 0, 320 * sizeof(float), stream);

  const int nodeBlocks = NB_NODE;
  const int aggBlocks  = (N_NODES * 64 + 255) / 256;
  const int edgeBlocks = (N_EDGES + 255) / 256;

  for (int f = 0; f < 5; f++) {
    const float* xf  = x + (size_t)f * N_NODES * 13;
    const int* srcA  = ei + (size_t)f * 2 * N_EDGES;
    const int* dstA  = srcA + N_EDGES;

    // CSR build (dst-sorted, real edges only; self-loops handled analytically)
    (void)hipMemsetAsync(deg, 0, N_NODES * sizeof(int), stream);
    k_hist<<<edgeBlocks, 256, 0, stream>>>(dstA, deg);
    k_scan1<<<nodeBlocks, 256, 0, stream>>>(deg, bsum);
    k_scan2<<<1, 256, 0, stream>>>(bsum, boff);
    k_scan3<<<nodeBlocks, 256, 0, stream>>>(deg, boff, rowptr, cur);
    k_scatter<<<edgeBlocks, 256, 0, stream>>>(srcA, dstA, cur, csr);

    k_node1<<<nodeBlocks, 256, 0, stream>>>(xf, W1, attS1, attD1, h1g, as1, ad1);
    k_agg1<<<aggBlocks, 256, 0, stream>>>(rowptr, csr, h1g, as1, ad1, acc);
    k_node2<<<nodeBlocks, 256, 0, stream>>>(acc, b1, W2, attS2, attD2, h1g, as2, ad2);
    k_agg2<<<aggBlocks, 256, 0, stream>>>(rowptr, csr, h1g, as2, ad2, acc);
    k_reduce<<<(N_NODES + NPB_RED - 1) / NPB_RED, 256, 0, stream>>>(acc, emb + f * 64);
  }

  k_transformer<<<1, 256, 0, stream>>>(emb, b2, tWqkv, tbqkv, tWo, tbo, tln1w, tln1b,
                                       tWff1, tbff1, tWff2, tbff2, tln2w, tln2b,
                                       Wh1, bh1, Wh2, bh2, out);
}

// Round 3
// 1335.372 us; speedup vs baseline: 1.5307x; 1.0455x over previous
//
#include <hip/hip_runtime.h>
#include <math.h>

#define N_NODES 50000
#define N_EDGES 400000
#define NPB_RED 512
#define NB_NODE ((N_NODES + 255) / 256)   // 196 blocks of 256 over nodes

__device__ __forceinline__ float lrelu02(float x) { return x > 0.f ? x : 0.2f * x; }

// ---------------- GAT layer 1: wave per node, lane = output channel ----------------
__global__ void __launch_bounds__(256, 8)
k_node1(const float* __restrict__ x, const float* __restrict__ W1,
        const float* __restrict__ attS, const float* __restrict__ attD,
        float* __restrict__ h1, float* __restrict__ as1, float* __restrict__ ad1) {
  int l = threadIdx.x & 63;
  int wid = (blockIdx.x * blockDim.x + threadIdx.x) >> 6;
  int nw = (gridDim.x * blockDim.x) >> 6;
  float w1r[13];
#pragma unroll
  for (int c = 0; c < 13; c++) w1r[c] = W1[l * 13 + c];
  float aS = attS[l], aD = attD[l];
  for (int n = wid; n < N_NODES; n += nw) {
    float xv = (l < 13) ? x[n * 13 + l] : 0.f;
    float acc = 0.f;
#pragma unroll
    for (int c = 0; c < 13; c++) acc = fmaf(__shfl(xv, c, 64), w1r[c], acc);
    h1[n * 64 + l] = acc;
    float s = acc * aS, d = acc * aD;
#pragma unroll
    for (int off = 1; off < 8; off <<= 1) {
      s += __shfl_xor(s, off, 64);
      d += __shfl_xor(d, off, 64);
    }
    if ((l & 7) == 0) { as1[n * 8 + (l >> 3)] = s; ad1[n * 8 + (l >> 3)] = d; }
  }
}

// ---------------- CSR build: histogram of real edges by dst ----------------
__global__ void k_hist(const int* __restrict__ dstA, int* __restrict__ deg) {
  int e = blockIdx.x * blockDim.x + threadIdx.x;
  if (e < N_EDGES) atomicAdd(&deg[dstA[e]], 1);
}

// ---------------- CSR build: per-block sums ----------------
__global__ void k_scan1(const int* __restrict__ deg, int* __restrict__ bsum) {
  __shared__ int part[256];
  int t = threadIdx.x;
  int i = blockIdx.x * 256 + t;
  part[t] = (i < N_NODES) ? deg[i] : 0;
  __syncthreads();
  for (int off = 128; off > 0; off >>= 1) {
    if (t < off) part[t] += part[t + off];
    __syncthreads();
  }
  if (t == 0) bsum[blockIdx.x] = part[0];
}

// ---------------- CSR build: scan of block sums (single block) ----------------
__global__ void k_scan2(const int* __restrict__ bsum, int* __restrict__ boff) {
  __shared__ int part[256];
  int t = threadIdx.x;
  part[t] = (t < NB_NODE) ? bsum[t] : 0;
  __syncthreads();
  for (int off = 1; off < 256; off <<= 1) {
    int v = (t >= off) ? part[t - off] : 0;
    __syncthreads();
    part[t] += v;
    __syncthreads();
  }
  if (t < NB_NODE) boff[t] = part[t] - bsum[t];  // exclusive
}

// ---------------- CSR build: intra-block scan -> rowptr & cursor ----------------
__global__ void k_scan3(const int* __restrict__ deg, const int* __restrict__ boff,
                        int* __restrict__ rowptr, int* __restrict__ cur) {
  __shared__ int part[256];
  int t = threadIdx.x;
  int i = blockIdx.x * 256 + t;
  int d = (i < N_NODES) ? deg[i] : 0;
  part[t] = d;
  __syncthreads();
  for (int off = 1; off < 256; off <<= 1) {
    int v = (t >= off) ? part[t - off] : 0;
    __syncthreads();
    part[t] += v;
    __syncthreads();
  }
  if (i < N_NODES) {
    int r = boff[blockIdx.x] + part[t] - d;  // exclusive prefix
    rowptr[i] = r;
    cur[i] = r;
  }
  if (blockIdx.x == 0 && t == 0) rowptr[N_NODES] = N_EDGES;
}

// ---------------- CSR build: scatter srcs by dst ----------------
__global__ void k_scatter(const int* __restrict__ srcA, const int* __restrict__ dstA,
                          int* __restrict__ cur, int* __restrict__ csr) {
  int e = blockIdx.x * blockDim.x + threadIdx.x;
  if (e >= N_EDGES) return;
  int pos = atomicAdd(&cur[dstA[e]], 1);
  csr[pos] = srcA[e];
}

// ---------------- GAT layer 1 aggregation: wave per dst, lane = channel ----------------
__global__ void k_agg1(const int* __restrict__ rowptr, const int* __restrict__ csr,
                       const float* __restrict__ h1, const float* __restrict__ as1,
                       const float* __restrict__ ad1, float* __restrict__ out1) {
  int gid = blockIdx.x * blockDim.x + threadIdx.x;
  int n = gid >> 6, l = gid & 63;
  if (n >= N_NODES) return;
  int h = l >> 3;
  float adv = ad1[n * 8 + h];
  // self loop
  float ex = expf(lrelu02(as1[n * 8 + h] + adv));
  float acc = ex * h1[n * 64 + l];
  float den = ex;
  int s0 = rowptr[n], s1 = rowptr[n + 1];
  for (int i = s0; i < s1; i++) {
    int src = csr[i];
    float e2 = expf(lrelu02(as1[src * 8 + h] + adv));
    acc = fmaf(e2, h1[src * 64 + l], acc);
    den += e2;
  }
  out1[n * 64 + l] = acc / den;
}

// ---------------- bias + ELU + GAT2 linear + att feats: wave per node ----------------
__global__ void __launch_bounds__(256, 4)
k_node2(const float* __restrict__ out1, const float* __restrict__ b1,
        const float* __restrict__ W2, const float* __restrict__ attS2,
        const float* __restrict__ attD2, float* __restrict__ g,
        float* __restrict__ as2, float* __restrict__ ad2) {
  int l = threadIdx.x & 63;
  int wid = (blockIdx.x * blockDim.x + threadIdx.x) >> 6;
  int nw = (gridDim.x * blockDim.x) >> 6;
  float w[64];
#pragma unroll
  for (int c4 = 0; c4 < 16; c4++) {
    float4 v = *reinterpret_cast<const float4*>(&W2[l * 64 + c4 * 4]);
    w[c4 * 4 + 0] = v.x; w[c4 * 4 + 1] = v.y; w[c4 * 4 + 2] = v.z; w[c4 * 4 + 3] = v.w;
  }
  float aS = attS2[l], aD = attD2[l], bb = b1[l];
  for (int n = wid; n < N_NODES; n += nw) {
    float v = out1[n * 64 + l] + bb;
    float hh = v > 0.f ? v : expm1f(v);
    float acc = 0.f;
#pragma unroll
    for (int c = 0; c < 64; c++) acc = fmaf(__shfl(hh, c, 64), w[c], acc);
    g[n * 64 + l] = acc;
    float s2 = acc * aS, d2 = acc * aD;
#pragma unroll
    for (int off = 32; off > 0; off >>= 1) {
      s2 += __shfl_xor(s2, off, 64);
      d2 += __shfl_xor(d2, off, 64);
    }
    if (l == 0) { as2[n] = s2; ad2[n] = d2; }
  }
}

// ---------------- GAT layer 2 aggregation: wave per dst, lane = channel ----------------
__global__ void k_agg2(const int* __restrict__ rowptr, const int* __restrict__ csr,
                       const float* __restrict__ g, const float* __restrict__ as2,
                       const float* __restrict__ ad2, float* __restrict__ out2) {
  int gid = blockIdx.x * blockDim.x + threadIdx.x;
  int n = gid >> 6, l = gid & 63;
  if (n >= N_NODES) return;
  float adv = ad2[n];
  float ex = expf(lrelu02(as2[n] + adv));
  float acc = ex * g[n * 64 + l];
  float den = ex;
  int s0 = rowptr[n], s1 = rowptr[n + 1];
  for (int i = s0; i < s1; i++) {
    int src = csr[i];
    float e2 = expf(lrelu02(as2[src] + adv));
    acc = fmaf(e2, g[src * 64 + l], acc);
    den += e2;
  }
  out2[n * 64 + l] = acc / den;
}

// ---------------- per-frame mean over nodes (out2 already normalized) ----------------
__global__ void k_reduce(const float* __restrict__ out2, float* __restrict__ emb) {
  __shared__ float part[4][64];
  int c = threadIdx.x & 63, r = threadIdx.x >> 6;
  int start = blockIdx.x * NPB_RED;
  int end = start + NPB_RED;
  if (end > N_NODES) end = N_NODES;
  float acc = 0.f;
  for (int n = start + r; n < end; n += 4) acc += out2[n * 64 + c];
  part[r][c] = acc;
  __syncthreads();
  if (r == 0)
    atomicAdd(&emb[c], (part[0][c] + part[1][c] + part[2][c] + part[3][c]) * (1.0f / N_NODES));
}

// ---------------- tiny transformer (1,5,64) ×3 layers + head, single block ----------------
// Per-layer weights (128 KB) staged into LDS with coalesced float4 loads.
__global__ void k_transformer(const float* __restrict__ emb, const float* __restrict__ b2,
                              const float* __restrict__ Wqkv, const float* __restrict__ bqkv,
                              const float* __restrict__ Wo, const float* __restrict__ bo,
                              const float* __restrict__ ln1w, const float* __restrict__ ln1b,
                              const float* __restrict__ Wff1, const float* __restrict__ bff1,
                              const float* __restrict__ Wff2, const float* __restrict__ bff2,
                              const float* __restrict__ ln2w, const float* __restrict__ ln2b,
                              const float* __restrict__ Wh1, const float* __restrict__ bh1,
                              const float* __restrict__ Wh2, const float* __restrict__ bh2,
                              float* __restrict__ out) {
  __shared__ float sWq[12288];
  __shared__ float sWo[4096];
  __shared__ float sWf1[8192];
  __shared__ float sWf2[8192];
  __shared__ float seq[5][64];
  __shared__ float qkv[5][192];
  __shared__ float att[4][5][5];
  __shared__ float ob[5][64];
  __shared__ float ffb[5][128];
  __shared__ float tmp[5][64];
  __shared__ float mv[5][2];
  __shared__ float hid[32];
  int t = threadIdx.x;
  for (int i = t; i < 320; i += 256) seq[i >> 6][i & 63] = emb[i] + b2[i & 63];
  __syncthreads();
  for (int l = 0; l < 3; l++) {
    // stage layer weights into LDS (coalesced float4)
    const float4* gWq = (const float4*)(Wqkv + l * 12288);
    const float4* gWo = (const float4*)(Wo + l * 4096);
    const float4* gW1 = (const float4*)(Wff1 + l * 8192);
    const float4* gW2 = (const float4*)(Wff2 + l * 8192);
    for (int i = t; i < 3072; i += 256) ((float4*)sWq)[i] = gWq[i];
    for (int i = t; i < 1024; i += 256) ((float4*)sWo)[i] = gWo[i];
    for (int i = t; i < 2048; i += 256) ((float4*)sWf1)[i] = gW1[i];
    for (int i = t; i < 2048; i += 256) ((float4*)sWf2)[i] = gW2[i];
    const float* bq = bqkv + l * 192;
    const float* bol = bo + l * 64;
    const float* w1 = ln1w + l * 64;  const float* bb1 = ln1b + l * 64;
    const float* bf1 = bff1 + l * 128;
    const float* bf2 = bff2 + l * 64;
    const float* w2 = ln2w + l * 64;  const float* bb2 = ln2b + l * 64;
    __syncthreads();

    for (int i = t; i < 960; i += 256) {
      int s = i / 192, j = i % 192;
      float acc = bq[j];
      for (int c = 0; c < 64; c++) acc = fmaf(seq[s][c], sWq[j * 64 + c], acc);
      qkv[s][j] = acc;
    }
    __syncthreads();
    if (t < 100) {
      int hh = t / 25, qs = (t / 5) % 5, ks = t % 5;
      float acc = 0.f;
      for (int d = 0; d < 16; d++) acc = fmaf(qkv[qs][hh * 16 + d], qkv[ks][64 + hh * 16 + d], acc);
      att[hh][qs][ks] = acc * 0.25f;
    }
    __syncthreads();
    if (t < 20) {
      int hh = t / 5, qs = t % 5;
      float m = att[hh][qs][0];
      for (int k2 = 1; k2 < 5; k2++) m = fmaxf(m, att[hh][qs][k2]);
      float ss = 0.f;
      for (int k2 = 0; k2 < 5; k2++) { float v = expf(att[hh][qs][k2] - m); att[hh][qs][k2] = v; ss += v; }
      float inv = 1.f / ss;
      for (int k2 = 0; k2 < 5; k2++) att[hh][qs][k2] *= inv;
    }
    __syncthreads();
    for (int i = t; i < 320; i += 256) {
      int s = i >> 6, j = i & 63, hh = j >> 4;
      float acc = 0.f;
      for (int k2 = 0; k2 < 5; k2++) acc = fmaf(att[hh][s][k2], qkv[k2][128 + j], acc);
      ob[s][j] = acc;
    }
    __syncthreads();
    for (int i = t; i < 320; i += 256) {
      int s = i >> 6, c = i & 63;
      float acc = bol[c];
      for (int j = 0; j < 64; j++) acc = fmaf(ob[s][j], sWo[c * 64 + j], acc);
      tmp[s][c] = seq[s][c] + acc;
    }
    __syncthreads();
    if (t < 5) {
      float m = 0.f;
      for (int c = 0; c < 64; c++) m += tmp[t][c];
      m *= (1.f / 64.f);
      float v = 0.f;
      for (int c = 0; c < 64; c++) { float d = tmp[t][c] - m; v = fmaf(d, d, v); }
      v *= (1.f / 64.f);
      mv[t][0] = m; mv[t][1] = 1.f / sqrtf(v + 1e-5f);
    }
    __syncthreads();
    for (int i = t; i < 320; i += 256) {
      int s = i >> 6, c = i & 63;
      seq[s][c] = (tmp[s][c] - mv[s][0]) * mv[s][1] * w1[c] + bb1[c];
    }
    __syncthreads();
    for (int i = t; i < 640; i += 256) {
      int s = i / 128, j = i % 128;
      float acc = bf1[j];
      for (int c = 0; c < 64; c++) acc = fmaf(seq[s][c], sWf1[j * 64 + c], acc);
      ffb[s][j] = fmaxf(acc, 0.f);
    }
    __syncthreads();
    for (int i = t; i < 320; i += 256) {
      int s = i >> 6, c = i & 63;
      float acc = bf2[c];
      for (int j = 0; j < 128; j++) acc = fmaf(ffb[s][j], sWf2[c * 128 + j], acc);
      tmp[s][c] = seq[s][c] + acc;
    }
    __syncthreads();
    if (t < 5) {
      float m = 0.f;
      for (int c = 0; c < 64; c++) m += tmp[t][c];
      m *= (1.f / 64.f);
      float v = 0.f;
      for (int c = 0; c < 64; c++) { float d = tmp[t][c] - m; v = fmaf(d, d, v); }
      v *= (1.f / 64.f);
      mv[t][0] = m; mv[t][1] = 1.f / sqrtf(v + 1e-5f);
    }
    __syncthreads();
    for (int i = t; i < 320; i += 256) {
      int s = i >> 6, c = i & 63;
      seq[s][c] = (tmp[s][c] - mv[s][0]) * mv[s][1] * w2[c] + bb2[c];
    }
    __syncthreads();
  }
  if (t < 32) {
    float acc = bh1[t];
    for (int c = 0; c < 64; c++) acc = fmaf(seq[4][c], Wh1[t * 64 + c], acc);
    hid[t] = fmaxf(acc, 0.f);
  }
  __syncthreads();
  if (t < 2) {
    float acc = bh2[t];
    for (int j = 0; j < 32; j++) acc = fmaf(hid[j], Wh2[t * 32 + j], acc);
    out[t] = acc;
  }
}

extern "C" void kernel_launch(void* const* d_in, const int* in_sizes, int n_in,
                              void* d_out, int out_size, void* d_ws, size_t ws_size,
                              hipStream_t stream) {
  const float* x     = (const float*)d_in[0];
  const int*   ei    = (const int*)d_in[1];
  const float* W1    = (const float*)d_in[2];
  const float* attS1 = (const float*)d_in[3];
  const float* attD1 = (const float*)d_in[4];
  const float* b1    = (const float*)d_in[5];
  const float* W2    = (const float*)d_in[6];
  const float* attS2 = (const float*)d_in[7];
  const float* attD2 = (const float*)d_in[8];
  const float* b2    = (const float*)d_in[9];
  const float* tWqkv = (const float*)d_in[10];
  const float* tbqkv = (const float*)d_in[11];
  const float* tWo   = (const float*)d_in[12];
  const float* tbo   = (const float*)d_in[13];
  const float* tln1w = (const float*)d_in[14];
  const float* tln1b = (const float*)d_in[15];
  const float* tWff1 = (const float*)d_in[16];
  const float* tbff1 = (const float*)d_in[17];
  const float* tWff2 = (const float*)d_in[18];
  const float* tbff2 = (const float*)d_in[19];
  const float* tln2w = (const float*)d_in[20];
  const float* tln2b = (const float*)d_in[21];
  const float* Wh1   = (const float*)d_in[22];
  const float* bh1   = (const float*)d_in[23];
  const float* Wh2   = (const float*)d_in[24];
  const float* bh2   = (const float*)d_in[25];
  float* out = (float*)d_out;

  float* ws  = (float*)d_ws;
  float* h1g = ws;                 // 3,200,000 floats: h1 (GAT1) then g (GAT2)
  float* as1 = h1g + 3200000;      // 400,000
  float* ad1 = as1 + 400000;       // 400,000
  float* acc = ad1 + 400000;       // 3,200,000 (out1; reused as out2)
  float* as2 = acc + 3200000;      // 50,000
  float* ad2 = as2 + 50000;        // 50,000
  float* emb = ad2 + 50000;        // 320
  int* deg    = (int*)(emb + 320); // 50,000
  int* rowptr = deg + 50000;       // 50,001
  int* cur    = rowptr + 50001;    // 50,000
  int* bsum   = cur + 50000;       // NB_NODE
  int* boff   = bsum + NB_NODE;    // NB_NODE
  int* csr    = boff + NB_NODE;    // 400,000

  (void)hipMemsetAsync(emb, 0, 320 * sizeof(float), stream);

  const int nodeBlocks = NB_NODE;
  const int waveBlocks = 1024;     // grid-stride wave-per-node kernels
  const int aggBlocks  = (N_NODES * 64 + 255) / 256;
  const int edgeBlocks = (N_EDGES + 255) / 256;

  for (int f = 0; f < 5; f++) {
    const float* xf  = x + (size_t)f * N_NODES * 13;
    const int* srcA  = ei + (size_t)f * 2 * N_EDGES;
    const int* dstA  = srcA + N_EDGES;

    // CSR build (dst-sorted, real edges only; self-loops handled analytically)
    (void)hipMemsetAsync(deg, 0, N_NODES * sizeof(int), stream);
    k_hist<<<edgeBlocks, 256, 0, stream>>>(dstA, deg);
    k_scan1<<<nodeBlocks, 256, 0, stream>>>(deg, bsum);
    k_scan2<<<1, 256, 0, stream>>>(bsum, boff);
    k_scan3<<<nodeBlocks, 256, 0, stream>>>(deg, boff, rowptr, cur);
    k_scatter<<<edgeBlocks, 256, 0, stream>>>(srcA, dstA, cur, csr);

    k_node1<<<waveBlocks, 256, 0, stream>>>(xf, W1, attS1, attD1, h1g, as1, ad1);
    k_agg1<<<aggBlocks, 256, 0, stream>>>(rowptr, csr, h1g, as1, ad1, acc);
    k_node2<<<waveBlocks, 256, 0, stream>>>(acc, b1, W2, attS2, attD2, h1g, as2, ad2);
    k_agg2<<<aggBlocks, 256, 0, stream>>>(rowptr, csr, h1g, as2, ad2, acc);
    k_reduce<<<(N_NODES + NPB_RED - 1) / NPB_RED, 256, 0, stream>>>(acc, emb + f * 64);
  }

  k_transformer<<<1, 256, 0, stream>>>(emb, b2, tWqkv, tbqkv, tWo, tbo, tln1w, tln1b,
                                       tWff1, tbff1, tWff2, tbff2, tln2w, tln2b,
                                       Wh1, bh1, Wh2, bh2, out);
}

// Round 4
// 1008.252 us; speedup vs baseline: 2.0273x; 1.3244x over previous
//
#include <hip/hip_runtime.h>
#include <math.h>

#define NN_F 50000      // nodes per frame
#define NE_F 400000     // edges per frame

__device__ __forceinline__ float lrelu02(float x) { return x > 0.f ? x : 0.2f * x; }

// ---------------- GAT layer 1: wave per node, lane = output channel ----------------
__global__ void __launch_bounds__(256)
k_node1(const float* __restrict__ x, const float* __restrict__ W1,
        const float* __restrict__ attS, const float* __restrict__ attD,
        float* __restrict__ h1, float* __restrict__ as1, float* __restrict__ ad1,
        int nNodes) {
  int l = threadIdx.x & 63;
  int wid = (blockIdx.x * blockDim.x + threadIdx.x) >> 6;
  int nw = (gridDim.x * blockDim.x) >> 6;
  float w1r[13];
#pragma unroll
  for (int c = 0; c < 13; c++) w1r[c] = W1[l * 13 + c];
  float aS = attS[l], aD = attD[l];
  for (int n = wid; n < nNodes; n += nw) {
    float xv = (l < 13) ? x[(size_t)n * 13 + l] : 0.f;
    float acc = 0.f;
#pragma unroll
    for (int c = 0; c < 13; c++) acc = fmaf(__shfl(xv, c, 64), w1r[c], acc);
    h1[(size_t)n * 64 + l] = acc;
    float s = acc * aS, d = acc * aD;
#pragma unroll
    for (int off = 1; off < 8; off <<= 1) {
      s += __shfl_xor(s, off, 64);
      d += __shfl_xor(d, off, 64);
    }
    if ((l & 7) == 0) { as1[n * 8 + (l >> 3)] = s; ad1[n * 8 + (l >> 3)] = d; }
  }
}

// ---------------- CSR build: histogram by dst (batched frames) ----------------
__global__ void k_hist(const int* __restrict__ ei, int* __restrict__ deg, int nFrames) {
  int e = blockIdx.x * blockDim.x + threadIdx.x;
  if (e >= nFrames * NE_F) return;
  int f = e / NE_F, idx = e - f * NE_F;
  int dst = ei[(size_t)f * 2 * NE_F + NE_F + idx];
  atomicAdd(&deg[f * NN_F + dst], 1);
}

// ---------------- CSR build: per-block sums ----------------
__global__ void k_scan1(const int* __restrict__ deg, int* __restrict__ bsum, int nNodes) {
  __shared__ int part[256];
  int t = threadIdx.x;
  int i = blockIdx.x * 256 + t;
  part[t] = (i < nNodes) ? deg[i] : 0;
  __syncthreads();
  for (int off = 128; off > 0; off >>= 1) {
    if (t < off) part[t] += part[t + off];
    __syncthreads();
  }
  if (t == 0) bsum[blockIdx.x] = part[0];
}

// ---------------- CSR build: scan of block sums (single block, up to 1024) ----------------
__global__ void __launch_bounds__(1024)
k_scan2(const int* __restrict__ bsum, int* __restrict__ boff, int nblk) {
  __shared__ int part[1024];
  int t = threadIdx.x;
  part[t] = (t < nblk) ? bsum[t] : 0;
  __syncthreads();
  for (int off = 1; off < 1024; off <<= 1) {
    int v = (t >= off) ? part[t - off] : 0;
    __syncthreads();
    part[t] += v;
    __syncthreads();
  }
  if (t < nblk) boff[t] = part[t] - bsum[t];  // exclusive
}

// ---------------- CSR build: intra-block scan -> rowptr & cursor ----------------
__global__ void k_scan3(const int* __restrict__ deg, const int* __restrict__ boff,
                        int* __restrict__ rowptr, int* __restrict__ cur,
                        int nNodes, int nEdges) {
  __shared__ int part[256];
  int t = threadIdx.x;
  int i = blockIdx.x * 256 + t;
  int d = (i < nNodes) ? deg[i] : 0;
  part[t] = d;
  __syncthreads();
  for (int off = 1; off < 256; off <<= 1) {
    int v = (t >= off) ? part[t - off] : 0;
    __syncthreads();
    part[t] += v;
    __syncthreads();
  }
  if (i < nNodes) {
    int r = boff[blockIdx.x] + part[t] - d;  // exclusive prefix
    rowptr[i] = r;
    cur[i] = r;
  }
  if (blockIdx.x == 0 && t == 0) rowptr[nNodes] = nEdges;
}

// ---------------- CSR build: scatter GLOBAL src ids by dst ----------------
__global__ void k_scatter(const int* __restrict__ ei, int* __restrict__ cur,
                          int* __restrict__ csr, int nFrames) {
  int e = blockIdx.x * blockDim.x + threadIdx.x;
  if (e >= nFrames * NE_F) return;
  int f = e / NE_F, idx = e - f * NE_F;
  const int* base = ei + (size_t)f * 2 * NE_F;
  int src = base[idx], dst = base[NE_F + idx];
  int pos = atomicAdd(&cur[f * NN_F + dst], 1);
  csr[pos] = f * NN_F + src;
}

// ---------------- GAT layer 1 aggregation: wave per dst, lane = channel ----------------
__global__ void k_agg1(const int* __restrict__ rowptr, const int* __restrict__ csr,
                       const float* __restrict__ h1, const float* __restrict__ as1,
                       const float* __restrict__ ad1, float* __restrict__ out1,
                       int nNodes) {
  int gid = blockIdx.x * blockDim.x + threadIdx.x;
  int n = gid >> 6, l = gid & 63;
  if (n >= nNodes) return;
  int h = l >> 3;
  float adv = ad1[n * 8 + h];
  float ex = expf(lrelu02(as1[n * 8 + h] + adv));     // self loop
  float acc = ex * h1[(size_t)n * 64 + l];
  float den = ex;
  int s0 = rowptr[n], s1 = rowptr[n + 1];
  for (int i = s0; i < s1; i++) {
    int src = csr[i];
    float e2 = expf(lrelu02(as1[src * 8 + h] + adv));
    acc = fmaf(e2, h1[(size_t)src * 64 + l], acc);
    den += e2;
  }
  out1[(size_t)n * 64 + l] = acc / den;
}

// ---------------- bias + ELU + GAT2 linear (in-place safe) + att feats ----------------
__global__ void __launch_bounds__(256, 4)
k_node2(const float* __restrict__ out1, const float* __restrict__ b1,
        const float* __restrict__ W2, const float* __restrict__ attS2,
        const float* __restrict__ attD2, float* __restrict__ g,
        float* __restrict__ as2, float* __restrict__ ad2, int nNodes) {
  int l = threadIdx.x & 63;
  int wid = (blockIdx.x * blockDim.x + threadIdx.x) >> 6;
  int nw = (gridDim.x * blockDim.x) >> 6;
  float w[64];
#pragma unroll
  for (int c4 = 0; c4 < 16; c4++) {
    float4 v = *reinterpret_cast<const float4*>(&W2[l * 64 + c4 * 4]);
    w[c4 * 4 + 0] = v.x; w[c4 * 4 + 1] = v.y; w[c4 * 4 + 2] = v.z; w[c4 * 4 + 3] = v.w;
  }
  float aS = attS2[l], aD = attD2[l], bb = b1[l];
  for (int n = wid; n < nNodes; n += nw) {
    float v = out1[(size_t)n * 64 + l] + bb;
    float hh = v > 0.f ? v : expm1f(v);
    float acc = 0.f;
#pragma unroll
    for (int c = 0; c < 64; c++) acc = fmaf(__shfl(hh, c, 64), w[c], acc);
    g[(size_t)n * 64 + l] = acc;     // in-place over out1 is safe: lane reads only its own elem
    float s2 = acc * aS, d2 = acc * aD;
#pragma unroll
    for (int off = 32; off > 0; off >>= 1) {
      s2 += __shfl_xor(s2, off, 64);
      d2 += __shfl_xor(d2, off, 64);
    }
    if (l == 0) { as2[n] = s2; ad2[n] = d2; }
  }
}

// ---------------- GAT layer 2 aggregation: wave per dst, lane = channel ----------------
__global__ void k_agg2(const int* __restrict__ rowptr, const int* __restrict__ csr,
                       const float* __restrict__ g, const float* __restrict__ as2,
                       const float* __restrict__ ad2, float* __restrict__ out2,
                       int nNodes) {
  int gid = blockIdx.x * blockDim.x + threadIdx.x;
  int n = gid >> 6, l = gid & 63;
  if (n >= nNodes) return;
  float adv = ad2[n];
  float ex = expf(lrelu02(as2[n] + adv));
  float acc = ex * g[(size_t)n * 64 + l];
  float den = ex;
  int s0 = rowptr[n], s1 = rowptr[n + 1];
  for (int i = s0; i < s1; i++) {
    int src = csr[i];
    float e2 = expf(lrelu02(as2[src] + adv));
    acc = fmaf(e2, g[(size_t)src * 64 + l], acc);
    den += e2;
  }
  out2[(size_t)n * 64 + l] = acc / den;
}

// ---------------- per-frame mean over nodes (500 nodes / block, 100 blocks / frame) ----
__global__ void k_reduce(const float* __restrict__ out2, float* __restrict__ emb) {
  __shared__ float part[4][64];
  int c = threadIdx.x & 63, r = threadIdx.x >> 6;
  int f = blockIdx.x / 100;
  int i0 = f * NN_F + (blockIdx.x - f * 100) * 500;
  float acc = 0.f;
  for (int n = i0 + r; n < i0 + 500; n += 4) acc += out2[(size_t)n * 64 + c];
  part[r][c] = acc;
  __syncthreads();
  if (r == 0)
    atomicAdd(&emb[f * 64 + c],
              (part[0][c] + part[1][c] + part[2][c] + part[3][c]) * (1.0f / NN_F));
}

// ---------------- tiny transformer: 1024 threads, 16-lane-group shuffle GEMVs ----------
__device__ __forceinline__ float grp16_reduce(float p) {
#pragma unroll
  for (int off = 1; off < 16; off <<= 1) p += __shfl_xor(p, off, 64);
  return p;
}

__global__ void __launch_bounds__(1024)
k_transformer(const float* __restrict__ emb, const float* __restrict__ b2,
              const float* __restrict__ Wqkv, const float* __restrict__ bqkv,
              const float* __restrict__ Wo, const float* __restrict__ bo,
              const float* __restrict__ ln1w, const float* __restrict__ ln1b,
              const float* __restrict__ Wff1, const float* __restrict__ bff1,
              const float* __restrict__ Wff2, const float* __restrict__ bff2,
              const float* __restrict__ ln2w, const float* __restrict__ ln2b,
              const float* __restrict__ Wh1, const float* __restrict__ bh1,
              const float* __restrict__ Wh2, const float* __restrict__ bh2,
              float* __restrict__ out) {
  __shared__ float seq[5][64];
  __shared__ float qkv[5][192];
  __shared__ float att[4][5][5];
  __shared__ float aob[5][64];
  __shared__ float ffb[5][128];
  __shared__ float tmp[5][64];
  __shared__ float hid[32];
  int t = threadIdx.x;
  int l = t & 63, w = t >> 6;        // 16 waves
  int g = l >> 4, q = l & 15;        // 4 groups of 16 lanes

  if (t < 320) seq[t >> 6][t & 63] = emb[t] + b2[t & 63];
  __syncthreads();

  for (int ly = 0; ly < 3; ly++) {
    const float* Wq  = Wqkv + ly * 12288; const float* bq  = bqkv + ly * 192;
    const float* Wol = Wo   + ly * 4096;  const float* bol = bo   + ly * 64;
    const float* w1  = ln1w + ly * 64;    const float* bb1 = ln1b + ly * 64;
    const float* Wf1 = Wff1 + ly * 8192;  const float* bf1 = bff1 + ly * 128;
    const float* Wf2 = Wff2 + ly * 8192;  const float* bf2 = bff2 + ly * 64;
    const float* w2  = ln2w + ly * 64;    const float* bb2 = ln2b + ly * 64;

    // qkv: 960 outputs, 64-dot; group-per-output, coalesced W rows from global
    for (int o = w * 4 + g; o < 960; o += 64) {
      int s = o / 192, j = o - s * 192;
      float4 wv = *reinterpret_cast<const float4*>(&Wq[j * 64 + q * 4]);
      float4 xv = *reinterpret_cast<const float4*>(&seq[s][q * 4]);
      float p = wv.x * xv.x + wv.y * xv.y + wv.z * xv.z + wv.w * xv.w;
      p = grp16_reduce(p);
      if (q == 0) qkv[s][j] = p + bq[j];
    }
    __syncthreads();

    // attention scores: 100 dots of 16
    if (t < 100) {
      int hh = t / 25, qs = (t / 5) % 5, ks = t % 5;
      float acc = 0.f;
      for (int d = 0; d < 16; d++)
        acc = fmaf(qkv[qs][hh * 16 + d], qkv[ks][64 + hh * 16 + d], acc);
      att[hh][qs][ks] = acc * 0.25f;
    }
    __syncthreads();
    if (t < 20) {
      int hh = t / 5, qs = t % 5;
      float m = att[hh][qs][0];
      for (int k2 = 1; k2 < 5; k2++) m = fmaxf(m, att[hh][qs][k2]);
      float ss = 0.f;
      for (int k2 = 0; k2 < 5; k2++) { float v = expf(att[hh][qs][k2] - m); att[hh][qs][k2] = v; ss += v; }
      float inv = 1.f / ss;
      for (int k2 = 0; k2 < 5; k2++) att[hh][qs][k2] *= inv;
    }
    __syncthreads();

    // att @ V : 320 outputs, 5-dot
    if (t < 320) {
      int s = t >> 6, j = t & 63, hh = j >> 4;
      float acc = 0.f;
      for (int k2 = 0; k2 < 5; k2++) acc = fmaf(att[hh][s][k2], qkv[k2][128 + j], acc);
      aob[s][j] = acc;
    }
    __syncthreads();

    // O-proj + residual: 320 outputs, 64-dot
    for (int o = w * 4 + g; o < 320; o += 64) {
      int s = o >> 6, c = o & 63;
      float4 wv = *reinterpret_cast<const float4*>(&Wol[c * 64 + q * 4]);
      float4 xv = *reinterpret_cast<const float4*>(&aob[s][q * 4]);
      float p = wv.x * xv.x + wv.y * xv.y + wv.z * xv.z + wv.w * xv.w;
      p = grp16_reduce(p);
      if (q == 0) tmp[s][c] = seq[s][c] + p + bol[c];
    }
    __syncthreads();

    // LN1: wave-per-row
    if (w < 5) {
      float v = tmp[w][l];
      float s1 = v, s2 = v * v;
#pragma unroll
      for (int off = 1; off < 64; off <<= 1) {
        s1 += __shfl_xor(s1, off, 64);
        s2 += __shfl_xor(s2, off, 64);
      }
      float m = s1 * (1.f / 64.f);
      float var = s2 * (1.f / 64.f) - m * m;
      float inv = 1.f / sqrtf(var + 1e-5f);
      seq[w][l] = (v - m) * inv * w1[l] + bb1[l];
    }
    __syncthreads();

    // FF1: 640 outputs, 64-dot, ReLU
    for (int o = w * 4 + g; o < 640; o += 64) {
      int s = o >> 7, j = o & 127;
      float4 wv = *reinterpret_cast<const float4*>(&Wf1[j * 64 + q * 4]);
      float4 xv = *reinterpret_cast<const float4*>(&seq[s][q * 4]);
      float p = wv.x * xv.x + wv.y * xv.y + wv.z * xv.z + wv.w * xv.w;
      p = grp16_reduce(p);
      if (q == 0) ffb[s][j] = fmaxf(p + bf1[j], 0.f);
    }
    __syncthreads();

    // FF2 + residual: 320 outputs, 128-dot (8 elems / lane)
    for (int o = w * 4 + g; o < 320; o += 64) {
      int s = o >> 6, c = o & 63;
      float4 wa = *reinterpret_cast<const float4*>(&Wf2[c * 128 + q * 8]);
      float4 wb = *reinterpret_cast<const float4*>(&Wf2[c * 128 + q * 8 + 4]);
      float4 xa = *reinterpret_cast<const float4*>(&ffb[s][q * 8]);
      float4 xb = *reinterpret_cast<const float4*>(&ffb[s][q * 8 + 4]);
      float p = wa.x * xa.x + wa.y * xa.y + wa.z * xa.z + wa.w * xa.w
              + wb.x * xb.x + wb.y * xb.y + wb.z * xb.z + wb.w * xb.w;
      p = grp16_reduce(p);
      if (q == 0) tmp[s][c] = seq[s][c] + p + bf2[c];
    }
    __syncthreads();

    // LN2: wave-per-row
    if (w < 5) {
      float v = tmp[w][l];
      float s1 = v, s2 = v * v;
#pragma unroll
      for (int off = 1; off < 64; off <<= 1) {
        s1 += __shfl_xor(s1, off, 64);
        s2 += __shfl_xor(s2, off, 64);
      }
      float m = s1 * (1.f / 64.f);
      float var = s2 * (1.f / 64.f) - m * m;
      float inv = 1.f / sqrtf(var + 1e-5f);
      seq[w][l] = (v - m) * inv * w2[l] + bb2[l];
    }
    __syncthreads();
  }

  // head layer 1: 32 outputs, 64-dot, ReLU
  for (int o = w * 4 + g; o < 32; o += 64) {
    float4 wv = *reinterpret_cast<const float4*>(&Wh1[o * 64 + q * 4]);
    float4 xv = *reinterpret_cast<const float4*>(&seq[4][q * 4]);
    float p = wv.x * xv.x + wv.y * xv.y + wv.z * xv.z + wv.w * xv.w;
    p = grp16_reduce(p);
    if (q == 0) hid[o] = fmaxf(p + bh1[o], 0.f);
  }
  __syncthreads();
  if (t < 2) {
    float acc = bh2[t];
    for (int j = 0; j < 32; j++) acc = fmaf(hid[j], Wh2[t * 32 + j], acc);
    out[t] = acc;
  }
}

extern "C" void kernel_launch(void* const* d_in, const int* in_sizes, int n_in,
                              void* d_out, int out_size, void* d_ws, size_t ws_size,
                              hipStream_t stream) {
  const float* x     = (const float*)d_in[0];
  const int*   ei    = (const int*)d_in[1];
  const float* W1    = (const float*)d_in[2];
  const float* attS1 = (const float*)d_in[3];
  const float* attD1 = (const float*)d_in[4];
  const float* b1    = (const float*)d_in[5];
  const float* W2    = (const float*)d_in[6];
  const float* attS2 = (const float*)d_in[7];
  const float* attD2 = (const float*)d_in[8];
  const float* b2    = (const float*)d_in[9];
  const float* tWqkv = (const float*)d_in[10];
  const float* tbqkv = (const float*)d_in[11];
  const float* tWo   = (const float*)d_in[12];
  const float* tbo   = (const float*)d_in[13];
  const float* tln1w = (const float*)d_in[14];
  const float* tln1b = (const float*)d_in[15];
  const float* tWff1 = (const float*)d_in[16];
  const float* tbff1 = (const float*)d_in[17];
  const float* tWff2 = (const float*)d_in[18];
  const float* tbff2 = (const float*)d_in[19];
  const float* tln2w = (const float*)d_in[20];
  const float* tln2b = (const float*)d_in[21];
  const float* Wh1   = (const float*)d_in[22];
  const float* bh1   = (const float*)d_in[23];
  const float* Wh2   = (const float*)d_in[24];
  const float* bh2   = (const float*)d_in[25];
  float* out = (float*)d_out;

  // Batched (all 5 frames in one pass) needs ~157 MB; fall back to per-frame otherwise.
  auto need_bytes = [](int F) -> size_t {
    size_t NT = (size_t)F * NN_F, ET = (size_t)F * NE_F;
    size_t fl = NT * 64 * 2 + NT * 8 * 2 + NT * 2 + 320;
    size_t it = NT * 3 + 1 + 2048 + ET;
    return (fl + it) * 4;
  };
  const int F = (ws_size >= need_bytes(5)) ? 5 : 1;
  const int NT = F * NN_F, ET = F * NE_F;

  float* ws  = (float*)d_ws;
  float* h1  = ws;                          // NT*64  (h1; later reused as out2)
  float* acc = h1 + (size_t)NT * 64;        // NT*64  (out1; node2 in-place -> g)
  float* as1 = acc + (size_t)NT * 64;       // NT*8
  float* ad1 = as1 + (size_t)NT * 8;        // NT*8
  float* as2 = ad1 + (size_t)NT * 8;        // NT
  float* ad2 = as2 + NT;                    // NT
  float* emb = ad2 + NT;                    // 320
  int* deg    = (int*)(emb + 320);          // NT
  int* rowptr = deg + NT;                   // NT+1
  int* cur    = rowptr + NT + 1;            // NT
  int* bsum   = cur + NT;                   // <=1024
  int* boff   = bsum + 1024;                // <=1024
  int* csr    = boff + 1024;                // ET

  (void)hipMemsetAsync(emb, 0, 320 * sizeof(float), stream);

  const int nblk = (NT + 255) / 256;
  const int edgeBlocks = (ET + 255) / 256;
  const int aggBlocks = (NT * 64) / 256;
  const int nodeBlocks = 2048;

  for (int f0 = 0; f0 < 5; f0 += F) {
    const float* xf = x + (size_t)f0 * NN_F * 13;
    const int* eif  = ei + (size_t)f0 * 2 * NE_F;

    (void)hipMemsetAsync(deg, 0, NT * sizeof(int), stream);
    k_hist<<<edgeBlocks, 256, 0, stream>>>(eif, deg, F);
    k_scan1<<<nblk, 256, 0, stream>>>(deg, bsum, NT);
    k_scan2<<<1, 1024, 0, stream>>>(bsum, boff, nblk);
    k_scan3<<<nblk, 256, 0, stream>>>(deg, boff, rowptr, cur, NT, ET);
    k_scatter<<<edgeBlocks, 256, 0, stream>>>(eif, cur, csr, F);

    k_node1<<<nodeBlocks, 256, 0, stream>>>(xf, W1, attS1, attD1, h1, as1, ad1, NT);
    k_agg1<<<aggBlocks, 256, 0, stream>>>(rowptr, csr, h1, as1, ad1, acc, NT);
    k_node2<<<nodeBlocks, 256, 0, stream>>>(acc, b1, W2, attS2, attD2, acc, as2, ad2, NT);
    k_agg2<<<aggBlocks, 256, 0, stream>>>(rowptr, csr, acc, as2, ad2, h1, NT);
    k_reduce<<<F * 100, 256, 0, stream>>>(h1, emb + f0 * 64);
  }

  k_transformer<<<1, 1024, 0, stream>>>(emb, b2, tWqkv, tbqkv, tWo, tbo, tln1w, tln1b,
                                        tWff1, tbff1, tWff2, tbff2, tln2w, tln2b,
                                        Wh1, bh1, Wh2, bh2, out);
}

// Round 5
// 764.925 us; speedup vs baseline: 2.6722x; 1.3181x over previous
//
#include <hip/hip_runtime.h>
#include <math.h>

#define NN_F 50000      // nodes per frame
#define NE_F 400000     // edges per frame
#define BPF  512        // blocks per frame for fused agg2+mean

__device__ __forceinline__ float lrelu02(float x) { return x > 0.f ? x : 0.2f * x; }

// ---------------- GAT layer 1: wave per node, lane = output channel ----------------
__global__ void __launch_bounds__(256)
k_node1(const float* __restrict__ x, const float* __restrict__ W1,
        const float* __restrict__ attS, const float* __restrict__ attD,
        float* __restrict__ h1, float* __restrict__ as1, float* __restrict__ ad1,
        int nNodes) {
  int l = threadIdx.x & 63;
  int wid = (blockIdx.x * blockDim.x + threadIdx.x) >> 6;
  int nw = (gridDim.x * blockDim.x) >> 6;
  float w1r[13];
#pragma unroll
  for (int c = 0; c < 13; c++) w1r[c] = W1[l * 13 + c];
  float aS = attS[l], aD = attD[l];
  for (int n = wid; n < nNodes; n += nw) {
    float xv = (l < 13) ? x[(size_t)n * 13 + l] : 0.f;
    float acc = 0.f;
#pragma unroll
    for (int c = 0; c < 13; c++) acc = fmaf(__shfl(xv, c, 64), w1r[c], acc);
    h1[(size_t)n * 64 + l] = acc;
    float s = acc * aS, d = acc * aD;
#pragma unroll
    for (int off = 1; off < 8; off <<= 1) {
      s += __shfl_xor(s, off, 64);
      d += __shfl_xor(d, off, 64);
    }
    if ((l & 7) == 0) { as1[n * 8 + (l >> 3)] = s; ad1[n * 8 + (l >> 3)] = d; }
  }
}

// ---------------- CSR build: histogram by dst (batched frames) ----------------
__global__ void k_hist(const int* __restrict__ ei, int* __restrict__ deg, int nFrames) {
  int e = blockIdx.x * blockDim.x + threadIdx.x;
  if (e >= nFrames * NE_F) return;
  int f = e / NE_F, idx = e - f * NE_F;
  int dst = ei[(size_t)f * 2 * NE_F + NE_F + idx];
  atomicAdd(&deg[f * NN_F + dst], 1);
}

// ---------------- CSR build: per-block sums ----------------
__global__ void k_scan1(const int* __restrict__ deg, int* __restrict__ bsum, int nNodes) {
  __shared__ int part[256];
  int t = threadIdx.x;
  int i = blockIdx.x * 256 + t;
  part[t] = (i < nNodes) ? deg[i] : 0;
  __syncthreads();
  for (int off = 128; off > 0; off >>= 1) {
    if (t < off) part[t] += part[t + off];
    __syncthreads();
  }
  if (t == 0) bsum[blockIdx.x] = part[0];
}

// ---------------- CSR build: scan of block sums (single block, up to 1024) ----------------
__global__ void __launch_bounds__(1024)
k_scan2(const int* __restrict__ bsum, int* __restrict__ boff, int nblk) {
  __shared__ int part[1024];
  int t = threadIdx.x;
  part[t] = (t < nblk) ? bsum[t] : 0;
  __syncthreads();
  for (int off = 1; off < 1024; off <<= 1) {
    int v = (t >= off) ? part[t - off] : 0;
    __syncthreads();
    part[t] += v;
    __syncthreads();
  }
  if (t < nblk) boff[t] = part[t] - bsum[t];  // exclusive
}

// ---------------- CSR build: intra-block scan -> rowptr & cursor ----------------
__global__ void k_scan3(const int* __restrict__ deg, const int* __restrict__ boff,
                        int* __restrict__ rowptr, int* __restrict__ cur,
                        int nNodes, int nEdges) {
  __shared__ int part[256];
  int t = threadIdx.x;
  int i = blockIdx.x * 256 + t;
  int d = (i < nNodes) ? deg[i] : 0;
  part[t] = d;
  __syncthreads();
  for (int off = 1; off < 256; off <<= 1) {
    int v = (t >= off) ? part[t - off] : 0;
    __syncthreads();
    part[t] += v;
    __syncthreads();
  }
  if (i < nNodes) {
    int r = boff[blockIdx.x] + part[t] - d;  // exclusive prefix
    rowptr[i] = r;
    cur[i] = r;
  }
  if (blockIdx.x == 0 && t == 0) rowptr[nNodes] = nEdges;
}

// ---------------- CSR build: scatter GLOBAL src ids by dst ----------------
__global__ void k_scatter(const int* __restrict__ ei, int* __restrict__ cur,
                          int* __restrict__ csr, int nFrames) {
  int e = blockIdx.x * blockDim.x + threadIdx.x;
  if (e >= nFrames * NE_F) return;
  int f = e / NE_F, idx = e - f * NE_F;
  const int* base = ei + (size_t)f * 2 * NE_F;
  int src = base[idx], dst = base[NE_F + idx];
  int pos = atomicAdd(&cur[f * NN_F + dst], 1);
  csr[pos] = f * NN_F + src;
}

// ---- GAT layer 1 aggregation: wave per dst, 8 edge-groups x 8 lanes (head = q) ----
__global__ void __launch_bounds__(256)
k_agg1(const int* __restrict__ rowptr, const int* __restrict__ csr,
       const float* __restrict__ h1, const float* __restrict__ as1,
       const float* __restrict__ ad1, float* __restrict__ out1, int nNodes) {
  int wid = (blockIdx.x * blockDim.x + threadIdx.x) >> 6;
  if (wid >= nNodes) return;
  int l = threadIdx.x & 63;
  int g = l >> 3, q = l & 7;          // group g handles edges i%8==g; lane q owns head q
  size_t nb = (size_t)wid * 64 + q * 8;
  float adv = ad1[wid * 8 + q];
  float a0, a1, a2, a3, a4, a5, a6, a7, den;
  if (g == 0) {
    float e0 = expf(lrelu02(as1[wid * 8 + q] + adv));
    float4 v0 = *reinterpret_cast<const float4*>(&h1[nb]);
    float4 v1 = *reinterpret_cast<const float4*>(&h1[nb + 4]);
    a0 = e0 * v0.x; a1 = e0 * v0.y; a2 = e0 * v0.z; a3 = e0 * v0.w;
    a4 = e0 * v1.x; a5 = e0 * v1.y; a6 = e0 * v1.z; a7 = e0 * v1.w;
    den = e0;
  } else {
    a0 = a1 = a2 = a3 = a4 = a5 = a6 = a7 = 0.f; den = 0.f;
  }
  int s0 = rowptr[wid], s1 = rowptr[wid + 1];
  for (int i = s0 + g; i < s1; i += 8) {
    int src = csr[i];
    float e2 = expf(lrelu02(as1[src * 8 + q] + adv));
    size_t sb = (size_t)src * 64 + q * 8;
    float4 v0 = *reinterpret_cast<const float4*>(&h1[sb]);
    float4 v1 = *reinterpret_cast<const float4*>(&h1[sb + 4]);
    a0 = fmaf(e2, v0.x, a0); a1 = fmaf(e2, v0.y, a1);
    a2 = fmaf(e2, v0.z, a2); a3 = fmaf(e2, v0.w, a3);
    a4 = fmaf(e2, v1.x, a4); a5 = fmaf(e2, v1.y, a5);
    a6 = fmaf(e2, v1.z, a6); a7 = fmaf(e2, v1.w, a7);
    den += e2;
  }
#pragma unroll
  for (int off = 8; off <= 32; off <<= 1) {
    a0 += __shfl_xor(a0, off, 64); a1 += __shfl_xor(a1, off, 64);
    a2 += __shfl_xor(a2, off, 64); a3 += __shfl_xor(a3, off, 64);
    a4 += __shfl_xor(a4, off, 64); a5 += __shfl_xor(a5, off, 64);
    a6 += __shfl_xor(a6, off, 64); a7 += __shfl_xor(a7, off, 64);
    den += __shfl_xor(den, off, 64);
  }
  if (g == 0) {
    float inv = 1.f / den;
    float4 r0 = make_float4(a0 * inv, a1 * inv, a2 * inv, a3 * inv);
    float4 r1 = make_float4(a4 * inv, a5 * inv, a6 * inv, a7 * inv);
    *reinterpret_cast<float4*>(&out1[nb]) = r0;
    *reinterpret_cast<float4*>(&out1[nb + 4]) = r1;
  }
}

// ---------------- bias + ELU + GAT2 linear (in-place safe) + att feats ----------------
__global__ void __launch_bounds__(256, 4)
k_node2(const float* __restrict__ out1, const float* __restrict__ b1,
        const float* __restrict__ W2, const float* __restrict__ attS2,
        const float* __restrict__ attD2, float* __restrict__ g,
        float* __restrict__ as2, float* __restrict__ ad2, int nNodes) {
  int l = threadIdx.x & 63;
  int wid = (blockIdx.x * blockDim.x + threadIdx.x) >> 6;
  int nw = (gridDim.x * blockDim.x) >> 6;
  float w[64];
#pragma unroll
  for (int c4 = 0; c4 < 16; c4++) {
    float4 v = *reinterpret_cast<const float4*>(&W2[l * 64 + c4 * 4]);
    w[c4 * 4 + 0] = v.x; w[c4 * 4 + 1] = v.y; w[c4 * 4 + 2] = v.z; w[c4 * 4 + 3] = v.w;
  }
  float aS = attS2[l], aD = attD2[l], bb = b1[l];
  for (int n = wid; n < nNodes; n += nw) {
    float v = out1[(size_t)n * 64 + l] + bb;
    float hh = v > 0.f ? v : expm1f(v);
    float acc = 0.f;
#pragma unroll
    for (int c = 0; c < 64; c++) acc = fmaf(__shfl(hh, c, 64), w[c], acc);
    g[(size_t)n * 64 + l] = acc;     // in-place over out1 is safe: lane reads only its own elem
    float s2 = acc * aS, d2 = acc * aD;
#pragma unroll
    for (int off = 32; off > 0; off >>= 1) {
      s2 += __shfl_xor(s2, off, 64);
      d2 += __shfl_xor(d2, off, 64);
    }
    if (l == 0) { as2[n] = s2; ad2[n] = d2; }
  }
}

// ---- GAT layer 2 aggregation FUSED with frame mean: 8 edge-groups x 8 lanes ----
__global__ void __launch_bounds__(256)
k_agg2mean(const int* __restrict__ rowptr, const int* __restrict__ csr,
           const float* __restrict__ gtab, const float* __restrict__ as2,
           const float* __restrict__ ad2, float* __restrict__ emb) {
  __shared__ float part[4][64];
  int t = threadIdx.x;
  int w = t >> 6, l = t & 63;
  int g = l >> 3, q = l & 7;
  int f = blockIdx.x / BPF;
  int wf = (blockIdx.x - f * BPF) * 4 + w;        // wave id within frame [0, BPF*4)
  float m0 = 0.f, m1 = 0.f, m2 = 0.f, m3 = 0.f, m4 = 0.f, m5 = 0.f, m6 = 0.f, m7 = 0.f;
  for (int j = wf; j < NN_F; j += BPF * 4) {
    int n = f * NN_F + j;
    size_t nb = (size_t)n * 64 + q * 8;
    float adv = ad2[n];
    float a0, a1, a2, a3, a4, a5, a6, a7, den;
    if (g == 0) {
      float e0 = expf(lrelu02(as2[n] + adv));
      float4 v0 = *reinterpret_cast<const float4*>(&gtab[nb]);
      float4 v1 = *reinterpret_cast<const float4*>(&gtab[nb + 4]);
      a0 = e0 * v0.x; a1 = e0 * v0.y; a2 = e0 * v0.z; a3 = e0 * v0.w;
      a4 = e0 * v1.x; a5 = e0 * v1.y; a6 = e0 * v1.z; a7 = e0 * v1.w;
      den = e0;
    } else {
      a0 = a1 = a2 = a3 = a4 = a5 = a6 = a7 = 0.f; den = 0.f;
    }
    int s0 = rowptr[n], s1 = rowptr[n + 1];
    for (int i = s0 + g; i < s1; i += 8) {
      int src = csr[i];
      float e2 = expf(lrelu02(as2[src] + adv));
      size_t sb = (size_t)src * 64 + q * 8;
      float4 v0 = *reinterpret_cast<const float4*>(&gtab[sb]);
      float4 v1 = *reinterpret_cast<const float4*>(&gtab[sb + 4]);
      a0 = fmaf(e2, v0.x, a0); a1 = fmaf(e2, v0.y, a1);
      a2 = fmaf(e2, v0.z, a2); a3 = fmaf(e2, v0.w, a3);
      a4 = fmaf(e2, v1.x, a4); a5 = fmaf(e2, v1.y, a5);
      a6 = fmaf(e2, v1.z, a6); a7 = fmaf(e2, v1.w, a7);
      den += e2;
    }
#pragma unroll
    for (int off = 8; off <= 32; off <<= 1) {
      a0 += __shfl_xor(a0, off, 64); a1 += __shfl_xor(a1, off, 64);
      a2 += __shfl_xor(a2, off, 64); a3 += __shfl_xor(a3, off, 64);
      a4 += __shfl_xor(a4, off, 64); a5 += __shfl_xor(a5, off, 64);
      a6 += __shfl_xor(a6, off, 64); a7 += __shfl_xor(a7, off, 64);
      den += __shfl_xor(den, off, 64);
    }
    float inv = 1.f / den;
    m0 = fmaf(a0, inv, m0); m1 = fmaf(a1, inv, m1);
    m2 = fmaf(a2, inv, m2); m3 = fmaf(a3, inv, m3);
    m4 = fmaf(a4, inv, m4); m5 = fmaf(a5, inv, m5);
    m6 = fmaf(a6, inv, m6); m7 = fmaf(a7, inv, m7);
  }
  if (g == 0) {
    part[w][q * 8 + 0] = m0; part[w][q * 8 + 1] = m1;
    part[w][q * 8 + 2] = m2; part[w][q * 8 + 3] = m3;
    part[w][q * 8 + 4] = m4; part[w][q * 8 + 5] = m5;
    part[w][q * 8 + 6] = m6; part[w][q * 8 + 7] = m7;
  }
  __syncthreads();
  if (w == 0)
    atomicAdd(&emb[f * 64 + l],
              (part[0][l] + part[1][l] + part[2][l] + part[3][l]) * (1.0f / NN_F));
}

// ---------------- tiny transformer: 1024 threads, 16-lane-group shuffle GEMVs ----------
__device__ __forceinline__ float grp16_reduce(float p) {
#pragma unroll
  for (int off = 1; off < 16; off <<= 1) p += __shfl_xor(p, off, 64);
  return p;
}

__global__ void __launch_bounds__(1024)
k_transformer(const float* __restrict__ emb, const float* __restrict__ b2,
              const float* __restrict__ Wqkv, const float* __restrict__ bqkv,
              const float* __restrict__ Wo, const float* __restrict__ bo,
              const float* __restrict__ ln1w, const float* __restrict__ ln1b,
              const float* __restrict__ Wff1, const float* __restrict__ bff1,
              const float* __restrict__ Wff2, const float* __restrict__ bff2,
              const float* __restrict__ ln2w, const float* __restrict__ ln2b,
              const float* __restrict__ Wh1, const float* __restrict__ bh1,
              const float* __restrict__ Wh2, const float* __restrict__ bh2,
              float* __restrict__ out) {
  __shared__ float seq[5][64];
  __shared__ float qkv[5][192];
  __shared__ float att[4][5][5];
  __shared__ float aob[5][64];
  __shared__ float ffb[5][128];
  __shared__ float tmp[5][64];
  __shared__ float hid[32];
  int t = threadIdx.x;
  int l = t & 63, w = t >> 6;        // 16 waves
  int g = l >> 4, q = l & 15;        // 4 groups of 16 lanes

  if (t < 320) seq[t >> 6][t & 63] = emb[t] + b2[t & 63];
  __syncthreads();

  for (int ly = 0; ly < 3; ly++) {
    const float* Wq  = Wqkv + ly * 12288; const float* bq  = bqkv + ly * 192;
    const float* Wol = Wo   + ly * 4096;  const float* bol = bo   + ly * 64;
    const float* w1  = ln1w + ly * 64;    const float* bb1 = ln1b + ly * 64;
    const float* Wf1 = Wff1 + ly * 8192;  const float* bf1 = bff1 + ly * 128;
    const float* Wf2 = Wff2 + ly * 8192;  const float* bf2 = bff2 + ly * 64;
    const float* w2  = ln2w + ly * 64;    const float* bb2 = ln2b + ly * 64;

    for (int o = w * 4 + g; o < 960; o += 64) {
      int s = o / 192, j = o - s * 192;
      float4 wv = *reinterpret_cast<const float4*>(&Wq[j * 64 + q * 4]);
      float4 xv = *reinterpret_cast<const float4*>(&seq[s][q * 4]);
      float p = wv.x * xv.x + wv.y * xv.y + wv.z * xv.z + wv.w * xv.w;
      p = grp16_reduce(p);
      if (q == 0) qkv[s][j] = p + bq[j];
    }
    __syncthreads();

    if (t < 100) {
      int hh = t / 25, qs = (t / 5) % 5, ks = t % 5;
      float acc = 0.f;
      for (int d = 0; d < 16; d++)
        acc = fmaf(qkv[qs][hh * 16 + d], qkv[ks][64 + hh * 16 + d], acc);
      att[hh][qs][ks] = acc * 0.25f;
    }
    __syncthreads();
    if (t < 20) {
      int hh = t / 5, qs = t % 5;
      float m = att[hh][qs][0];
      for (int k2 = 1; k2 < 5; k2++) m = fmaxf(m, att[hh][qs][k2]);
      float ss = 0.f;
      for (int k2 = 0; k2 < 5; k2++) { float v = expf(att[hh][qs][k2] - m); att[hh][qs][k2] = v; ss += v; }
      float inv = 1.f / ss;
      for (int k2 = 0; k2 < 5; k2++) att[hh][qs][k2] *= inv;
    }
    __syncthreads();

    if (t < 320) {
      int s = t >> 6, j = t & 63, hh = j >> 4;
      float acc = 0.f;
      for (int k2 = 0; k2 < 5; k2++) acc = fmaf(att[hh][s][k2], qkv[k2][128 + j], acc);
      aob[s][j] = acc;
    }
    __syncthreads();

    for (int o = w * 4 + g; o < 320; o += 64) {
      int s = o >> 6, c = o & 63;
      float4 wv = *reinterpret_cast<const float4*>(&Wol[c * 64 + q * 4]);
      float4 xv = *reinterpret_cast<const float4*>(&aob[s][q * 4]);
      float p = wv.x * xv.x + wv.y * xv.y + wv.z * xv.z + wv.w * xv.w;
      p = grp16_reduce(p);
      if (q == 0) tmp[s][c] = seq[s][c] + p + bol[c];
    }
    __syncthreads();

    if (w < 5) {
      float v = tmp[w][l];
      float s1 = v, s2 = v * v;
#pragma unroll
      for (int off = 1; off < 64; off <<= 1) {
        s1 += __shfl_xor(s1, off, 64);
        s2 += __shfl_xor(s2, off, 64);
      }
      float m = s1 * (1.f / 64.f);
      float var = s2 * (1.f / 64.f) - m * m;
      float inv = 1.f / sqrtf(var + 1e-5f);
      seq[w][l] = (v - m) * inv * w1[l] + bb1[l];
    }
    __syncthreads();

    for (int o = w * 4 + g; o < 640; o += 64) {
      int s = o >> 7, j = o & 127;
      float4 wv = *reinterpret_cast<const float4*>(&Wf1[j * 64 + q * 4]);
      float4 xv = *reinterpret_cast<const float4*>(&seq[s][q * 4]);
      float p = wv.x * xv.x + wv.y * xv.y + wv.z * xv.z + wv.w * xv.w;
      p = grp16_reduce(p);
      if (q == 0) ffb[s][j] = fmaxf(p + bf1[j], 0.f);
    }
    __syncthreads();

    for (int o = w * 4 + g; o < 320; o += 64) {
      int s = o >> 6, c = o & 63;
      float4 wa = *reinterpret_cast<const float4*>(&Wf2[c * 128 + q * 8]);
      float4 wb = *reinterpret_cast<const float4*>(&Wf2[c * 128 + q * 8 + 4]);
      float4 xa = *reinterpret_cast<const float4*>(&ffb[s][q * 8]);
      float4 xb = *reinterpret_cast<const float4*>(&ffb[s][q * 8 + 4]);
      float p = wa.x * xa.x + wa.y * xa.y + wa.z * xa.z + wa.w * xa.w
              + wb.x * xb.x + wb.y * xb.y + wb.z * xb.z + wb.w * xb.w;
      p = grp16_reduce(p);
      if (q == 0) tmp[s][c] = seq[s][c] + p + bf2[c];
    }
    __syncthreads();

    if (w < 5) {
      float v = tmp[w][l];
      float s1 = v, s2 = v * v;
#pragma unroll
      for (int off = 1; off < 64; off <<= 1) {
        s1 += __shfl_xor(s1, off, 64);
        s2 += __shfl_xor(s2, off, 64);
      }
      float m = s1 * (1.f / 64.f);
      float var = s2 * (1.f / 64.f) - m * m;
      float inv = 1.f / sqrtf(var + 1e-5f);
      seq[w][l] = (v - m) * inv * w2[l] + bb2[l];
    }
    __syncthreads();
  }

  for (int o = w * 4 + g; o < 32; o += 64) {
    float4 wv = *reinterpret_cast<const float4*>(&Wh1[o * 64 + q * 4]);
    float4 xv = *reinterpret_cast<const float4*>(&seq[4][q * 4]);
    float p = wv.x * xv.x + wv.y * xv.y + wv.z * xv.z + wv.w * xv.w;
    p = grp16_reduce(p);
    if (q == 0) hid[o] = fmaxf(p + bh1[o], 0.f);
  }
  __syncthreads();
  if (t < 2) {
    float acc = bh2[t];
    for (int j = 0; j < 32; j++) acc = fmaf(hid[j], Wh2[t * 32 + j], acc);
    out[t] = acc;
  }
}

extern "C" void kernel_launch(void* const* d_in, const int* in_sizes, int n_in,
                              void* d_out, int out_size, void* d_ws, size_t ws_size,
                              hipStream_t stream) {
  const float* x     = (const float*)d_in[0];
  const int*   ei    = (const int*)d_in[1];
  const float* W1    = (const float*)d_in[2];
  const float* attS1 = (const float*)d_in[3];
  const float* attD1 = (const float*)d_in[4];
  const float* b1    = (const float*)d_in[5];
  const float* W2    = (const float*)d_in[6];
  const float* attS2 = (const float*)d_in[7];
  const float* attD2 = (const float*)d_in[8];
  const float* b2    = (const float*)d_in[9];
  const float* tWqkv = (const float*)d_in[10];
  const float* tbqkv = (const float*)d_in[11];
  const float* tWo   = (const float*)d_in[12];
  const float* tbo   = (const float*)d_in[13];
  const float* tln1w = (const float*)d_in[14];
  const float* tln1b = (const float*)d_in[15];
  const float* tWff1 = (const float*)d_in[16];
  const float* tbff1 = (const float*)d_in[17];
  const float* tWff2 = (const float*)d_in[18];
  const float* tbff2 = (const float*)d_in[19];
  const float* tln2w = (const float*)d_in[20];
  const float* tln2b = (const float*)d_in[21];
  const float* Wh1   = (const float*)d_in[22];
  const float* bh1   = (const float*)d_in[23];
  const float* Wh2   = (const float*)d_in[24];
  const float* bh2   = (const float*)d_in[25];
  float* out = (float*)d_out;

  auto need_bytes = [](int F) -> size_t {
    size_t NT = (size_t)F * NN_F, ET = (size_t)F * NE_F;
    size_t fl = NT * 64 * 2 + NT * 8 * 2 + NT * 2 + 320;
    size_t it = NT * 3 + 1 + 2048 + ET;
    return (fl + it) * 4;
  };
  const int F = (ws_size >= need_bytes(5)) ? 5 : 1;
  const int NT = F * NN_F, ET = F * NE_F;

  float* ws  = (float*)d_ws;
  float* h1  = ws;                          // NT*64
  float* acc = h1 + (size_t)NT * 64;        // NT*64  (out1; node2 in-place -> g)
  float* as1 = acc + (size_t)NT * 64;       // NT*8
  float* ad1 = as1 + (size_t)NT * 8;        // NT*8
  float* as2 = ad1 + (size_t)NT * 8;        // NT
  float* ad2 = as2 + NT;                    // NT
  float* emb = ad2 + NT;                    // 320
  int* deg    = (int*)(emb + 320);          // NT
  int* rowptr = deg + NT;                   // NT+1
  int* cur    = rowptr + NT + 1;            // NT
  int* bsum   = cur + NT;                   // <=1024
  int* boff   = bsum + 1024;                // <=1024
  int* csr    = boff + 1024;                // ET

  (void)hipMemsetAsync(emb, 0, 320 * sizeof(float), stream);

  const int nblk = (NT + 255) / 256;
  const int edgeBlocks = (ET + 255) / 256;
  const int aggBlocks = (NT + 3) / 4;       // wave per node, 4 waves/block
  const int nodeBlocks = 2048;

  for (int f0 = 0; f0 < 5; f0 += F) {
    const float* xf = x + (size_t)f0 * NN_F * 13;
    const int* eif  = ei + (size_t)f0 * 2 * NE_F;

    (void)hipMemsetAsync(deg, 0, NT * sizeof(int), stream);
    k_hist<<<edgeBlocks, 256, 0, stream>>>(eif, deg, F);
    k_scan1<<<nblk, 256, 0, stream>>>(deg, bsum, NT);
    k_scan2<<<1, 1024, 0, stream>>>(bsum, boff, nblk);
    k_scan3<<<nblk, 256, 0, stream>>>(deg, boff, rowptr, cur, NT, ET);
    k_scatter<<<edgeBlocks, 256, 0, stream>>>(eif, cur, csr, F);

    k_node1<<<nodeBlocks, 256, 0, stream>>>(xf, W1, attS1, attD1, h1, as1, ad1, NT);
    k_agg1<<<aggBlocks, 256, 0, stream>>>(rowptr, csr, h1, as1, ad1, acc, NT);
    k_node2<<<nodeBlocks, 256, 0, stream>>>(acc, b1, W2, attS2, attD2, acc, as2, ad2, NT);
    // fused agg2 + frame mean (emb accumulated via atomics; zeroed above)
    k_agg2mean<<<F * BPF, 256, 0, stream>>>(rowptr, csr, acc, as2, ad2, emb + f0 * 64);
  }

  k_transformer<<<1, 1024, 0, stream>>>(emb, b2, tWqkv, tbqkv, tWo, tbo, tln1w, tln1b,
                                        tWff1, tbff1, tWff2, tbff2, tln2w, tln2b,
                                        Wh1, bh1, Wh2, bh2, out);
}

// Round 6
// 620.327 us; speedup vs baseline: 3.2951x; 1.2331x over previous
//
#include <hip/hip_runtime.h>
#include <math.h>

#define NN_F 50000      // nodes per frame
#define NE_F 400000     // edges per frame
#define BPF  512        // blocks per frame for fused agg2+mean

__device__ __forceinline__ float lrelu02(float x) { return x > 0.f ? x : 0.2f * x; }

// ---------------- GAT layer 1: wave per node, lane = output channel ----------------
// x-row broadcast via per-wave LDS buffer (uniform-address float4 reads, 0-padded to 16)
__global__ void __launch_bounds__(256, 3)
k_node1(const float* __restrict__ x, const float* __restrict__ W1,
        const float* __restrict__ attS, const float* __restrict__ attD,
        float* __restrict__ h1, float* __restrict__ as1, float* __restrict__ ad1,
        int nNodes) {
  __shared__ float xbuf[4][16];
  int l = threadIdx.x & 63;
  int w = threadIdx.x >> 6;
  int wid = (blockIdx.x * blockDim.x + threadIdx.x) >> 6;
  int nw = (gridDim.x * blockDim.x) >> 6;
  // W1 row l in named registers, padded to 16 with zeros
  float4 wA = make_float4(W1[l * 13 + 0], W1[l * 13 + 1], W1[l * 13 + 2], W1[l * 13 + 3]);
  float4 wB = make_float4(W1[l * 13 + 4], W1[l * 13 + 5], W1[l * 13 + 6], W1[l * 13 + 7]);
  float4 wC = make_float4(W1[l * 13 + 8], W1[l * 13 + 9], W1[l * 13 + 10], W1[l * 13 + 11]);
  float4 wD = make_float4(W1[l * 13 + 12], 0.f, 0.f, 0.f);
  float aS = attS[l], aD = attD[l];
  const float4* xb = reinterpret_cast<const float4*>(xbuf[w]);
  for (int n = wid; n < nNodes; n += nw) {
    if (l < 16) xbuf[w][l] = (l < 13) ? x[(size_t)n * 13 + l] : 0.f;
    float4 x0 = xb[0], x1 = xb[1], x2 = xb[2], x3 = xb[3];
    float a0 = x0.x * wA.x, a1 = x0.y * wA.y, a2 = x0.z * wA.z, a3 = x0.w * wA.w;
    a0 = fmaf(x1.x, wB.x, a0); a1 = fmaf(x1.y, wB.y, a1);
    a2 = fmaf(x1.z, wB.z, a2); a3 = fmaf(x1.w, wB.w, a3);
    a0 = fmaf(x2.x, wC.x, a0); a1 = fmaf(x2.y, wC.y, a1);
    a2 = fmaf(x2.z, wC.z, a2); a3 = fmaf(x2.w, wC.w, a3);
    a0 = fmaf(x3.x, wD.x, a0);
    float acc = (a0 + a1) + (a2 + a3);
    h1[(size_t)n * 64 + l] = acc;
    float s = acc * aS, d = acc * aD;
#pragma unroll
    for (int off = 1; off < 8; off <<= 1) {
      s += __shfl_xor(s, off, 64);
      d += __shfl_xor(d, off, 64);
    }
    if ((l & 7) == 0) { as1[n * 8 + (l >> 3)] = s; ad1[n * 8 + (l >> 3)] = d; }
  }
}

// ---------------- CSR build: histogram by dst (batched frames) ----------------
__global__ void k_hist(const int* __restrict__ ei, int* __restrict__ deg, int nFrames) {
  int e = blockIdx.x * blockDim.x + threadIdx.x;
  if (e >= nFrames * NE_F) return;
  int f = e / NE_F, idx = e - f * NE_F;
  int dst = ei[(size_t)f * 2 * NE_F + NE_F + idx];
  atomicAdd(&deg[f * NN_F + dst], 1);
}

// ---------------- CSR build: per-block sums ----------------
__global__ void k_scan1(const int* __restrict__ deg, int* __restrict__ bsum, int nNodes) {
  __shared__ int part[256];
  int t = threadIdx.x;
  int i = blockIdx.x * 256 + t;
  part[t] = (i < nNodes) ? deg[i] : 0;
  __syncthreads();
  for (int off = 128; off > 0; off >>= 1) {
    if (t < off) part[t] += part[t + off];
    __syncthreads();
  }
  if (t == 0) bsum[blockIdx.x] = part[0];
}

// ---------------- CSR build: scan of block sums (single block, up to 1024) ----------------
__global__ void __launch_bounds__(1024)
k_scan2(const int* __restrict__ bsum, int* __restrict__ boff, int nblk) {
  __shared__ int part[1024];
  int t = threadIdx.x;
  part[t] = (t < nblk) ? bsum[t] : 0;
  __syncthreads();
  for (int off = 1; off < 1024; off <<= 1) {
    int v = (t >= off) ? part[t - off] : 0;
    __syncthreads();
    part[t] += v;
    __syncthreads();
  }
  if (t < nblk) boff[t] = part[t] - bsum[t];  // exclusive
}

// ---------------- CSR build: intra-block scan -> rowptr & cursor ----------------
__global__ void k_scan3(const int* __restrict__ deg, const int* __restrict__ boff,
                        int* __restrict__ rowptr, int* __restrict__ cur,
                        int nNodes, int nEdges) {
  __shared__ int part[256];
  int t = threadIdx.x;
  int i = blockIdx.x * 256 + t;
  int d = (i < nNodes) ? deg[i] : 0;
  part[t] = d;
  __syncthreads();
  for (int off = 1; off < 256; off <<= 1) {
    int v = (t >= off) ? part[t - off] : 0;
    __syncthreads();
    part[t] += v;
    __syncthreads();
  }
  if (i < nNodes) {
    int r = boff[blockIdx.x] + part[t] - d;  // exclusive prefix
    rowptr[i] = r;
    cur[i] = r;
  }
  if (blockIdx.x == 0 && t == 0) rowptr[nNodes] = nEdges;
}

// ---------------- CSR build: scatter GLOBAL src ids by dst ----------------
__global__ void k_scatter(const int* __restrict__ ei, int* __restrict__ cur,
                          int* __restrict__ csr, int nFrames) {
  int e = blockIdx.x * blockDim.x + threadIdx.x;
  if (e >= nFrames * NE_F) return;
  int f = e / NE_F, idx = e - f * NE_F;
  const int* base = ei + (size_t)f * 2 * NE_F;
  int src = base[idx], dst = base[NE_F + idx];
  int pos = atomicAdd(&cur[f * NN_F + dst], 1);
  csr[pos] = f * NN_F + src;
}

// ---- GAT layer 1 aggregation: wave per dst, 8 edge-groups x 8 lanes (head = q) ----
__global__ void __launch_bounds__(256)
k_agg1(const int* __restrict__ rowptr, const int* __restrict__ csr,
       const float* __restrict__ h1, const float* __restrict__ as1,
       const float* __restrict__ ad1, float* __restrict__ out1, int nNodes) {
  int wid = (blockIdx.x * blockDim.x + threadIdx.x) >> 6;
  if (wid >= nNodes) return;
  int l = threadIdx.x & 63;
  int g = l >> 3, q = l & 7;          // group g handles edges i%8==g; lane q owns head q
  size_t nb = (size_t)wid * 64 + q * 8;
  float adv = ad1[wid * 8 + q];
  float a0, a1, a2, a3, a4, a5, a6, a7, den;
  if (g == 0) {
    float e0 = expf(lrelu02(as1[wid * 8 + q] + adv));
    float4 v0 = *reinterpret_cast<const float4*>(&h1[nb]);
    float4 v1 = *reinterpret_cast<const float4*>(&h1[nb + 4]);
    a0 = e0 * v0.x; a1 = e0 * v0.y; a2 = e0 * v0.z; a3 = e0 * v0.w;
    a4 = e0 * v1.x; a5 = e0 * v1.y; a6 = e0 * v1.z; a7 = e0 * v1.w;
    den = e0;
  } else {
    a0 = a1 = a2 = a3 = a4 = a5 = a6 = a7 = 0.f; den = 0.f;
  }
  int s0 = rowptr[wid], s1 = rowptr[wid + 1];
  for (int i = s0 + g; i < s1; i += 8) {
    int src = csr[i];
    float e2 = expf(lrelu02(as1[src * 8 + q] + adv));
    size_t sb = (size_t)src * 64 + q * 8;
    float4 v0 = *reinterpret_cast<const float4*>(&h1[sb]);
    float4 v1 = *reinterpret_cast<const float4*>(&h1[sb + 4]);
    a0 = fmaf(e2, v0.x, a0); a1 = fmaf(e2, v0.y, a1);
    a2 = fmaf(e2, v0.z, a2); a3 = fmaf(e2, v0.w, a3);
    a4 = fmaf(e2, v1.x, a4); a5 = fmaf(e2, v1.y, a5);
    a6 = fmaf(e2, v1.z, a6); a7 = fmaf(e2, v1.w, a7);
    den += e2;
  }
#pragma unroll
  for (int off = 8; off <= 32; off <<= 1) {
    a0 += __shfl_xor(a0, off, 64); a1 += __shfl_xor(a1, off, 64);
    a2 += __shfl_xor(a2, off, 64); a3 += __shfl_xor(a3, off, 64);
    a4 += __shfl_xor(a4, off, 64); a5 += __shfl_xor(a5, off, 64);
    a6 += __shfl_xor(a6, off, 64); a7 += __shfl_xor(a7, off, 64);
    den += __shfl_xor(den, off, 64);
  }
  if (g == 0) {
    float inv = 1.f / den;
    float4 r0 = make_float4(a0 * inv, a1 * inv, a2 * inv, a3 * inv);
    float4 r1 = make_float4(a4 * inv, a5 * inv, a6 * inv, a7 * inv);
    *reinterpret_cast<float4*>(&out1[nb]) = r0;
    *reinterpret_cast<float4*>(&out1[nb + 4]) = r1;
  }
}

// ---------------- bias + ELU + GAT2 linear (in-place safe) + att feats ----------------
// W2 row in 16 named float4 registers; h2 broadcast via per-wave LDS buffer
// (16 uniform ds_read_b128 per node, 4 independent FMA chains).
__global__ void __launch_bounds__(256, 3)
k_node2(const float* __restrict__ out1, const float* __restrict__ b1,
        const float* __restrict__ W2, const float* __restrict__ attS2,
        const float* __restrict__ attD2, float* __restrict__ g,
        float* __restrict__ as2, float* __restrict__ ad2, int nNodes) {
  __shared__ float hbuf[4][64];
  int l = threadIdx.x & 63;
  int w = threadIdx.x >> 6;
  int wid = (blockIdx.x * blockDim.x + threadIdx.x) >> 6;
  int nw = (gridDim.x * blockDim.x) >> 6;
  const float4* W4 = reinterpret_cast<const float4*>(&W2[l * 64]);
  float4 w0 = W4[0],  w1 = W4[1],  w2 = W4[2],  w3 = W4[3];
  float4 w4 = W4[4],  w5 = W4[5],  w6 = W4[6],  w7 = W4[7];
  float4 w8 = W4[8],  w9 = W4[9],  w10 = W4[10], w11 = W4[11];
  float4 w12 = W4[12], w13 = W4[13], w14 = W4[14], w15 = W4[15];
  float aS = attS2[l], aD = attD2[l], bb = b1[l];
  const float4* hb = reinterpret_cast<const float4*>(hbuf[w]);
  for (int n = wid; n < nNodes; n += nw) {
    float v = out1[(size_t)n * 64 + l] + bb;
    float hh = v > 0.f ? v : expm1f(v);
    hbuf[w][l] = hh;
    float a0 = 0.f, a1 = 0.f, a2 = 0.f, a3 = 0.f;
#define NSTEP(i, wv) { float4 hv = hb[i]; \
    a0 = fmaf(hv.x, wv.x, a0); a1 = fmaf(hv.y, wv.y, a1); \
    a2 = fmaf(hv.z, wv.z, a2); a3 = fmaf(hv.w, wv.w, a3); }
    NSTEP(0, w0)  NSTEP(1, w1)  NSTEP(2, w2)  NSTEP(3, w3)
    NSTEP(4, w4)  NSTEP(5, w5)  NSTEP(6, w6)  NSTEP(7, w7)
    NSTEP(8, w8)  NSTEP(9, w9)  NSTEP(10, w10) NSTEP(11, w11)
    NSTEP(12, w12) NSTEP(13, w13) NSTEP(14, w14) NSTEP(15, w15)
#undef NSTEP
    float acc = (a0 + a1) + (a2 + a3);
    g[(size_t)n * 64 + l] = acc;     // in-place over out1 is safe: lane reads only its own elem
    float s2 = acc * aS, d2 = acc * aD;
#pragma unroll
    for (int off = 32; off > 0; off >>= 1) {
      s2 += __shfl_xor(s2, off, 64);
      d2 += __shfl_xor(d2, off, 64);
    }
    if (l == 0) { as2[n] = s2; ad2[n] = d2; }
  }
}

// ---- GAT layer 2 aggregation FUSED with frame mean: 8 edge-groups x 8 lanes ----
__global__ void __launch_bounds__(256)
k_agg2mean(const int* __restrict__ rowptr, const int* __restrict__ csr,
           const float* __restrict__ gtab, const float* __restrict__ as2,
           const float* __restrict__ ad2, float* __restrict__ emb) {
  __shared__ float part[4][64];
  int t = threadIdx.x;
  int w = t >> 6, l = t & 63;
  int g = l >> 3, q = l & 7;
  int f = blockIdx.x / BPF;
  int wf = (blockIdx.x - f * BPF) * 4 + w;        // wave id within frame [0, BPF*4)
  float m0 = 0.f, m1 = 0.f, m2 = 0.f, m3 = 0.f, m4 = 0.f, m5 = 0.f, m6 = 0.f, m7 = 0.f;
  for (int j = wf; j < NN_F; j += BPF * 4) {
    int n = f * NN_F + j;
    size_t nb = (size_t)n * 64 + q * 8;
    float adv = ad2[n];
    float a0, a1, a2, a3, a4, a5, a6, a7, den;
    if (g == 0) {
      float e0 = expf(lrelu02(as2[n] + adv));
      float4 v0 = *reinterpret_cast<const float4*>(&gtab[nb]);
      float4 v1 = *reinterpret_cast<const float4*>(&gtab[nb + 4]);
      a0 = e0 * v0.x; a1 = e0 * v0.y; a2 = e0 * v0.z; a3 = e0 * v0.w;
      a4 = e0 * v1.x; a5 = e0 * v1.y; a6 = e0 * v1.z; a7 = e0 * v1.w;
      den = e0;
    } else {
      a0 = a1 = a2 = a3 = a4 = a5 = a6 = a7 = 0.f; den = 0.f;
    }
    int s0 = rowptr[n], s1 = rowptr[n + 1];
    for (int i = s0 + g; i < s1; i += 8) {
      int src = csr[i];
      float e2 = expf(lrelu02(as2[src] + adv));
      size_t sb = (size_t)src * 64 + q * 8;
      float4 v0 = *reinterpret_cast<const float4*>(&gtab[sb]);
      float4 v1 = *reinterpret_cast<const float4*>(&gtab[sb + 4]);
      a0 = fmaf(e2, v0.x, a0); a1 = fmaf(e2, v0.y, a1);
      a2 = fmaf(e2, v0.z, a2); a3 = fmaf(e2, v0.w, a3);
      a4 = fmaf(e2, v1.x, a4); a5 = fmaf(e2, v1.y, a5);
      a6 = fmaf(e2, v1.z, a6); a7 = fmaf(e2, v1.w, a7);
      den += e2;
    }
#pragma unroll
    for (int off = 8; off <= 32; off <<= 1) {
      a0 += __shfl_xor(a0, off, 64); a1 += __shfl_xor(a1, off, 64);
      a2 += __shfl_xor(a2, off, 64); a3 += __shfl_xor(a3, off, 64);
      a4 += __shfl_xor(a4, off, 64); a5 += __shfl_xor(a5, off, 64);
      a6 += __shfl_xor(a6, off, 64); a7 += __shfl_xor(a7, off, 64);
      den += __shfl_xor(den, off, 64);
    }
    float inv = 1.f / den;
    m0 = fmaf(a0, inv, m0); m1 = fmaf(a1, inv, m1);
    m2 = fmaf(a2, inv, m2); m3 = fmaf(a3, inv, m3);
    m4 = fmaf(a4, inv, m4); m5 = fmaf(a5, inv, m5);
    m6 = fmaf(a6, inv, m6); m7 = fmaf(a7, inv, m7);
  }
  if (g == 0) {
    part[w][q * 8 + 0] = m0; part[w][q * 8 + 1] = m1;
    part[w][q * 8 + 2] = m2; part[w][q * 8 + 3] = m3;
    part[w][q * 8 + 4] = m4; part[w][q * 8 + 5] = m5;
    part[w][q * 8 + 6] = m6; part[w][q * 8 + 7] = m7;
  }
  __syncthreads();
  if (w == 0)
    atomicAdd(&emb[f * 64 + l],
              (part[0][l] + part[1][l] + part[2][l] + part[3][l]) * (1.0f / NN_F));
}

// ---------------- tiny transformer: 1024 threads, 16-lane-group shuffle GEMVs ----------
__device__ __forceinline__ float grp16_reduce(float p) {
#pragma unroll
  for (int off = 1; off < 16; off <<= 1) p += __shfl_xor(p, off, 64);
  return p;
}

__global__ void __launch_bounds__(1024)
k_transformer(const float* __restrict__ emb, const float* __restrict__ b2,
              const float* __restrict__ Wqkv, const float* __restrict__ bqkv,
              const float* __restrict__ Wo, const float* __restrict__ bo,
              const float* __restrict__ ln1w, const float* __restrict__ ln1b,
              const float* __restrict__ Wff1, const float* __restrict__ bff1,
              const float* __restrict__ Wff2, const float* __restrict__ bff2,
              const float* __restrict__ ln2w, const float* __restrict__ ln2b,
              const float* __restrict__ Wh1, const float* __restrict__ bh1,
              const float* __restrict__ Wh2, const float* __restrict__ bh2,
              float* __restrict__ out) {
  __shared__ float seq[5][64];
  __shared__ float qkv[5][192];
  __shared__ float att[4][5][5];
  __shared__ float aob[5][64];
  __shared__ float ffb[5][128];
  __shared__ float tmp[5][64];
  __shared__ float hid[32];
  int t = threadIdx.x;
  int l = t & 63, w = t >> 6;        // 16 waves
  int g = l >> 4, q = l & 15;        // 4 groups of 16 lanes

  if (t < 320) seq[t >> 6][t & 63] = emb[t] + b2[t & 63];
  __syncthreads();

  for (int ly = 0; ly < 3; ly++) {
    const float* Wq  = Wqkv + ly * 12288; const float* bq  = bqkv + ly * 192;
    const float* Wol = Wo   + ly * 4096;  const float* bol = bo   + ly * 64;
    const float* w1  = ln1w + ly * 64;    const float* bb1 = ln1b + ly * 64;
    const float* Wf1 = Wff1 + ly * 8192;  const float* bf1 = bff1 + ly * 128;
    const float* Wf2 = Wff2 + ly * 8192;  const float* bf2 = bff2 + ly * 64;
    const float* w2  = ln2w + ly * 64;    const float* bb2 = ln2b + ly * 64;

    for (int o = w * 4 + g; o < 960; o += 64) {
      int s = o / 192, j = o - s * 192;
      float4 wv = *reinterpret_cast<const float4*>(&Wq[j * 64 + q * 4]);
      float4 xv = *reinterpret_cast<const float4*>(&seq[s][q * 4]);
      float p = wv.x * xv.x + wv.y * xv.y + wv.z * xv.z + wv.w * xv.w;
      p = grp16_reduce(p);
      if (q == 0) qkv[s][j] = p + bq[j];
    }
    __syncthreads();

    if (t < 100) {
      int hh = t / 25, qs = (t / 5) % 5, ks = t % 5;
      float acc = 0.f;
      for (int d = 0; d < 16; d++)
        acc = fmaf(qkv[qs][hh * 16 + d], qkv[ks][64 + hh * 16 + d], acc);
      att[hh][qs][ks] = acc * 0.25f;
    }
    __syncthreads();
    if (t < 20) {
      int hh = t / 5, qs = t % 5;
      float m = att[hh][qs][0];
      for (int k2 = 1; k2 < 5; k2++) m = fmaxf(m, att[hh][qs][k2]);
      float ss = 0.f;
      for (int k2 = 0; k2 < 5; k2++) { float v = expf(att[hh][qs][k2] - m); att[hh][qs][k2] = v; ss += v; }
      float inv = 1.f / ss;
      for (int k2 = 0; k2 < 5; k2++) att[hh][qs][k2] *= inv;
    }
    __syncthreads();

    if (t < 320) {
      int s = t >> 6, j = t & 63, hh = j >> 4;
      float acc = 0.f;
      for (int k2 = 0; k2 < 5; k2++) acc = fmaf(att[hh][s][k2], qkv[k2][128 + j], acc);
      aob[s][j] = acc;
    }
    __syncthreads();

    for (int o = w * 4 + g; o < 320; o += 64) {
      int s = o >> 6, c = o & 63;
      float4 wv = *reinterpret_cast<const float4*>(&Wol[c * 64 + q * 4]);
      float4 xv = *reinterpret_cast<const float4*>(&aob[s][q * 4]);
      float p = wv.x * xv.x + wv.y * xv.y + wv.z * xv.z + wv.w * xv.w;
      p = grp16_reduce(p);
      if (q == 0) tmp[s][c] = seq[s][c] + p + bol[c];
    }
    __syncthreads();

    if (w < 5) {
      float v = tmp[w][l];
      float s1 = v, s2 = v * v;
#pragma unroll
      for (int off = 1; off < 64; off <<= 1) {
        s1 += __shfl_xor(s1, off, 64);
        s2 += __shfl_xor(s2, off, 64);
      }
      float m = s1 * (1.f / 64.f);
      float var = s2 * (1.f / 64.f) - m * m;
      float inv = 1.f / sqrtf(var + 1e-5f);
      seq[w][l] = (v - m) * inv * w1[l] + bb1[l];
    }
    __syncthreads();

    for (int o = w * 4 + g; o < 640; o += 64) {
      int s = o >> 7, j = o & 127;
      float4 wv = *reinterpret_cast<const float4*>(&Wf1[j * 64 + q * 4]);
      float4 xv = *reinterpret_cast<const float4*>(&seq[s][q * 4]);
      float p = wv.x * xv.x + wv.y * xv.y + wv.z * xv.z + wv.w * xv.w;
      p = grp16_reduce(p);
      if (q == 0) ffb[s][j] = fmaxf(p + bf1[j], 0.f);
    }
    __syncthreads();

    for (int o = w * 4 + g; o < 320; o += 64) {
      int s = o >> 6, c = o & 63;
      float4 wa = *reinterpret_cast<const float4*>(&Wf2[c * 128 + q * 8]);
      float4 wb = *reinterpret_cast<const float4*>(&Wf2[c * 128 + q * 8 + 4]);
      float4 xa = *reinterpret_cast<const float4*>(&ffb[s][q * 8]);
      float4 xb = *reinterpret_cast<const float4*>(&ffb[s][q * 8 + 4]);
      float p = wa.x * xa.x + wa.y * xa.y + wa.z * xa.z + wa.w * xa.w
              + wb.x * xb.x + wb.y * xb.y + wb.z * xb.z + wb.w * xb.w;
      p = grp16_reduce(p);
      if (q == 0) tmp[s][c] = seq[s][c] + p + bf2[c];
    }
    __syncthreads();

    if (w < 5) {
      float v = tmp[w][l];
      float s1 = v, s2 = v * v;
#pragma unroll
      for (int off = 1; off < 64; off <<= 1) {
        s1 += __shfl_xor(s1, off, 64);
        s2 += __shfl_xor(s2, off, 64);
      }
      float m = s1 * (1.f / 64.f);
      float var = s2 * (1.f / 64.f) - m * m;
      float inv = 1.f / sqrtf(var + 1e-5f);
      seq[w][l] = (v - m) * inv * w2[l] + bb2[l];
    }
    __syncthreads();
  }

  for (int o = w * 4 + g; o < 32; o += 64) {
    float4 wv = *reinterpret_cast<const float4*>(&Wh1[o * 64 + q * 4]);
    float4 xv = *reinterpret_cast<const float4*>(&seq[4][q * 4]);
    float p = wv.x * xv.x + wv.y * xv.y + wv.z * xv.z + wv.w * xv.w;
    p = grp16_reduce(p);
    if (q == 0) hid[o] = fmaxf(p + bh1[o], 0.f);
  }
  __syncthreads();
  if (t < 2) {
    float acc = bh2[t];
    for (int j = 0; j < 32; j++) acc = fmaf(hid[j], Wh2[t * 32 + j], acc);
    out[t] = acc;
  }
}

extern "C" void kernel_launch(void* const* d_in, const int* in_sizes, int n_in,
                              void* d_out, int out_size, void* d_ws, size_t ws_size,
                              hipStream_t stream) {
  const float* x     = (const float*)d_in[0];
  const int*   ei    = (const int*)d_in[1];
  const float* W1    = (const float*)d_in[2];
  const float* attS1 = (const float*)d_in[3];
  const float* attD1 = (const float*)d_in[4];
  const float* b1    = (const float*)d_in[5];
  const float* W2    = (const float*)d_in[6];
  const float* attS2 = (const float*)d_in[7];
  const float* attD2 = (const float*)d_in[8];
  const float* b2    = (const float*)d_in[9];
  const float* tWqkv = (const float*)d_in[10];
  const float* tbqkv = (const float*)d_in[11];
  const float* tWo   = (const float*)d_in[12];
  const float* tbo   = (const float*)d_in[13];
  const float* tln1w = (const float*)d_in[14];
  const float* tln1b = (const float*)d_in[15];
  const float* tWff1 = (const float*)d_in[16];
  const float* tbff1 = (const float*)d_in[17];
  const float* tWff2 = (const float*)d_in[18];
  const float* tbff2 = (const float*)d_in[19];
  const float* tln2w = (const float*)d_in[20];
  const float* tln2b = (const float*)d_in[21];
  const float* Wh1   = (const float*)d_in[22];
  const float* bh1   = (const float*)d_in[23];
  const float* Wh2   = (const float*)d_in[24];
  const float* bh2   = (const float*)d_in[25];
  float* out = (float*)d_out;

  auto need_bytes = [](int F) -> size_t {
    size_t NT = (size_t)F * NN_F, ET = (size_t)F * NE_F;
    size_t fl = NT * 64 * 2 + NT * 8 * 2 + NT * 2 + 320;
    size_t it = NT * 3 + 1 + 2048 + ET;
    return (fl + it) * 4;
  };
  const int F = (ws_size >= need_bytes(5)) ? 5 : 1;
  const int NT = F * NN_F, ET = F * NE_F;

  float* ws  = (float*)d_ws;
  float* h1  = ws;                          // NT*64
  float* acc = h1 + (size_t)NT * 64;        // NT*64  (out1; node2 in-place -> g)
  float* as1 = acc + (size_t)NT * 64;       // NT*8
  float* ad1 = as1 + (size_t)NT * 8;        // NT*8
  float* as2 = ad1 + (size_t)NT * 8;        // NT
  float* ad2 = as2 + NT;                    // NT
  float* emb = ad2 + NT;                    // 320
  int* deg    = (int*)(emb + 320);          // NT
  int* rowptr = deg + NT;                   // NT+1
  int* cur    = rowptr + NT + 1;            // NT
  int* bsum   = cur + NT;                   // <=1024
  int* boff   = bsum + 1024;                // <=1024
  int* csr    = boff + 1024;                // ET

  (void)hipMemsetAsync(emb, 0, 320 * sizeof(float), stream);

  const int nblk = (NT + 255) / 256;
  const int edgeBlocks = (ET + 255) / 256;
  const int aggBlocks = (NT + 3) / 4;       // wave per node, 4 waves/block
  const int nodeBlocks = 2048;

  for (int f0 = 0; f0 < 5; f0 += F) {
    const float* xf = x + (size_t)f0 * NN_F * 13;
    const int* eif  = ei + (size_t)f0 * 2 * NE_F;

    (void)hipMemsetAsync(deg, 0, NT * sizeof(int), stream);
    k_hist<<<edgeBlocks, 256, 0, stream>>>(eif, deg, F);
    k_scan1<<<nblk, 256, 0, stream>>>(deg, bsum, NT);
    k_scan2<<<1, 1024, 0, stream>>>(bsum, boff, nblk);
    k_scan3<<<nblk, 256, 0, stream>>>(deg, boff, rowptr, cur, NT, ET);
    k_scatter<<<edgeBlocks, 256, 0, stream>>>(eif, cur, csr, F);

    k_node1<<<nodeBlocks, 256, 0, stream>>>(xf, W1, attS1, attD1, h1, as1, ad1, NT);
    k_agg1<<<aggBlocks, 256, 0, stream>>>(rowptr, csr, h1, as1, ad1, acc, NT);
    k_node2<<<nodeBlocks, 256, 0, stream>>>(acc, b1, W2, attS2, attD2, acc, as2, ad2, NT);
    // fused agg2 + frame mean (emb accumulated via atomics; zeroed above)
    k_agg2mean<<<F * BPF, 256, 0, stream>>>(rowptr, csr, acc, as2, ad2, emb + f0 * 64);
  }

  k_transformer<<<1, 1024, 0, stream>>>(emb, b2, tWqkv, tbqkv, tWo, tbo, tln1w, tln1b,
                                        tWff1, tbff1, tWff2, tbff2, tln2w, tln2b,
                                        Wh1, bh1, Wh2, bh2, out);
}

// Round 7
// 525.730 us; speedup vs baseline: 3.8880x; 1.1799x over previous
//
#include <hip/hip_runtime.h>
#include <math.h>

#define NN_F 50000      // nodes per frame
#define NE_F 400000     // edges per frame
#define BPF  512        // blocks per frame for fused agg2+mean

__device__ __forceinline__ float lrelu02(float x) { return x > 0.f ? x : 0.2f * x; }

// ---------------- GAT layer 1: wave per node, lane = output channel ----------------
__global__ void __launch_bounds__(256, 3)
k_node1(const float* __restrict__ x, const float* __restrict__ W1,
        const float* __restrict__ attS, const float* __restrict__ attD,
        float* __restrict__ h1, float* __restrict__ as1, float* __restrict__ ad1,
        int nNodes) {
  __shared__ float xbuf[4][16];
  int l = threadIdx.x & 63;
  int w = threadIdx.x >> 6;
  int wid = (blockIdx.x * blockDim.x + threadIdx.x) >> 6;
  int nw = (gridDim.x * blockDim.x) >> 6;
  float4 wA = make_float4(W1[l * 13 + 0], W1[l * 13 + 1], W1[l * 13 + 2], W1[l * 13 + 3]);
  float4 wB = make_float4(W1[l * 13 + 4], W1[l * 13 + 5], W1[l * 13 + 6], W1[l * 13 + 7]);
  float4 wC = make_float4(W1[l * 13 + 8], W1[l * 13 + 9], W1[l * 13 + 10], W1[l * 13 + 11]);
  float4 wD = make_float4(W1[l * 13 + 12], 0.f, 0.f, 0.f);
  float aS = attS[l], aD = attD[l];
  const float4* xb = reinterpret_cast<const float4*>(xbuf[w]);
  for (int n = wid; n < nNodes; n += nw) {
    if (l < 16) xbuf[w][l] = (l < 13) ? x[(size_t)n * 13 + l] : 0.f;
    float4 x0 = xb[0], x1 = xb[1], x2 = xb[2], x3 = xb[3];
    float a0 = x0.x * wA.x, a1 = x0.y * wA.y, a2 = x0.z * wA.z, a3 = x0.w * wA.w;
    a0 = fmaf(x1.x, wB.x, a0); a1 = fmaf(x1.y, wB.y, a1);
    a2 = fmaf(x1.z, wB.z, a2); a3 = fmaf(x1.w, wB.w, a3);
    a0 = fmaf(x2.x, wC.x, a0); a1 = fmaf(x2.y, wC.y, a1);
    a2 = fmaf(x2.z, wC.z, a2); a3 = fmaf(x2.w, wC.w, a3);
    a0 = fmaf(x3.x, wD.x, a0);
    float acc = (a0 + a1) + (a2 + a3);
    h1[(size_t)n * 64 + l] = acc;
    float s = acc * aS, d = acc * aD;
#pragma unroll
    for (int off = 1; off < 8; off <<= 1) {
      s += __shfl_xor(s, off, 64);
      d += __shfl_xor(d, off, 64);
    }
    if ((l & 7) == 0) { as1[n * 8 + (l >> 3)] = s; ad1[n * 8 + (l >> 3)] = d; }
  }
}

// ---- CSR build pass A: per-edge rank via histogram atomic (4x ILP) ----
__global__ void k_rank(const int* __restrict__ ei, int* __restrict__ deg,
                       int* __restrict__ rank, int nFrames) {
  int tid = blockIdx.x * blockDim.x + threadIdx.x;
  int T = (nFrames * NE_F) >> 2;
  if (tid >= T) return;
  int gd[4];
#pragma unroll
  for (int i = 0; i < 4; i++) {
    int e = tid + i * T;
    int f = e / NE_F, idx = e - f * NE_F;
    gd[i] = f * NN_F + ei[(size_t)f * 2 * NE_F + NE_F + idx];
  }
  int r[4];
#pragma unroll
  for (int i = 0; i < 4; i++) r[i] = atomicAdd(&deg[gd[i]], 1);
#pragma unroll
  for (int i = 0; i < 4; i++) rank[tid + i * T] = r[i];
}

// ---------------- CSR build: per-block sums ----------------
__global__ void k_scan1(const int* __restrict__ deg, int* __restrict__ bsum, int nNodes) {
  __shared__ int part[256];
  int t = threadIdx.x;
  int i = blockIdx.x * 256 + t;
  part[t] = (i < nNodes) ? deg[i] : 0;
  __syncthreads();
  for (int off = 128; off > 0; off >>= 1) {
    if (t < off) part[t] += part[t + off];
    __syncthreads();
  }
  if (t == 0) bsum[blockIdx.x] = part[0];
}

// ---------------- CSR build: scan of block sums (single block, up to 1024) ----------------
__global__ void __launch_bounds__(1024)
k_scan2(const int* __restrict__ bsum, int* __restrict__ boff, int nblk) {
  __shared__ int part[1024];
  int t = threadIdx.x;
  part[t] = (t < nblk) ? bsum[t] : 0;
  __syncthreads();
  for (int off = 1; off < 1024; off <<= 1) {
    int v = (t >= off) ? part[t - off] : 0;
    __syncthreads();
    part[t] += v;
    __syncthreads();
  }
  if (t < nblk) boff[t] = part[t] - bsum[t];  // exclusive
}

// ---------------- CSR build: intra-block scan -> rowptr ----------------
__global__ void k_scan3(const int* __restrict__ deg, const int* __restrict__ boff,
                        int* __restrict__ rowptr, int nNodes, int nEdges) {
  __shared__ int part[256];
  int t = threadIdx.x;
  int i = blockIdx.x * 256 + t;
  int d = (i < nNodes) ? deg[i] : 0;
  part[t] = d;
  __syncthreads();
  for (int off = 1; off < 256; off <<= 1) {
    int v = (t >= off) ? part[t - off] : 0;
    __syncthreads();
    part[t] += v;
    __syncthreads();
  }
  if (i < nNodes) rowptr[i] = boff[blockIdx.x] + part[t] - d;  // exclusive prefix
  if (blockIdx.x == 0 && t == 0) rowptr[nNodes] = nEdges;
}

// ---- CSR build pass B: place srcs (NO atomics; 4x ILP) ----
__global__ void k_place(const int* __restrict__ ei, const int* __restrict__ rowptr,
                        const int* __restrict__ rank, int* __restrict__ csr, int nFrames) {
  int tid = blockIdx.x * blockDim.x + threadIdx.x;
  int T = (nFrames * NE_F) >> 2;
  if (tid >= T) return;
#pragma unroll
  for (int i = 0; i < 4; i++) {
    int e = tid + i * T;
    int f = e / NE_F, idx = e - f * NE_F;
    const int* base = ei + (size_t)f * 2 * NE_F;
    int src = base[idx], dst = base[NE_F + idx];
    csr[rowptr[f * NN_F + dst] + rank[e]] = f * NN_F + src;
  }
}

// ---- GAT layer 1 aggregation: wave per dst, 8 edge-groups x 8 lanes (head = q) ----
__global__ void __launch_bounds__(256)
k_agg1(const int* __restrict__ rowptr, const int* __restrict__ csr,
       const float* __restrict__ h1, const float* __restrict__ as1,
       const float* __restrict__ ad1, float* __restrict__ out1, int nNodes) {
  int wid = (blockIdx.x * blockDim.x + threadIdx.x) >> 6;
  if (wid >= nNodes) return;
  int l = threadIdx.x & 63;
  int g = l >> 3, q = l & 7;          // group g handles edges i%8==g; lane q owns head q
  size_t nb = (size_t)wid * 64 + q * 8;
  float adv = ad1[wid * 8 + q];
  float a0, a1, a2, a3, a4, a5, a6, a7, den;
  if (g == 0) {
    float e0 = expf(lrelu02(as1[wid * 8 + q] + adv));
    float4 v0 = *reinterpret_cast<const float4*>(&h1[nb]);
    float4 v1 = *reinterpret_cast<const float4*>(&h1[nb + 4]);
    a0 = e0 * v0.x; a1 = e0 * v0.y; a2 = e0 * v0.z; a3 = e0 * v0.w;
    a4 = e0 * v1.x; a5 = e0 * v1.y; a6 = e0 * v1.z; a7 = e0 * v1.w;
    den = e0;
  } else {
    a0 = a1 = a2 = a3 = a4 = a5 = a6 = a7 = 0.f; den = 0.f;
  }
  int s0 = rowptr[wid], s1 = rowptr[wid + 1];
  for (int i = s0 + g; i < s1; i += 8) {
    int src = csr[i];
    float e2 = expf(lrelu02(as1[src * 8 + q] + adv));
    size_t sb = (size_t)src * 64 + q * 8;
    float4 v0 = *reinterpret_cast<const float4*>(&h1[sb]);
    float4 v1 = *reinterpret_cast<const float4*>(&h1[sb + 4]);
    a0 = fmaf(e2, v0.x, a0); a1 = fmaf(e2, v0.y, a1);
    a2 = fmaf(e2, v0.z, a2); a3 = fmaf(e2, v0.w, a3);
    a4 = fmaf(e2, v1.x, a4); a5 = fmaf(e2, v1.y, a5);
    a6 = fmaf(e2, v1.z, a6); a7 = fmaf(e2, v1.w, a7);
    den += e2;
  }
#pragma unroll
  for (int off = 8; off <= 32; off <<= 1) {
    a0 += __shfl_xor(a0, off, 64); a1 += __shfl_xor(a1, off, 64);
    a2 += __shfl_xor(a2, off, 64); a3 += __shfl_xor(a3, off, 64);
    a4 += __shfl_xor(a4, off, 64); a5 += __shfl_xor(a5, off, 64);
    a6 += __shfl_xor(a6, off, 64); a7 += __shfl_xor(a7, off, 64);
    den += __shfl_xor(den, off, 64);
  }
  if (g == 0) {
    float inv = 1.f / den;
    float4 r0 = make_float4(a0 * inv, a1 * inv, a2 * inv, a3 * inv);
    float4 r1 = make_float4(a4 * inv, a5 * inv, a6 * inv, a7 * inv);
    *reinterpret_cast<float4*>(&out1[nb]) = r0;
    *reinterpret_cast<float4*>(&out1[nb + 4]) = r1;
  }
}

// ---------------- bias + ELU + GAT2 linear (in-place safe) + att feats ----------------
__global__ void __launch_bounds__(256, 3)
k_node2(const float* __restrict__ out1, const float* __restrict__ b1,
        const float* __restrict__ W2, const float* __restrict__ attS2,
        const float* __restrict__ attD2, float* __restrict__ g,
        float* __restrict__ as2, float* __restrict__ ad2, int nNodes) {
  __shared__ float hbuf[4][64];
  int l = threadIdx.x & 63;
  int w = threadIdx.x >> 6;
  int wid = (blockIdx.x * blockDim.x + threadIdx.x) >> 6;
  int nw = (gridDim.x * blockDim.x) >> 6;
  const float4* W4 = reinterpret_cast<const float4*>(&W2[l * 64]);
  float4 w0 = W4[0],  w1 = W4[1],  w2 = W4[2],  w3 = W4[3];
  float4 w4 = W4[4],  w5 = W4[5],  w6 = W4[6],  w7 = W4[7];
  float4 w8 = W4[8],  w9 = W4[9],  w10 = W4[10], w11 = W4[11];
  float4 w12 = W4[12], w13 = W4[13], w14 = W4[14], w15 = W4[15];
  float aS = attS2[l], aD = attD2[l], bb = b1[l];
  const float4* hb = reinterpret_cast<const float4*>(hbuf[w]);
  for (int n = wid; n < nNodes; n += nw) {
    float v = out1[(size_t)n * 64 + l] + bb;
    float hh = v > 0.f ? v : expm1f(v);
    hbuf[w][l] = hh;
    float a0 = 0.f, a1 = 0.f, a2 = 0.f, a3 = 0.f;
#define NSTEP(i, wv) { float4 hv = hb[i]; \
    a0 = fmaf(hv.x, wv.x, a0); a1 = fmaf(hv.y, wv.y, a1); \
    a2 = fmaf(hv.z, wv.z, a2); a3 = fmaf(hv.w, wv.w, a3); }
    NSTEP(0, w0)  NSTEP(1, w1)  NSTEP(2, w2)  NSTEP(3, w3)
    NSTEP(4, w4)  NSTEP(5, w5)  NSTEP(6, w6)  NSTEP(7, w7)
    NSTEP(8, w8)  NSTEP(9, w9)  NSTEP(10, w10) NSTEP(11, w11)
    NSTEP(12, w12) NSTEP(13, w13) NSTEP(14, w14) NSTEP(15, w15)
#undef NSTEP
    float acc = (a0 + a1) + (a2 + a3);
    g[(size_t)n * 64 + l] = acc;
    float s2 = acc * aS, d2 = acc * aD;
#pragma unroll
    for (int off = 32; off > 0; off >>= 1) {
      s2 += __shfl_xor(s2, off, 64);
      d2 += __shfl_xor(d2, off, 64);
    }
    if (l == 0) { as2[n] = s2; ad2[n] = d2; }
  }
}

// ---- GAT layer 2 aggregation FUSED with frame mean: 8 edge-groups x 8 lanes ----
__global__ void __launch_bounds__(256)
k_agg2mean(const int* __restrict__ rowptr, const int* __restrict__ csr,
           const float* __restrict__ gtab, const float* __restrict__ as2,
           const float* __restrict__ ad2, float* __restrict__ emb) {
  __shared__ float part[4][64];
  int t = threadIdx.x;
  int w = t >> 6, l = t & 63;
  int g = l >> 3, q = l & 7;
  int f = blockIdx.x / BPF;
  int wf = (blockIdx.x - f * BPF) * 4 + w;        // wave id within frame [0, BPF*4)
  float m0 = 0.f, m1 = 0.f, m2 = 0.f, m3 = 0.f, m4 = 0.f, m5 = 0.f, m6 = 0.f, m7 = 0.f;
  for (int j = wf; j < NN_F; j += BPF * 4) {
    int n = f * NN_F + j;
    size_t nb = (size_t)n * 64 + q * 8;
    float adv = ad2[n];
    float a0, a1, a2, a3, a4, a5, a6, a7, den;
    if (g == 0) {
      float e0 = expf(lrelu02(as2[n] + adv));
      float4 v0 = *reinterpret_cast<const float4*>(&gtab[nb]);
      float4 v1 = *reinterpret_cast<const float4*>(&gtab[nb + 4]);
      a0 = e0 * v0.x; a1 = e0 * v0.y; a2 = e0 * v0.z; a3 = e0 * v0.w;
      a4 = e0 * v1.x; a5 = e0 * v1.y; a6 = e0 * v1.z; a7 = e0 * v1.w;
      den = e0;
    } else {
      a0 = a1 = a2 = a3 = a4 = a5 = a6 = a7 = 0.f; den = 0.f;
    }
    int s0 = rowptr[n], s1 = rowptr[n + 1];
    for (int i = s0 + g; i < s1; i += 8) {
      int src = csr[i];
      float e2 = expf(lrelu02(as2[src] + adv));
      size_t sb = (size_t)src * 64 + q * 8;
      float4 v0 = *reinterpret_cast<const float4*>(&gtab[sb]);
      float4 v1 = *reinterpret_cast<const float4*>(&gtab[sb + 4]);
      a0 = fmaf(e2, v0.x, a0); a1 = fmaf(e2, v0.y, a1);
      a2 = fmaf(e2, v0.z, a2); a3 = fmaf(e2, v0.w, a3);
      a4 = fmaf(e2, v1.x, a4); a5 = fmaf(e2, v1.y, a5);
      a6 = fmaf(e2, v1.z, a6); a7 = fmaf(e2, v1.w, a7);
      den += e2;
    }
#pragma unroll
    for (int off = 8; off <= 32; off <<= 1) {
      a0 += __shfl_xor(a0, off, 64); a1 += __shfl_xor(a1, off, 64);
      a2 += __shfl_xor(a2, off, 64); a3 += __shfl_xor(a3, off, 64);
      a4 += __shfl_xor(a4, off, 64); a5 += __shfl_xor(a5, off, 64);
      a6 += __shfl_xor(a6, off, 64); a7 += __shfl_xor(a7, off, 64);
      den += __shfl_xor(den, off, 64);
    }
    float inv = 1.f / den;
    m0 = fmaf(a0, inv, m0); m1 = fmaf(a1, inv, m1);
    m2 = fmaf(a2, inv, m2); m3 = fmaf(a3, inv, m3);
    m4 = fmaf(a4, inv, m4); m5 = fmaf(a5, inv, m5);
    m6 = fmaf(a6, inv, m6); m7 = fmaf(a7, inv, m7);
  }
  if (g == 0) {
    part[w][q * 8 + 0] = m0; part[w][q * 8 + 1] = m1;
    part[w][q * 8 + 2] = m2; part[w][q * 8 + 3] = m3;
    part[w][q * 8 + 4] = m4; part[w][q * 8 + 5] = m5;
    part[w][q * 8 + 6] = m6; part[w][q * 8 + 7] = m7;
  }
  __syncthreads();
  if (w == 0)
    atomicAdd(&emb[f * 64 + l],
              (part[0][l] + part[1][l] + part[2][l] + part[3][l]) * (1.0f / NN_F));
}

// ---------------- tiny transformer: 1024 threads, 16-lane-group shuffle GEMVs ----------
__device__ __forceinline__ float grp16_reduce(float p) {
#pragma unroll
  for (int off = 1; off < 16; off <<= 1) p += __shfl_xor(p, off, 64);
  return p;
}

__global__ void __launch_bounds__(1024)
k_transformer(const float* __restrict__ emb, const float* __restrict__ b2,
              const float* __restrict__ Wqkv, const float* __restrict__ bqkv,
              const float* __restrict__ Wo, const float* __restrict__ bo,
              const float* __restrict__ ln1w, const float* __restrict__ ln1b,
              const float* __restrict__ Wff1, const float* __restrict__ bff1,
              const float* __restrict__ Wff2, const float* __restrict__ bff2,
              const float* __restrict__ ln2w, const float* __restrict__ ln2b,
              const float* __restrict__ Wh1, const float* __restrict__ bh1,
              const float* __restrict__ Wh2, const float* __restrict__ bh2,
              float* __restrict__ out) {
  __shared__ float seq[5][64];
  __shared__ float qkv[5][192];
  __shared__ float att[4][5][5];
  __shared__ float aob[5][64];
  __shared__ float ffb[5][128];
  __shared__ float tmp[5][64];
  __shared__ float hid[32];
  int t = threadIdx.x;
  int l = t & 63, w = t >> 6;        // 16 waves
  int g = l >> 4, q = l & 15;        // 4 groups of 16 lanes

  if (t < 320) seq[t >> 6][t & 63] = emb[t] + b2[t & 63];
  __syncthreads();

  for (int ly = 0; ly < 3; ly++) {
    const float* Wq  = Wqkv + ly * 12288; const float* bq  = bqkv + ly * 192;
    const float* Wol = Wo   + ly * 4096;  const float* bol = bo   + ly * 64;
    const float* w1  = ln1w + ly * 64;    const float* bb1 = ln1b + ly * 64;
    const float* Wf1 = Wff1 + ly * 8192;  const float* bf1 = bff1 + ly * 128;
    const float* Wf2 = Wff2 + ly * 8192;  const float* bf2 = bff2 + ly * 64;
    const float* w2  = ln2w + ly * 64;    const float* bb2 = ln2b + ly * 64;

    for (int o = w * 4 + g; o < 960; o += 64) {
      int s = o / 192, j = o - s * 192;
      float4 wv = *reinterpret_cast<const float4*>(&Wq[j * 64 + q * 4]);
      float4 xv = *reinterpret_cast<const float4*>(&seq[s][q * 4]);
      float p = wv.x * xv.x + wv.y * xv.y + wv.z * xv.z + wv.w * xv.w;
      p = grp16_reduce(p);
      if (q == 0) qkv[s][j] = p + bq[j];
    }
    __syncthreads();

    if (t < 100) {
      int hh = t / 25, qs = (t / 5) % 5, ks = t % 5;
      float acc = 0.f;
      for (int d = 0; d < 16; d++)
        acc = fmaf(qkv[qs][hh * 16 + d], qkv[ks][64 + hh * 16 + d], acc);
      att[hh][qs][ks] = acc * 0.25f;
    }
    __syncthreads();
    if (t < 20) {
      int hh = t / 5, qs = t % 5;
      float m = att[hh][qs][0];
      for (int k2 = 1; k2 < 5; k2++) m = fmaxf(m, att[hh][qs][k2]);
      float ss = 0.f;
      for (int k2 = 0; k2 < 5; k2++) { float v = expf(att[hh][qs][k2] - m); att[hh][qs][k2] = v; ss += v; }
      float inv = 1.f / ss;
      for (int k2 = 0; k2 < 5; k2++) att[hh][qs][k2] *= inv;
    }
    __syncthreads();

    if (t < 320) {
      int s = t >> 6, j = t & 63, hh = j >> 4;
      float acc = 0.f;
      for (int k2 = 0; k2 < 5; k2++) acc = fmaf(att[hh][s][k2], qkv[k2][128 + j], acc);
      aob[s][j] = acc;
    }
    __syncthreads();

    for (int o = w * 4 + g; o < 320; o += 64) {
      int s = o >> 6, c = o & 63;
      float4 wv = *reinterpret_cast<const float4*>(&Wol[c * 64 + q * 4]);
      float4 xv = *reinterpret_cast<const float4*>(&aob[s][q * 4]);
      float p = wv.x * xv.x + wv.y * xv.y + wv.z * xv.z + wv.w * xv.w;
      p = grp16_reduce(p);
      if (q == 0) tmp[s][c] = seq[s][c] + p + bol[c];
    }
    __syncthreads();

    if (w < 5) {
      float v = tmp[w][l];
      float s1 = v, s2 = v * v;
#pragma unroll
      for (int off = 1; off < 64; off <<= 1) {
        s1 += __shfl_xor(s1, off, 64);
        s2 += __shfl_xor(s2, off, 64);
      }
      float m = s1 * (1.f / 64.f);
      float var = s2 * (1.f / 64.f) - m * m;
      float inv = 1.f / sqrtf(var + 1e-5f);
      seq[w][l] = (v - m) * inv * w1[l] + bb1[l];
    }
    __syncthreads();

    for (int o = w * 4 + g; o < 640; o += 64) {
      int s = o >> 7, j = o & 127;
      float4 wv = *reinterpret_cast<const float4*>(&Wf1[j * 64 + q * 4]);
      float4 xv = *reinterpret_cast<const float4*>(&seq[s][q * 4]);
      float p = wv.x * xv.x + wv.y * xv.y + wv.z * xv.z + wv.w * xv.w;
      p = grp16_reduce(p);
      if (q == 0) ffb[s][j] = fmaxf(p + bf1[j], 0.f);
    }
    __syncthreads();

    for (int o = w * 4 + g; o < 320; o += 64) {
      int s = o >> 6, c = o & 63;
      float4 wa = *reinterpret_cast<const float4*>(&Wf2[c * 128 + q * 8]);
      float4 wb = *reinterpret_cast<const float4*>(&Wf2[c * 128 + q * 8 + 4]);
      float4 xa = *reinterpret_cast<const float4*>(&ffb[s][q * 8]);
      float4 xb = *reinterpret_cast<const float4*>(&ffb[s][q * 8 + 4]);
      float p = wa.x * xa.x + wa.y * xa.y + wa.z * xa.z + wa.w * xa.w
              + wb.x * xb.x + wb.y * xb.y + wb.z * xb.z + wb.w * xb.w;
      p = grp16_reduce(p);
      if (q == 0) tmp[s][c] = seq[s][c] + p + bf2[c];
    }
    __syncthreads();

    if (w < 5) {
      float v = tmp[w][l];
      float s1 = v, s2 = v * v;
#pragma unroll
      for (int off = 1; off < 64; off <<= 1) {
        s1 += __shfl_xor(s1, off, 64);
        s2 += __shfl_xor(s2, off, 64);
      }
      float m = s1 * (1.f / 64.f);
      float var = s2 * (1.f / 64.f) - m * m;
      float inv = 1.f / sqrtf(var + 1e-5f);
      seq[w][l] = (v - m) * inv * w2[l] + bb2[l];
    }
    __syncthreads();
  }

  for (int o = w * 4 + g; o < 32; o += 64) {
    float4 wv = *reinterpret_cast<const float4*>(&Wh1[o * 64 + q * 4]);
    float4 xv = *reinterpret_cast<const float4*>(&seq[4][q * 4]);
    float p = wv.x * xv.x + wv.y * xv.y + wv.z * xv.z + wv.w * xv.w;
    p = grp16_reduce(p);
    if (q == 0) hid[o] = fmaxf(p + bh1[o], 0.f);
  }
  __syncthreads();
  if (t < 2) {
    float acc = bh2[t];
    for (int j = 0; j < 32; j++) acc = fmaf(hid[j], Wh2[t * 32 + j], acc);
    out[t] = acc;
  }
}

extern "C" void kernel_launch(void* const* d_in, const int* in_sizes, int n_in,
                              void* d_out, int out_size, void* d_ws, size_t ws_size,
                              hipStream_t stream) {
  const float* x     = (const float*)d_in[0];
  const int*   ei    = (const int*)d_in[1];
  const float* W1    = (const float*)d_in[2];
  const float* attS1 = (const float*)d_in[3];
  const float* attD1 = (const float*)d_in[4];
  const float* b1    = (const float*)d_in[5];
  const float* W2    = (const float*)d_in[6];
  const float* attS2 = (const float*)d_in[7];
  const float* attD2 = (const float*)d_in[8];
  const float* b2    = (const float*)d_in[9];
  const float* tWqkv = (const float*)d_in[10];
  const float* tbqkv = (const float*)d_in[11];
  const float* tWo   = (const float*)d_in[12];
  const float* tbo   = (const float*)d_in[13];
  const float* tln1w = (const float*)d_in[14];
  const float* tln1b = (const float*)d_in[15];
  const float* tWff1 = (const float*)d_in[16];
  const float* tbff1 = (const float*)d_in[17];
  const float* tWff2 = (const float*)d_in[18];
  const float* tbff2 = (const float*)d_in[19];
  const float* tln2w = (const float*)d_in[20];
  const float* tln2b = (const float*)d_in[21];
  const float* Wh1   = (const float*)d_in[22];
  const float* bh1   = (const float*)d_in[23];
  const float* Wh2   = (const float*)d_in[24];
  const float* bh2   = (const float*)d_in[25];
  float* out = (float*)d_out;

  auto need_bytes = [](int F) -> size_t {
    size_t NT = (size_t)F * NN_F, ET = (size_t)F * NE_F;
    size_t fl = NT * 64 * 2 + NT * 8 * 2 + NT * 2 + 320;
    size_t it = NT * 2 + 1 + 2048 + ET * 2;
    return (fl + it) * 4;
  };
  const int F = (ws_size >= need_bytes(5)) ? 5 : 1;
  const int NT = F * NN_F, ET = F * NE_F;

  float* ws  = (float*)d_ws;
  float* h1  = ws;                          // NT*64
  float* acc = h1 + (size_t)NT * 64;        // NT*64  (out1; node2 in-place -> g)
  float* as1 = acc + (size_t)NT * 64;       // NT*8
  float* ad1 = as1 + (size_t)NT * 8;        // NT*8
  float* as2 = ad1 + (size_t)NT * 8;        // NT
  float* ad2 = as2 + NT;                    // NT
  float* emb = ad2 + NT;                    // 320
  int* deg    = (int*)(emb + 320);          // NT
  int* rowptr = deg + NT;                   // NT+1
  int* bsum   = rowptr + NT + 1;            // <=1024
  int* boff   = bsum + 1024;                // <=1024
  int* rank   = boff + 1024;                // ET
  int* csr    = rank + ET;                  // ET

  (void)hipMemsetAsync(emb, 0, 320 * sizeof(float), stream);

  const int nblk = (NT + 255) / 256;
  const int edge4Blocks = ((ET >> 2) + 255) / 256;
  const int aggBlocks = (NT + 3) / 4;       // wave per node, 4 waves/block
  const int nodeBlocks = 2048;

  for (int f0 = 0; f0 < 5; f0 += F) {
    const float* xf = x + (size_t)f0 * NN_F * 13;
    const int* eif  = ei + (size_t)f0 * 2 * NE_F;

    (void)hipMemsetAsync(deg, 0, NT * sizeof(int), stream);
    k_rank<<<edge4Blocks, 256, 0, stream>>>(eif, deg, rank, F);
    k_scan1<<<nblk, 256, 0, stream>>>(deg, bsum, NT);
    k_scan2<<<1, 1024, 0, stream>>>(bsum, boff, nblk);
    k_scan3<<<nblk, 256, 0, stream>>>(deg, boff, rowptr, NT, ET);
    k_place<<<edge4Blocks, 256, 0, stream>>>(eif, rowptr, rank, csr, F);

    k_node1<<<nodeBlocks, 256, 0, stream>>>(xf, W1, attS1, attD1, h1, as1, ad1, NT);
    k_agg1<<<aggBlocks, 256, 0, stream>>>(rowptr, csr, h1, as1, ad1, acc, NT);
    k_node2<<<nodeBlocks, 256, 0, stream>>>(acc, b1, W2, attS2, attD2, acc, as2, ad2, NT);
    k_agg2mean<<<F * BPF, 256, 0, stream>>>(rowptr, csr, acc, as2, ad2, emb + f0 * 64);
  }

  k_transformer<<<1, 1024, 0, stream>>>(emb, b2, tWqkv, tbqkv, tWo, tbo, tln1w, tln1b,
                                        tWff1, tbff1, tWff2, tbff2, tln2w, tln2b,
                                        Wh1, bh1, Wh2, bh2, out);
}

// Round 8
// 511.360 us; speedup vs baseline: 3.9972x; 1.0281x over previous
//
#include <hip/hip_runtime.h>
#include <math.h>

#define NN_F 50000      // nodes per frame
#define NE_F 400000     // edges per frame
#define BPF  512        // blocks per frame for fused agg2+mean

__device__ __forceinline__ float lrelu02(float x) { return x > 0.f ? x : 0.2f * x; }

// bf16 pack (RNE) / unpack helpers
__device__ __forceinline__ unsigned short f2bf(float f) {
  unsigned int u = __float_as_uint(f);
  u += 0x7fffu + ((u >> 16) & 1u);
  return (unsigned short)(u >> 16);
}
__device__ __forceinline__ float bf_lo(unsigned int u) { return __uint_as_float(u << 16); }
__device__ __forceinline__ float bf_hi(unsigned int u) { return __uint_as_float(u & 0xffff0000u); }

// ---------------- GAT layer 1: wave per node, lane = output channel ----------------
__global__ void __launch_bounds__(256, 3)
k_node1(const float* __restrict__ x, const float* __restrict__ W1,
        const float* __restrict__ attS, const float* __restrict__ attD,
        unsigned short* __restrict__ h1b, float* __restrict__ as1, float* __restrict__ ad1,
        int nNodes) {
  __shared__ float xbuf[4][16];
  int l = threadIdx.x & 63;
  int w = threadIdx.x >> 6;
  int wid = (blockIdx.x * blockDim.x + threadIdx.x) >> 6;
  int nw = (gridDim.x * blockDim.x) >> 6;
  float4 wA = make_float4(W1[l * 13 + 0], W1[l * 13 + 1], W1[l * 13 + 2], W1[l * 13 + 3]);
  float4 wB = make_float4(W1[l * 13 + 4], W1[l * 13 + 5], W1[l * 13 + 6], W1[l * 13 + 7]);
  float4 wC = make_float4(W1[l * 13 + 8], W1[l * 13 + 9], W1[l * 13 + 10], W1[l * 13 + 11]);
  float4 wD = make_float4(W1[l * 13 + 12], 0.f, 0.f, 0.f);
  float aS = attS[l], aD = attD[l];
  const float4* xb = reinterpret_cast<const float4*>(xbuf[w]);
  for (int n = wid; n < nNodes; n += nw) {
    if (l < 16) xbuf[w][l] = (l < 13) ? x[(size_t)n * 13 + l] : 0.f;
    float4 x0 = xb[0], x1 = xb[1], x2 = xb[2], x3 = xb[3];
    float a0 = x0.x * wA.x, a1 = x0.y * wA.y, a2 = x0.z * wA.z, a3 = x0.w * wA.w;
    a0 = fmaf(x1.x, wB.x, a0); a1 = fmaf(x1.y, wB.y, a1);
    a2 = fmaf(x1.z, wB.z, a2); a3 = fmaf(x1.w, wB.w, a3);
    a0 = fmaf(x2.x, wC.x, a0); a1 = fmaf(x2.y, wC.y, a1);
    a2 = fmaf(x2.z, wC.z, a2); a3 = fmaf(x2.w, wC.w, a3);
    a0 = fmaf(x3.x, wD.x, a0);
    float acc = (a0 + a1) + (a2 + a3);
    h1b[(size_t)n * 64 + l] = f2bf(acc);
    float s = acc * aS, d = acc * aD;
#pragma unroll
    for (int off = 1; off < 8; off <<= 1) {
      s += __shfl_xor(s, off, 64);
      d += __shfl_xor(d, off, 64);
    }
    if ((l & 7) == 0) { as1[n * 8 + (l >> 3)] = s; ad1[n * 8 + (l >> 3)] = d; }
  }
}

// ---- CSR build pass A: per-edge rank via histogram atomic (4x ILP) ----
__global__ void k_rank(const int* __restrict__ ei, int* __restrict__ deg,
                       int* __restrict__ rank, int nFrames) {
  int tid = blockIdx.x * blockDim.x + threadIdx.x;
  int T = (nFrames * NE_F) >> 2;
  if (tid >= T) return;
  int gd[4];
#pragma unroll
  for (int i = 0; i < 4; i++) {
    int e = tid + i * T;
    int f = e / NE_F, idx = e - f * NE_F;
    gd[i] = f * NN_F + ei[(size_t)f * 2 * NE_F + NE_F + idx];
  }
  int r[4];
#pragma unroll
  for (int i = 0; i < 4; i++) r[i] = atomicAdd(&deg[gd[i]], 1);
#pragma unroll
  for (int i = 0; i < 4; i++) rank[tid + i * T] = r[i];
}

// ---------------- CSR build: per-block sums ----------------
__global__ void k_scan1(const int* __restrict__ deg, int* __restrict__ bsum, int nNodes) {
  __shared__ int part[256];
  int t = threadIdx.x;
  int i = blockIdx.x * 256 + t;
  part[t] = (i < nNodes) ? deg[i] : 0;
  __syncthreads();
  for (int off = 128; off > 0; off >>= 1) {
    if (t < off) part[t] += part[t + off];
    __syncthreads();
  }
  if (t == 0) bsum[blockIdx.x] = part[0];
}

// ---------------- CSR build: scan of block sums (single block, up to 1024) ----------------
__global__ void __launch_bounds__(1024)
k_scan2(const int* __restrict__ bsum, int* __restrict__ boff, int nblk) {
  __shared__ int part[1024];
  int t = threadIdx.x;
  part[t] = (t < nblk) ? bsum[t] : 0;
  __syncthreads();
  for (int off = 1; off < 1024; off <<= 1) {
    int v = (t >= off) ? part[t - off] : 0;
    __syncthreads();
    part[t] += v;
    __syncthreads();
  }
  if (t < nblk) boff[t] = part[t] - bsum[t];  // exclusive
}

// ---------------- CSR build: intra-block scan -> rowptr ----------------
__global__ void k_scan3(const int* __restrict__ deg, const int* __restrict__ boff,
                        int* __restrict__ rowptr, int nNodes, int nEdges) {
  __shared__ int part[256];
  int t = threadIdx.x;
  int i = blockIdx.x * 256 + t;
  int d = (i < nNodes) ? deg[i] : 0;
  part[t] = d;
  __syncthreads();
  for (int off = 1; off < 256; off <<= 1) {
    int v = (t >= off) ? part[t - off] : 0;
    __syncthreads();
    part[t] += v;
    __syncthreads();
  }
  if (i < nNodes) rowptr[i] = boff[blockIdx.x] + part[t] - d;  // exclusive prefix
  if (blockIdx.x == 0 && t == 0) rowptr[nNodes] = nEdges;
}

// ---- CSR build pass B: place srcs (NO atomics; 4x ILP) ----
__global__ void k_place(const int* __restrict__ ei, const int* __restrict__ rowptr,
                        const int* __restrict__ rank, int* __restrict__ csr, int nFrames) {
  int tid = blockIdx.x * blockDim.x + threadIdx.x;
  int T = (nFrames * NE_F) >> 2;
  if (tid >= T) return;
#pragma unroll
  for (int i = 0; i < 4; i++) {
    int e = tid + i * T;
    int f = e / NE_F, idx = e - f * NE_F;
    const int* base = ei + (size_t)f * 2 * NE_F;
    int src = base[idx], dst = base[NE_F + idx];
    csr[rowptr[f * NN_F + dst] + rank[e]] = f * NN_F + src;
  }
}

// ---- GAT layer 1 aggregation: wave per dst, 8 edge-groups x 8 lanes (head = q) ----
// feature rows gathered as bf16 (128 B/row)
__global__ void __launch_bounds__(256)
k_agg1(const int* __restrict__ rowptr, const int* __restrict__ csr,
       const unsigned short* __restrict__ h1b, const float* __restrict__ as1,
       const float* __restrict__ ad1, float* __restrict__ out1, int nNodes) {
  int wid = (blockIdx.x * blockDim.x + threadIdx.x) >> 6;
  if (wid >= nNodes) return;
  int l = threadIdx.x & 63;
  int g = l >> 3, q = l & 7;          // group g handles edges i%8==g; lane q owns head q
  float adv = ad1[wid * 8 + q];
  float a0, a1, a2, a3, a4, a5, a6, a7, den;
  if (g == 0) {
    float e0 = expf(lrelu02(as1[wid * 8 + q] + adv));
    uint4 pv = *reinterpret_cast<const uint4*>(h1b + (size_t)wid * 64 + q * 8);
    a0 = e0 * bf_lo(pv.x); a1 = e0 * bf_hi(pv.x);
    a2 = e0 * bf_lo(pv.y); a3 = e0 * bf_hi(pv.y);
    a4 = e0 * bf_lo(pv.z); a5 = e0 * bf_hi(pv.z);
    a6 = e0 * bf_lo(pv.w); a7 = e0 * bf_hi(pv.w);
    den = e0;
  } else {
    a0 = a1 = a2 = a3 = a4 = a5 = a6 = a7 = 0.f; den = 0.f;
  }
  int s0 = rowptr[wid], s1 = rowptr[wid + 1];
  for (int i = s0 + g; i < s1; i += 8) {
    int src = csr[i];
    float e2 = expf(lrelu02(as1[src * 8 + q] + adv));
    uint4 pv = *reinterpret_cast<const uint4*>(h1b + (size_t)src * 64 + q * 8);
    a0 = fmaf(e2, bf_lo(pv.x), a0); a1 = fmaf(e2, bf_hi(pv.x), a1);
    a2 = fmaf(e2, bf_lo(pv.y), a2); a3 = fmaf(e2, bf_hi(pv.y), a3);
    a4 = fmaf(e2, bf_lo(pv.z), a4); a5 = fmaf(e2, bf_hi(pv.z), a5);
    a6 = fmaf(e2, bf_lo(pv.w), a6); a7 = fmaf(e2, bf_hi(pv.w), a7);
    den += e2;
  }
#pragma unroll
  for (int off = 8; off <= 32; off <<= 1) {
    a0 += __shfl_xor(a0, off, 64); a1 += __shfl_xor(a1, off, 64);
    a2 += __shfl_xor(a2, off, 64); a3 += __shfl_xor(a3, off, 64);
    a4 += __shfl_xor(a4, off, 64); a5 += __shfl_xor(a5, off, 64);
    a6 += __shfl_xor(a6, off, 64); a7 += __shfl_xor(a7, off, 64);
    den += __shfl_xor(den, off, 64);
  }
  if (g == 0) {
    float inv = 1.f / den;
    size_t nb = (size_t)wid * 64 + q * 8;
    float4 r0 = make_float4(a0 * inv, a1 * inv, a2 * inv, a3 * inv);
    float4 r1 = make_float4(a4 * inv, a5 * inv, a6 * inv, a7 * inv);
    *reinterpret_cast<float4*>(&out1[nb]) = r0;
    *reinterpret_cast<float4*>(&out1[nb + 4]) = r1;
  }
}

// ---------------- bias + ELU + GAT2 linear + att feats; g written as bf16 ----------------
__global__ void __launch_bounds__(256, 3)
k_node2(const float* __restrict__ out1, const float* __restrict__ b1,
        const float* __restrict__ W2, const float* __restrict__ attS2,
        const float* __restrict__ attD2, unsigned short* __restrict__ gb,
        float* __restrict__ as2, float* __restrict__ ad2, int nNodes) {
  __shared__ float hbuf[4][64];
  int l = threadIdx.x & 63;
  int w = threadIdx.x >> 6;
  int wid = (blockIdx.x * blockDim.x + threadIdx.x) >> 6;
  int nw = (gridDim.x * blockDim.x) >> 6;
  const float4* W4 = reinterpret_cast<const float4*>(&W2[l * 64]);
  float4 w0 = W4[0],  w1 = W4[1],  w2 = W4[2],  w3 = W4[3];
  float4 w4 = W4[4],  w5 = W4[5],  w6 = W4[6],  w7 = W4[7];
  float4 w8 = W4[8],  w9 = W4[9],  w10 = W4[10], w11 = W4[11];
  float4 w12 = W4[12], w13 = W4[13], w14 = W4[14], w15 = W4[15];
  float aS = attS2[l], aD = attD2[l], bb = b1[l];
  const float4* hb = reinterpret_cast<const float4*>(hbuf[w]);
  for (int n = wid; n < nNodes; n += nw) {
    float v = out1[(size_t)n * 64 + l] + bb;
    float hh = v > 0.f ? v : expm1f(v);
    hbuf[w][l] = hh;
    float a0 = 0.f, a1 = 0.f, a2 = 0.f, a3 = 0.f;
#define NSTEP(i, wv) { float4 hv = hb[i]; \
    a0 = fmaf(hv.x, wv.x, a0); a1 = fmaf(hv.y, wv.y, a1); \
    a2 = fmaf(hv.z, wv.z, a2); a3 = fmaf(hv.w, wv.w, a3); }
    NSTEP(0, w0)  NSTEP(1, w1)  NSTEP(2, w2)  NSTEP(3, w3)
    NSTEP(4, w4)  NSTEP(5, w5)  NSTEP(6, w6)  NSTEP(7, w7)
    NSTEP(8, w8)  NSTEP(9, w9)  NSTEP(10, w10) NSTEP(11, w11)
    NSTEP(12, w12) NSTEP(13, w13) NSTEP(14, w14) NSTEP(15, w15)
#undef NSTEP
    float acc = (a0 + a1) + (a2 + a3);
    gb[(size_t)n * 64 + l] = f2bf(acc);
    float s2 = acc * aS, d2 = acc * aD;
#pragma unroll
    for (int off = 32; off > 0; off >>= 1) {
      s2 += __shfl_xor(s2, off, 64);
      d2 += __shfl_xor(d2, off, 64);
    }
    if (l == 0) { as2[n] = s2; ad2[n] = d2; }
  }
}

// ---- GAT layer 2 aggregation FUSED with frame mean: bf16 feature gathers ----
__global__ void __launch_bounds__(256)
k_agg2mean(const int* __restrict__ rowptr, const int* __restrict__ csr,
           const unsigned short* __restrict__ gtab, const float* __restrict__ as2,
           const float* __restrict__ ad2, float* __restrict__ emb) {
  __shared__ float part[4][64];
  int t = threadIdx.x;
  int w = t >> 6, l = t & 63;
  int g = l >> 3, q = l & 7;
  int f = blockIdx.x / BPF;
  int wf = (blockIdx.x - f * BPF) * 4 + w;        // wave id within frame [0, BPF*4)
  float m0 = 0.f, m1 = 0.f, m2 = 0.f, m3 = 0.f, m4 = 0.f, m5 = 0.f, m6 = 0.f, m7 = 0.f;
  for (int j = wf; j < NN_F; j += BPF * 4) {
    int n = f * NN_F + j;
    float adv = ad2[n];
    float a0, a1, a2, a3, a4, a5, a6, a7, den;
    if (g == 0) {
      float e0 = expf(lrelu02(as2[n] + adv));
      uint4 pv = *reinterpret_cast<const uint4*>(gtab + (size_t)n * 64 + q * 8);
      a0 = e0 * bf_lo(pv.x); a1 = e0 * bf_hi(pv.x);
      a2 = e0 * bf_lo(pv.y); a3 = e0 * bf_hi(pv.y);
      a4 = e0 * bf_lo(pv.z); a5 = e0 * bf_hi(pv.z);
      a6 = e0 * bf_lo(pv.w); a7 = e0 * bf_hi(pv.w);
      den = e0;
    } else {
      a0 = a1 = a2 = a3 = a4 = a5 = a6 = a7 = 0.f; den = 0.f;
    }
    int s0 = rowptr[n], s1 = rowptr[n + 1];
    for (int i = s0 + g; i < s1; i += 8) {
      int src = csr[i];
      float e2 = expf(lrelu02(as2[src] + adv));
      uint4 pv = *reinterpret_cast<const uint4*>(gtab + (size_t)src * 64 + q * 8);
      a0 = fmaf(e2, bf_lo(pv.x), a0); a1 = fmaf(e2, bf_hi(pv.x), a1);
      a2 = fmaf(e2, bf_lo(pv.y), a2); a3 = fmaf(e2, bf_hi(pv.y), a3);
      a4 = fmaf(e2, bf_lo(pv.z), a4); a5 = fmaf(e2, bf_hi(pv.z), a5);
      a6 = fmaf(e2, bf_lo(pv.w), a6); a7 = fmaf(e2, bf_hi(pv.w), a7);
      den += e2;
    }
#pragma unroll
    for (int off = 8; off <= 32; off <<= 1) {
      a0 += __shfl_xor(a0, off, 64); a1 += __shfl_xor(a1, off, 64);
      a2 += __shfl_xor(a2, off, 64); a3 += __shfl_xor(a3, off, 64);
      a4 += __shfl_xor(a4, off, 64); a5 += __shfl_xor(a5, off, 64);
      a6 += __shfl_xor(a6, off, 64); a7 += __shfl_xor(a7, off, 64);
      den += __shfl_xor(den, off, 64);
    }
    float inv = 1.f / den;
    m0 = fmaf(a0, inv, m0); m1 = fmaf(a1, inv, m1);
    m2 = fmaf(a2, inv, m2); m3 = fmaf(a3, inv, m3);
    m4 = fmaf(a4, inv, m4); m5 = fmaf(a5, inv, m5);
    m6 = fmaf(a6, inv, m6); m7 = fmaf(a7, inv, m7);
  }
  if (g == 0) {
    part[w][q * 8 + 0] = m0; part[w][q * 8 + 1] = m1;
    part[w][q * 8 + 2] = m2; part[w][q * 8 + 3] = m3;
    part[w][q * 8 + 4] = m4; part[w][q * 8 + 5] = m5;
    part[w][q * 8 + 6] = m6; part[w][q * 8 + 7] = m7;
  }
  __syncthreads();
  if (w == 0)
    atomicAdd(&emb[f * 64 + l],
              (part[0][l] + part[1][l] + part[2][l] + part[3][l]) * (1.0f / NN_F));
}

// ---------------- tiny transformer: 1024 threads, 16-lane-group shuffle GEMVs ----------
__device__ __forceinline__ float grp16_reduce(float p) {
#pragma unroll
  for (int off = 1; off < 16; off <<= 1) p += __shfl_xor(p, off, 64);
  return p;
}

__global__ void __launch_bounds__(1024)
k_transformer(const float* __restrict__ emb, const float* __restrict__ b2,
              const float* __restrict__ Wqkv, const float* __restrict__ bqkv,
              const float* __restrict__ Wo, const float* __restrict__ bo,
              const float* __restrict__ ln1w, const float* __restrict__ ln1b,
              const float* __restrict__ Wff1, const float* __restrict__ bff1,
              const float* __restrict__ Wff2, const float* __restrict__ bff2,
              const float* __restrict__ ln2w, const float* __restrict__ ln2b,
              const float* __restrict__ Wh1, const float* __restrict__ bh1,
              const float* __restrict__ Wh2, const float* __restrict__ bh2,
              float* __restrict__ out) {
  __shared__ float seq[5][64];
  __shared__ float qkv[5][192];
  __shared__ float att[4][5][5];
  __shared__ float aob[5][64];
  __shared__ float ffb[5][128];
  __shared__ float tmp[5][64];
  __shared__ float hid[32];
  int t = threadIdx.x;
  int l = t & 63, w = t >> 6;        // 16 waves
  int g = l >> 4, q = l & 15;        // 4 groups of 16 lanes

  if (t < 320) seq[t >> 6][t & 63] = emb[t] + b2[t & 63];
  __syncthreads();

  for (int ly = 0; ly < 3; ly++) {
    const float* Wq  = Wqkv + ly * 12288; const float* bq  = bqkv + ly * 192;
    const float* Wol = Wo   + ly * 4096;  const float* bol = bo   + ly * 64;
    const float* w1  = ln1w + ly * 64;    const float* bb1 = ln1b + ly * 64;
    const float* Wf1 = Wff1 + ly * 8192;  const float* bf1 = bff1 + ly * 128;
    const float* Wf2 = Wff2 + ly * 8192;  const float* bf2 = bff2 + ly * 64;
    const float* w2  = ln2w + ly * 64;    const float* bb2 = ln2b + ly * 64;

    for (int o = w * 4 + g; o < 960; o += 64) {
      int s = o / 192, j = o - s * 192;
      float4 wv = *reinterpret_cast<const float4*>(&Wq[j * 64 + q * 4]);
      float4 xv = *reinterpret_cast<const float4*>(&seq[s][q * 4]);
      float p = wv.x * xv.x + wv.y * xv.y + wv.z * xv.z + wv.w * xv.w;
      p = grp16_reduce(p);
      if (q == 0) qkv[s][j] = p + bq[j];
    }
    __syncthreads();

    if (t < 100) {
      int hh = t / 25, qs = (t / 5) % 5, ks = t % 5;
      float acc = 0.f;
      for (int d = 0; d < 16; d++)
        acc = fmaf(qkv[qs][hh * 16 + d], qkv[ks][64 + hh * 16 + d], acc);
      att[hh][qs][ks] = acc * 0.25f;
    }
    __syncthreads();
    if (t < 20) {
      int hh = t / 5, qs = t % 5;
      float m = att[hh][qs][0];
      for (int k2 = 1; k2 < 5; k2++) m = fmaxf(m, att[hh][qs][k2]);
      float ss = 0.f;
      for (int k2 = 0; k2 < 5; k2++) { float v = expf(att[hh][qs][k2] - m); att[hh][qs][k2] = v; ss += v; }
      float inv = 1.f / ss;
      for (int k2 = 0; k2 < 5; k2++) att[hh][qs][k2] *= inv;
    }
    __syncthreads();

    if (t < 320) {
      int s = t >> 6, j = t & 63, hh = j >> 4;
      float acc = 0.f;
      for (int k2 = 0; k2 < 5; k2++) acc = fmaf(att[hh][s][k2], qkv[k2][128 + j], acc);
      aob[s][j] = acc;
    }
    __syncthreads();

    for (int o = w * 4 + g; o < 320; o += 64) {
      int s = o >> 6, c = o & 63;
      float4 wv = *reinterpret_cast<const float4*>(&Wol[c * 64 + q * 4]);
      float4 xv = *reinterpret_cast<const float4*>(&aob[s][q * 4]);
      float p = wv.x * xv.x + wv.y * xv.y + wv.z * xv.z + wv.w * xv.w;
      p = grp16_reduce(p);
      if (q == 0) tmp[s][c] = seq[s][c] + p + bol[c];
    }
    __syncthreads();

    if (w < 5) {
      float v = tmp[w][l];
      float s1 = v, s2 = v * v;
#pragma unroll
      for (int off = 1; off < 64; off <<= 1) {
        s1 += __shfl_xor(s1, off, 64);
        s2 += __shfl_xor(s2, off, 64);
      }
      float m = s1 * (1.f / 64.f);
      float var = s2 * (1.f / 64.f) - m * m;
      float inv = 1.f / sqrtf(var + 1e-5f);
      seq[w][l] = (v - m) * inv * w1[l] + bb1[l];
    }
    __syncthreads();

    for (int o = w * 4 + g; o < 640; o += 64) {
      int s = o >> 7, j = o & 127;
      float4 wv = *reinterpret_cast<const float4*>(&Wf1[j * 64 + q * 4]);
      float4 xv = *reinterpret_cast<const float4*>(&seq[s][q * 4]);
      float p = wv.x * xv.x + wv.y * xv.y + wv.z * xv.z + wv.w * xv.w;
      p = grp16_reduce(p);
      if (q == 0) ffb[s][j] = fmaxf(p + bf1[j], 0.f);
    }
    __syncthreads();

    for (int o = w * 4 + g; o < 320; o += 64) {
      int s = o >> 6, c = o & 63;
      float4 wa = *reinterpret_cast<const float4*>(&Wf2[c * 128 + q * 8]);
      float4 wb = *reinterpret_cast<const float4*>(&Wf2[c * 128 + q * 8 + 4]);
      float4 xa = *reinterpret_cast<const float4*>(&ffb[s][q * 8]);
      float4 xb = *reinterpret_cast<const float4*>(&ffb[s][q * 8 + 4]);
      float p = wa.x * xa.x + wa.y * xa.y + wa.z * xa.z + wa.w * xa.w
              + wb.x * xb.x + wb.y * xb.y + wb.z * xb.z + wb.w * xb.w;
      p = grp16_reduce(p);
      if (q == 0) tmp[s][c] = seq[s][c] + p + bf2[c];
    }
    __syncthreads();

    if (w < 5) {
      float v = tmp[w][l];
      float s1 = v, s2 = v * v;
#pragma unroll
      for (int off = 1; off < 64; off <<= 1) {
        s1 += __shfl_xor(s1, off, 64);
        s2 += __shfl_xor(s2, off, 64);
      }
      float m = s1 * (1.f / 64.f);
      float var = s2 * (1.f / 64.f) - m * m;
      float inv = 1.f / sqrtf(var + 1e-5f);
      seq[w][l] = (v - m) * inv * w2[l] + bb2[l];
    }
    __syncthreads();
  }

  for (int o = w * 4 + g; o < 32; o += 64) {
    float4 wv = *reinterpret_cast<const float4*>(&Wh1[o * 64 + q * 4]);
    float4 xv = *reinterpret_cast<const float4*>(&seq[4][q * 4]);
    float p = wv.x * xv.x + wv.y * xv.y + wv.z * xv.z + wv.w * xv.w;
    p = grp16_reduce(p);
    if (q == 0) hid[o] = fmaxf(p + bh1[o], 0.f);
  }
  __syncthreads();
  if (t < 2) {
    float acc = bh2[t];
    for (int j = 0; j < 32; j++) acc = fmaf(hid[j], Wh2[t * 32 + j], acc);
    out[t] = acc;
  }
}

extern "C" void kernel_launch(void* const* d_in, const int* in_sizes, int n_in,
                              void* d_out, int out_size, void* d_ws, size_t ws_size,
                              hipStream_t stream) {
  const float* x     = (const float*)d_in[0];
  const int*   ei    = (const int*)d_in[1];
  const float* W1    = (const float*)d_in[2];
  const float* attS1 = (const float*)d_in[3];
  const float* attD1 = (const float*)d_in[4];
  const float* b1    = (const float*)d_in[5];
  const float* W2    = (const float*)d_in[6];
  const float* attS2 = (const float*)d_in[7];
  const float* attD2 = (const float*)d_in[8];
  const float* b2    = (const float*)d_in[9];
  const float* tWqkv = (const float*)d_in[10];
  const float* tbqkv = (const float*)d_in[11];
  const float* tWo   = (const float*)d_in[12];
  const float* tbo   = (const float*)d_in[13];
  const float* tln1w = (const float*)d_in[14];
  const float* tln1b = (const float*)d_in[15];
  const float* tWff1 = (const float*)d_in[16];
  const float* tbff1 = (const float*)d_in[17];
  const float* tWff2 = (const float*)d_in[18];
  const float* tbff2 = (const float*)d_in[19];
  const float* tln2w = (const float*)d_in[20];
  const float* tln2b = (const float*)d_in[21];
  const float* Wh1   = (const float*)d_in[22];
  const float* bh1   = (const float*)d_in[23];
  const float* Wh2   = (const float*)d_in[24];
  const float* bh2   = (const float*)d_in[25];
  float* out = (float*)d_out;

  // floats: out1 NT*64 + as1/ad1 NT*16 + as2/ad2 NT*2 + emb 320
  // ushorts (bf16): h1b NT*64 + gb NT*64
  // ints: deg NT + rowptr NT+1 + bsum/boff 2048 + rank ET + csr ET
  auto need_bytes = [](int F) -> size_t {
    size_t NT = (size_t)F * NN_F, ET = (size_t)F * NE_F;
    size_t fl = NT * 82 + 320;
    size_t us = NT * 128;
    size_t it = NT * 2 + 1 + 2048 + ET * 2;
    return fl * 4 + us * 2 + it * 4;
  };
  const int F = (ws_size >= need_bytes(5)) ? 5 : 1;
  const int NT = F * NN_F, ET = F * NE_F;

  float* ws  = (float*)d_ws;
  float* acc = ws;                          // NT*64 (out1)
  float* as1 = acc + (size_t)NT * 64;       // NT*8
  float* ad1 = as1 + (size_t)NT * 8;        // NT*8
  float* as2 = ad1 + (size_t)NT * 8;        // NT
  float* ad2 = as2 + NT;                    // NT
  float* emb = ad2 + NT;                    // 320
  unsigned short* h1b = (unsigned short*)(emb + 320);  // NT*64 bf16
  unsigned short* gb  = h1b + (size_t)NT * 64;         // NT*64 bf16
  int* deg    = (int*)(gb + (size_t)NT * 64);          // NT
  int* rowptr = deg + NT;                   // NT+1
  int* bsum   = rowptr + NT + 1;            // <=1024
  int* boff   = bsum + 1024;                // <=1024
  int* rank   = boff + 1024;                // ET
  int* csr    = rank + ET;                  // ET

  (void)hipMemsetAsync(emb, 0, 320 * sizeof(float), stream);

  const int nblk = (NT + 255) / 256;
  const int edge4Blocks = ((ET >> 2) + 255) / 256;
  const int aggBlocks = (NT + 3) / 4;       // wave per node, 4 waves/block
  const int nodeBlocks = 2048;

  for (int f0 = 0; f0 < 5; f0 += F) {
    const float* xf = x + (size_t)f0 * NN_F * 13;
    const int* eif  = ei + (size_t)f0 * 2 * NE_F;

    (void)hipMemsetAsync(deg, 0, NT * sizeof(int), stream);
    k_rank<<<edge4Blocks, 256, 0, stream>>>(eif, deg, rank, F);
    k_scan1<<<nblk, 256, 0, stream>>>(deg, bsum, NT);
    k_scan2<<<1, 1024, 0, stream>>>(bsum, boff, nblk);
    k_scan3<<<nblk, 256, 0, stream>>>(deg, boff, rowptr, NT, ET);
    k_place<<<edge4Blocks, 256, 0, stream>>>(eif, rowptr, rank, csr, F);

    k_node1<<<nodeBlocks, 256, 0, stream>>>(xf, W1, attS1, attD1, h1b, as1, ad1, NT);
    k_agg1<<<aggBlocks, 256, 0, stream>>>(rowptr, csr, h1b, as1, ad1, acc, NT);
    k_node2<<<nodeBlocks, 256, 0, stream>>>(acc, b1, W2, attS2, attD2, gb, as2, ad2, NT);
    k_agg2mean<<<F * BPF, 256, 0, stream>>>(rowptr, csr, gb, as2, ad2, emb + f0 * 64);
  }

  k_transformer<<<1, 1024, 0, stream>>>(emb, b2, tWqkv, tbqkv, tWo, tbo, tln1w, tln1b,
                                        tWff1, tbff1, tWff2, tbff2, tln2w, tln2b,
                                        Wh1, bh1, Wh2, bh2, out);
}

// Round 9
// 508.750 us; speedup vs baseline: 4.0177x; 1.0051x over previous
//
#include <hip/hip_runtime.h>
#include <math.h>

#define NN_F 50000      // nodes per frame
#define NE_F 400000     // edges per frame
#define BPF  1536       // blocks per frame for fused agg2+mean

__device__ __forceinline__ float lrelu02(float x) { return x > 0.f ? x : 0.2f * x; }
// fast exp: native v_exp_f32 (2^x) with log2e scale; ~1e-6 rel error
__device__ __forceinline__ float fexp(float x) { return __expf(x); }

// bf16 pack (RNE) / unpack helpers
__device__ __forceinline__ unsigned short f2bf(float f) {
  unsigned int u = __float_as_uint(f);
  u += 0x7fffu + ((u >> 16) & 1u);
  return (unsigned short)(u >> 16);
}
__device__ __forceinline__ float bf_lo(unsigned int u) { return __uint_as_float(u << 16); }
__device__ __forceinline__ float bf_hi(unsigned int u) { return __uint_as_float(u & 0xffff0000u); }
__device__ __forceinline__ unsigned int pack2(float a, float b) {
  return (unsigned int)f2bf(a) | ((unsigned int)f2bf(b) << 16);
}

// ---------------- GAT layer 1: wave per node, lane = output channel ----------------
__global__ void __launch_bounds__(256, 3)
k_node1(const float* __restrict__ x, const float* __restrict__ W1,
        const float* __restrict__ attS, const float* __restrict__ attD,
        unsigned short* __restrict__ h1b, float* __restrict__ as1, float* __restrict__ ad1,
        int nNodes) {
  __shared__ float xbuf[4][16];
  int l = threadIdx.x & 63;
  int w = threadIdx.x >> 6;
  int wid = (blockIdx.x * blockDim.x + threadIdx.x) >> 6;
  int nw = (gridDim.x * blockDim.x) >> 6;
  float4 wA = make_float4(W1[l * 13 + 0], W1[l * 13 + 1], W1[l * 13 + 2], W1[l * 13 + 3]);
  float4 wB = make_float4(W1[l * 13 + 4], W1[l * 13 + 5], W1[l * 13 + 6], W1[l * 13 + 7]);
  float4 wC = make_float4(W1[l * 13 + 8], W1[l * 13 + 9], W1[l * 13 + 10], W1[l * 13 + 11]);
  float4 wD = make_float4(W1[l * 13 + 12], 0.f, 0.f, 0.f);
  float aS = attS[l], aD = attD[l];
  const float4* xb = reinterpret_cast<const float4*>(xbuf[w]);
  for (int n = wid; n < nNodes; n += nw) {
    if (l < 16) xbuf[w][l] = (l < 13) ? x[(size_t)n * 13 + l] : 0.f;
    float4 x0 = xb[0], x1 = xb[1], x2 = xb[2], x3 = xb[3];
    float a0 = x0.x * wA.x, a1 = x0.y * wA.y, a2 = x0.z * wA.z, a3 = x0.w * wA.w;
    a0 = fmaf(x1.x, wB.x, a0); a1 = fmaf(x1.y, wB.y, a1);
    a2 = fmaf(x1.z, wB.z, a2); a3 = fmaf(x1.w, wB.w, a3);
    a0 = fmaf(x2.x, wC.x, a0); a1 = fmaf(x2.y, wC.y, a1);
    a2 = fmaf(x2.z, wC.z, a2); a3 = fmaf(x2.w, wC.w, a3);
    a0 = fmaf(x3.x, wD.x, a0);
    float acc = (a0 + a1) + (a2 + a3);
    h1b[(size_t)n * 64 + l] = f2bf(acc);
    float s = acc * aS, d = acc * aD;
#pragma unroll
    for (int off = 1; off < 8; off <<= 1) {
      s += __shfl_xor(s, off, 64);
      d += __shfl_xor(d, off, 64);
    }
    if ((l & 7) == 0) { as1[n * 8 + (l >> 3)] = s; ad1[n * 8 + (l >> 3)] = d; }
  }
}

// ---- CSR build pass A: per-edge rank via histogram atomic (4x ILP) ----
__global__ void k_rank(const int* __restrict__ ei, int* __restrict__ deg,
                       int* __restrict__ rank, int nFrames) {
  int tid = blockIdx.x * blockDim.x + threadIdx.x;
  int T = (nFrames * NE_F) >> 2;
  if (tid >= T) return;
  int gd[4];
#pragma unroll
  for (int i = 0; i < 4; i++) {
    int e = tid + i * T;
    int f = e / NE_F, idx = e - f * NE_F;
    gd[i] = f * NN_F + ei[(size_t)f * 2 * NE_F + NE_F + idx];
  }
  int r[4];
#pragma unroll
  for (int i = 0; i < 4; i++) r[i] = atomicAdd(&deg[gd[i]], 1);
#pragma unroll
  for (int i = 0; i < 4; i++) rank[tid + i * T] = r[i];
}

// ---------------- CSR build: per-block sums ----------------
__global__ void k_scan1(const int* __restrict__ deg, int* __restrict__ bsum, int nNodes) {
  __shared__ int part[256];
  int t = threadIdx.x;
  int i = blockIdx.x * 256 + t;
  part[t] = (i < nNodes) ? deg[i] : 0;
  __syncthreads();
  for (int off = 128; off > 0; off >>= 1) {
    if (t < off) part[t] += part[t + off];
    __syncthreads();
  }
  if (t == 0) bsum[blockIdx.x] = part[0];
}

// ---------------- CSR build: scan of block sums (single block, up to 1024) ----------------
__global__ void __launch_bounds__(1024)
k_scan2(const int* __restrict__ bsum, int* __restrict__ boff, int nblk) {
  __shared__ int part[1024];
  int t = threadIdx.x;
  part[t] = (t < nblk) ? bsum[t] : 0;
  __syncthreads();
  for (int off = 1; off < 1024; off <<= 1) {
    int v = (t >= off) ? part[t - off] : 0;
    __syncthreads();
    part[t] += v;
    __syncthreads();
  }
  if (t < nblk) boff[t] = part[t] - bsum[t];  // exclusive
}

// ---------------- CSR build: intra-block scan -> rowptr ----------------
__global__ void k_scan3(const int* __restrict__ deg, const int* __restrict__ boff,
                        int* __restrict__ rowptr, int nNodes, int nEdges) {
  __shared__ int part[256];
  int t = threadIdx.x;
  int i = blockIdx.x * 256 + t;
  int d = (i < nNodes) ? deg[i] : 0;
  part[t] = d;
  __syncthreads();
  for (int off = 1; off < 256; off <<= 1) {
    int v = (t >= off) ? part[t - off] : 0;
    __syncthreads();
    part[t] += v;
    __syncthreads();
  }
  if (i < nNodes) rowptr[i] = boff[blockIdx.x] + part[t] - d;  // exclusive prefix
  if (blockIdx.x == 0 && t == 0) rowptr[nNodes] = nEdges;
}

// ---- CSR build pass B: place srcs (NO atomics; 4x ILP) ----
__global__ void k_place(const int* __restrict__ ei, const int* __restrict__ rowptr,
                        const int* __restrict__ rank, int* __restrict__ csr, int nFrames) {
  int tid = blockIdx.x * blockDim.x + threadIdx.x;
  int T = (nFrames * NE_F) >> 2;
  if (tid >= T) return;
#pragma unroll
  for (int i = 0; i < 4; i++) {
    int e = tid + i * T;
    int f = e / NE_F, idx = e - f * NE_F;
    const int* base = ei + (size_t)f * 2 * NE_F;
    int src = base[idx], dst = base[NE_F + idx];
    csr[rowptr[f * NN_F + dst] + rank[e]] = f * NN_F + src;
  }
}

// ---- GAT layer 1 aggregation: wave per dst, 8 edge-groups x 8 lanes (head = q) ----
// bf16 feature gathers; bf16 output (re-read once by k_node2)
__global__ void __launch_bounds__(256)
k_agg1(const int* __restrict__ rowptr, const int* __restrict__ csr,
       const unsigned short* __restrict__ h1b, const float* __restrict__ as1,
       const float* __restrict__ ad1, unsigned short* __restrict__ out1b, int nNodes) {
  int wid = (blockIdx.x * blockDim.x + threadIdx.x) >> 6;
  if (wid >= nNodes) return;
  int l = threadIdx.x & 63;
  int g = l >> 3, q = l & 7;          // group g handles edges i%8==g; lane q owns head q
  float adv = ad1[wid * 8 + q];
  float a0, a1, a2, a3, a4, a5, a6, a7, den;
  if (g == 0) {
    float e0 = fexp(lrelu02(as1[wid * 8 + q] + adv));
    uint4 pv = *reinterpret_cast<const uint4*>(h1b + (size_t)wid * 64 + q * 8);
    a0 = e0 * bf_lo(pv.x); a1 = e0 * bf_hi(pv.x);
    a2 = e0 * bf_lo(pv.y); a3 = e0 * bf_hi(pv.y);
    a4 = e0 * bf_lo(pv.z); a5 = e0 * bf_hi(pv.z);
    a6 = e0 * bf_lo(pv.w); a7 = e0 * bf_hi(pv.w);
    den = e0;
  } else {
    a0 = a1 = a2 = a3 = a4 = a5 = a6 = a7 = 0.f; den = 0.f;
  }
  int s0 = rowptr[wid], s1 = rowptr[wid + 1];
  for (int i = s0 + g; i < s1; i += 8) {
    int src = csr[i];
    float e2 = fexp(lrelu02(as1[src * 8 + q] + adv));
    uint4 pv = *reinterpret_cast<const uint4*>(h1b + (size_t)src * 64 + q * 8);
    a0 = fmaf(e2, bf_lo(pv.x), a0); a1 = fmaf(e2, bf_hi(pv.x), a1);
    a2 = fmaf(e2, bf_lo(pv.y), a2); a3 = fmaf(e2, bf_hi(pv.y), a3);
    a4 = fmaf(e2, bf_lo(pv.z), a4); a5 = fmaf(e2, bf_hi(pv.z), a5);
    a6 = fmaf(e2, bf_lo(pv.w), a6); a7 = fmaf(e2, bf_hi(pv.w), a7);
    den += e2;
  }
#pragma unroll
  for (int off = 8; off <= 32; off <<= 1) {
    a0 += __shfl_xor(a0, off, 64); a1 += __shfl_xor(a1, off, 64);
    a2 += __shfl_xor(a2, off, 64); a3 += __shfl_xor(a3, off, 64);
    a4 += __shfl_xor(a4, off, 64); a5 += __shfl_xor(a5, off, 64);
    a6 += __shfl_xor(a6, off, 64); a7 += __shfl_xor(a7, off, 64);
    den += __shfl_xor(den, off, 64);
  }
  if (g == 0) {
    float inv = 1.f / den;
    uint4 o;
    o.x = pack2(a0 * inv, a1 * inv);
    o.y = pack2(a2 * inv, a3 * inv);
    o.z = pack2(a4 * inv, a5 * inv);
    o.w = pack2(a6 * inv, a7 * inv);
    *reinterpret_cast<uint4*>(out1b + (size_t)wid * 64 + q * 8) = o;
  }
}

// ---------------- bias + ELU + GAT2 linear + att feats; bf16 in, bf16 out ----------------
__global__ void __launch_bounds__(256, 3)
k_node2(const unsigned short* __restrict__ out1b, const float* __restrict__ b1,
        const float* __restrict__ W2, const float* __restrict__ attS2,
        const float* __restrict__ attD2, unsigned short* __restrict__ gb,
        float* __restrict__ as2, float* __restrict__ ad2, int nNodes) {
  __shared__ float hbuf[4][64];
  int l = threadIdx.x & 63;
  int w = threadIdx.x >> 6;
  int wid = (blockIdx.x * blockDim.x + threadIdx.x) >> 6;
  int nw = (gridDim.x * blockDim.x) >> 6;
  const float4* W4 = reinterpret_cast<const float4*>(&W2[l * 64]);
  float4 w0 = W4[0],  w1 = W4[1],  w2 = W4[2],  w3 = W4[3];
  float4 w4 = W4[4],  w5 = W4[5],  w6 = W4[6],  w7 = W4[7];
  float4 w8 = W4[8],  w9 = W4[9],  w10 = W4[10], w11 = W4[11];
  float4 w12 = W4[12], w13 = W4[13], w14 = W4[14], w15 = W4[15];
  float aS = attS2[l], aD = attD2[l], bb = b1[l];
  const float4* hb = reinterpret_cast<const float4*>(hbuf[w]);
  for (int n = wid; n < nNodes; n += nw) {
    float v = __uint_as_float((unsigned int)out1b[(size_t)n * 64 + l] << 16) + bb;
    float hh = v > 0.f ? v : (fexp(v) - 1.f);
    hbuf[w][l] = hh;
    float a0 = 0.f, a1 = 0.f, a2 = 0.f, a3 = 0.f;
#define NSTEP(i, wv) { float4 hv = hb[i]; \
    a0 = fmaf(hv.x, wv.x, a0); a1 = fmaf(hv.y, wv.y, a1); \
    a2 = fmaf(hv.z, wv.z, a2); a3 = fmaf(hv.w, wv.w, a3); }
    NSTEP(0, w0)  NSTEP(1, w1)  NSTEP(2, w2)  NSTEP(3, w3)
    NSTEP(4, w4)  NSTEP(5, w5)  NSTEP(6, w6)  NSTEP(7, w7)
    NSTEP(8, w8)  NSTEP(9, w9)  NSTEP(10, w10) NSTEP(11, w11)
    NSTEP(12, w12) NSTEP(13, w13) NSTEP(14, w14) NSTEP(15, w15)
#undef NSTEP
    float acc = (a0 + a1) + (a2 + a3);
    gb[(size_t)n * 64 + l] = f2bf(acc);
    float s2 = acc * aS, d2 = acc * aD;
#pragma unroll
    for (int off = 32; off > 0; off >>= 1) {
      s2 += __shfl_xor(s2, off, 64);
      d2 += __shfl_xor(d2, off, 64);
    }
    if (l == 0) { as2[n] = s2; ad2[n] = d2; }
  }
}

// ---- GAT layer 2 aggregation FUSED with frame mean; rowptr-prefetch pipeline ----
__global__ void __launch_bounds__(256)
k_agg2mean(const int* __restrict__ rowptr, const int* __restrict__ csr,
           const unsigned short* __restrict__ gtab, const float* __restrict__ as2,
           const float* __restrict__ ad2, float* __restrict__ emb) {
  __shared__ float part[4][64];
  int t = threadIdx.x;
  int w = t >> 6, l = t & 63;
  int g = l >> 3, q = l & 7;
  int f = blockIdx.x / BPF;
  int wf = (blockIdx.x - f * BPF) * 4 + w;        // wave id within frame [0, BPF*4)
  const int stride = BPF * 4;
  float m0 = 0.f, m1 = 0.f, m2 = 0.f, m3 = 0.f, m4 = 0.f, m5 = 0.f, m6 = 0.f, m7 = 0.f;
  // prefetched row bounds for the first node
  int s0 = rowptr[f * NN_F + wf];
  int s1 = rowptr[f * NN_F + wf + 1];
  for (int j = wf; j < NN_F; j += stride) {
    int n = f * NN_F + j;
    int cs0 = s0, cs1 = s1;
    // issue first-batch csr load immediately
    int i0 = cs0 + g;
    int src0 = (i0 < cs1) ? csr[i0] : -1;
    // prefetch next node's row bounds (overlaps with this node's gathers/compute)
    if (j + stride < NN_F) {
      s0 = rowptr[n + stride];
      s1 = rowptr[n + stride + 1];
    }
    float adv = ad2[n];
    float a0, a1, a2, a3, a4, a5, a6, a7, den;
    if (g == 0) {
      float e0 = fexp(lrelu02(as2[n] + adv));
      uint4 pv = *reinterpret_cast<const uint4*>(gtab + (size_t)n * 64 + q * 8);
      a0 = e0 * bf_lo(pv.x); a1 = e0 * bf_hi(pv.x);
      a2 = e0 * bf_lo(pv.y); a3 = e0 * bf_hi(pv.y);
      a4 = e0 * bf_lo(pv.z); a5 = e0 * bf_hi(pv.z);
      a6 = e0 * bf_lo(pv.w); a7 = e0 * bf_hi(pv.w);
      den = e0;
    } else {
      a0 = a1 = a2 = a3 = a4 = a5 = a6 = a7 = 0.f; den = 0.f;
    }
    if (src0 >= 0) {
      float e2 = fexp(lrelu02(as2[src0] + adv));
      uint4 pv = *reinterpret_cast<const uint4*>(gtab + (size_t)src0 * 64 + q * 8);
      a0 = fmaf(e2, bf_lo(pv.x), a0); a1 = fmaf(e2, bf_hi(pv.x), a1);
      a2 = fmaf(e2, bf_lo(pv.y), a2); a3 = fmaf(e2, bf_hi(pv.y), a3);
      a4 = fmaf(e2, bf_lo(pv.z), a4); a5 = fmaf(e2, bf_hi(pv.z), a5);
      a6 = fmaf(e2, bf_lo(pv.w), a6); a7 = fmaf(e2, bf_hi(pv.w), a7);
      den += e2;
    }
    for (int i = i0 + 8; i < cs1; i += 8) {
      int src = csr[i];
      float e2 = fexp(lrelu02(as2[src] + adv));
      uint4 pv = *reinterpret_cast<const uint4*>(gtab + (size_t)src * 64 + q * 8);
      a0 = fmaf(e2, bf_lo(pv.x), a0); a1 = fmaf(e2, bf_hi(pv.x), a1);
      a2 = fmaf(e2, bf_lo(pv.y), a2); a3 = fmaf(e2, bf_hi(pv.y), a3);
      a4 = fmaf(e2, bf_lo(pv.z), a4); a5 = fmaf(e2, bf_hi(pv.z), a5);
      a6 = fmaf(e2, bf_lo(pv.w), a6); a7 = fmaf(e2, bf_hi(pv.w), a7);
      den += e2;
    }
#pragma unroll
    for (int off = 8; off <= 32; off <<= 1) {
      a0 += __shfl_xor(a0, off, 64); a1 += __shfl_xor(a1, off, 64);
      a2 += __shfl_xor(a2, off, 64); a3 += __shfl_xor(a3, off, 64);
      a4 += __shfl_xor(a4, off, 64); a5 += __shfl_xor(a5, off, 64);
      a6 += __shfl_xor(a6, off, 64); a7 += __shfl_xor(a7, off, 64);
      den += __shfl_xor(den, off, 64);
    }
    float inv = 1.f / den;
    m0 = fmaf(a0, inv, m0); m1 = fmaf(a1, inv, m1);
    m2 = fmaf(a2, inv, m2); m3 = fmaf(a3, inv, m3);
    m4 = fmaf(a4, inv, m4); m5 = fmaf(a5, inv, m5);
    m6 = fmaf(a6, inv, m6); m7 = fmaf(a7, inv, m7);
  }
  if (g == 0) {
    part[w][q * 8 + 0] = m0; part[w][q * 8 + 1] = m1;
    part[w][q * 8 + 2] = m2; part[w][q * 8 + 3] = m3;
    part[w][q * 8 + 4] = m4; part[w][q * 8 + 5] = m5;
    part[w][q * 8 + 6] = m6; part[w][q * 8 + 7] = m7;
  }
  __syncthreads();
  if (w == 0)
    atomicAdd(&emb[f * 64 + l],
              (part[0][l] + part[1][l] + part[2][l] + part[3][l]) * (1.0f / NN_F));
}

// ---------------- tiny transformer: 1024 threads, 16-lane-group shuffle GEMVs ----------
__device__ __forceinline__ float grp16_reduce(float p) {
#pragma unroll
  for (int off = 1; off < 16; off <<= 1) p += __shfl_xor(p, off, 64);
  return p;
}

__global__ void __launch_bounds__(1024)
k_transformer(const float* __restrict__ emb, const float* __restrict__ b2,
              const float* __restrict__ Wqkv, const float* __restrict__ bqkv,
              const float* __restrict__ Wo, const float* __restrict__ bo,
              const float* __restrict__ ln1w, const float* __restrict__ ln1b,
              const float* __restrict__ Wff1, const float* __restrict__ bff1,
              const float* __restrict__ Wff2, const float* __restrict__ bff2,
              const float* __restrict__ ln2w, const float* __restrict__ ln2b,
              const float* __restrict__ Wh1, const float* __restrict__ bh1,
              const float* __restrict__ Wh2, const float* __restrict__ bh2,
              float* __restrict__ out) {
  __shared__ float seq[5][64];
  __shared__ float qkv[5][192];
  __shared__ float att[4][5][5];
  __shared__ float aob[5][64];
  __shared__ float ffb[5][128];
  __shared__ float tmp[5][64];
  __shared__ float hid[32];
  int t = threadIdx.x;
  int l = t & 63, w = t >> 6;        // 16 waves
  int g = l >> 4, q = l & 15;        // 4 groups of 16 lanes

  if (t < 320) seq[t >> 6][t & 63] = emb[t] + b2[t & 63];
  __syncthreads();

  for (int ly = 0; ly < 3; ly++) {
    const float* Wq  = Wqkv + ly * 12288; const float* bq  = bqkv + ly * 192;
    const float* Wol = Wo   + ly * 4096;  const float* bol = bo   + ly * 64;
    const float* w1  = ln1w + ly * 64;    const float* bb1 = ln1b + ly * 64;
    const float* Wf1 = Wff1 + ly * 8192;  const float* bf1 = bff1 + ly * 128;
    const float* Wf2 = Wff2 + ly * 8192;  const float* bf2 = bff2 + ly * 64;
    const float* w2  = ln2w + ly * 64;    const float* bb2 = ln2b + ly * 64;

    for (int o = w * 4 + g; o < 960; o += 64) {
      int s = o / 192, j = o - s * 192;
      float4 wv = *reinterpret_cast<const float4*>(&Wq[j * 64 + q * 4]);
      float4 xv = *reinterpret_cast<const float4*>(&seq[s][q * 4]);
      float p = wv.x * xv.x + wv.y * xv.y + wv.z * xv.z + wv.w * xv.w;
      p = grp16_reduce(p);
      if (q == 0) qkv[s][j] = p + bq[j];
    }
    __syncthreads();

    if (t < 100) {
      int hh = t / 25, qs = (t / 5) % 5, ks = t % 5;
      float acc = 0.f;
      for (int d = 0; d < 16; d++)
        acc = fmaf(qkv[qs][hh * 16 + d], qkv[ks][64 + hh * 16 + d], acc);
      att[hh][qs][ks] = acc * 0.25f;
    }
    __syncthreads();
    if (t < 20) {
      int hh = t / 5, qs = t % 5;
      float m = att[hh][qs][0];
      for (int k2 = 1; k2 < 5; k2++) m = fmaxf(m, att[hh][qs][k2]);
      float ss = 0.f;
      for (int k2 = 0; k2 < 5; k2++) { float v = expf(att[hh][qs][k2] - m); att[hh][qs][k2] = v; ss += v; }
      float inv = 1.f / ss;
      for (int k2 = 0; k2 < 5; k2++) att[hh][qs][k2] *= inv;
    }
    __syncthreads();

    if (t < 320) {
      int s = t >> 6, j = t & 63, hh = j >> 4;
      float acc = 0.f;
      for (int k2 = 0; k2 < 5; k2++) acc = fmaf(att[hh][s][k2], qkv[k2][128 + j], acc);
      aob[s][j] = acc;
    }
    __syncthreads();

    for (int o = w * 4 + g; o < 320; o += 64) {
      int s = o >> 6, c = o & 63;
      float4 wv = *reinterpret_cast<const float4*>(&Wol[c * 64 + q * 4]);
      float4 xv = *reinterpret_cast<const float4*>(&aob[s][q * 4]);
      float p = wv.x * xv.x + wv.y * xv.y + wv.z * xv.z + wv.w * xv.w;
      p = grp16_reduce(p);
      if (q == 0) tmp[s][c] = seq[s][c] + p + bol[c];
    }
    __syncthreads();

    if (w < 5) {
      float v = tmp[w][l];
      float s1 = v, s2 = v * v;
#pragma unroll
      for (int off = 1; off < 64; off <<= 1) {
        s1 += __shfl_xor(s1, off, 64);
        s2 += __shfl_xor(s2, off, 64);
      }
      float m = s1 * (1.f / 64.f);
      float var = s2 * (1.f / 64.f) - m * m;
      float inv = 1.f / sqrtf(var + 1e-5f);
      seq[w][l] = (v - m) * inv * w1[l] + bb1[l];
    }
    __syncthreads();

    for (int o = w * 4 + g; o < 640; o += 64) {
      int s = o >> 7, j = o & 127;
      float4 wv = *reinterpret_cast<const float4*>(&Wf1[j * 64 + q * 4]);
      float4 xv = *reinterpret_cast<const float4*>(&seq[s][q * 4]);
      float p = wv.x * xv.x + wv.y * xv.y + wv.z * xv.z + wv.w * xv.w;
      p = grp16_reduce(p);
      if (q == 0) ffb[s][j] = fmaxf(p + bf1[j], 0.f);
    }
    __syncthreads();

    for (int o = w * 4 + g; o < 320; o += 64) {
      int s = o >> 6, c = o & 63;
      float4 wa = *reinterpret_cast<const float4*>(&Wf2[c * 128 + q * 8]);
      float4 wb = *reinterpret_cast<const float4*>(&Wf2[c * 128 + q * 8 + 4]);
      float4 xa = *reinterpret_cast<const float4*>(&ffb[s][q * 8]);
      float4 xb = *reinterpret_cast<const float4*>(&ffb[s][q * 8 + 4]);
      float p = wa.x * xa.x + wa.y * xa.y + wa.z * xa.z + wa.w * xa.w
              + wb.x * xb.x + wb.y * xb.y + wb.z * xb.z + wb.w * xb.w;
      p = grp16_reduce(p);
      if (q == 0) tmp[s][c] = seq[s][c] + p + bf2[c];
    }
    __syncthreads();

    if (w < 5) {
      float v = tmp[w][l];
      float s1 = v, s2 = v * v;
#pragma unroll
      for (int off = 1; off < 64; off <<= 1) {
        s1 += __shfl_xor(s1, off, 64);
        s2 += __shfl_xor(s2, off, 64);
      }
      float m = s1 * (1.f / 64.f);
      float var = s2 * (1.f / 64.f) - m * m;
      float inv = 1.f / sqrtf(var + 1e-5f);
      seq[w][l] = (v - m) * inv * w2[l] + bb2[l];
    }
    __syncthreads();
  }

  for (int o = w * 4 + g; o < 32; o += 64) {
    float4 wv = *reinterpret_cast<const float4*>(&Wh1[o * 64 + q * 4]);
    float4 xv = *reinterpret_cast<const float4*>(&seq[4][q * 4]);
    float p = wv.x * xv.x + wv.y * xv.y + wv.z * xv.z + wv.w * xv.w;
    p = grp16_reduce(p);
    if (q == 0) hid[o] = fmaxf(p + bh1[o], 0.f);
  }
  __syncthreads();
  if (t < 2) {
    float acc = bh2[t];
    for (int j = 0; j < 32; j++) acc = fmaf(hid[j], Wh2[t * 32 + j], acc);
    out[t] = acc;
  }
}

extern "C" void kernel_launch(void* const* d_in, const int* in_sizes, int n_in,
                              void* d_out, int out_size, void* d_ws, size_t ws_size,
                              hipStream_t stream) {
  const float* x     = (const float*)d_in[0];
  const int*   ei    = (const int*)d_in[1];
  const float* W1    = (const float*)d_in[2];
  const float* attS1 = (const float*)d_in[3];
  const float* attD1 = (const float*)d_in[4];
  const float* b1    = (const float*)d_in[5];
  const float* W2    = (const float*)d_in[6];
  const float* attS2 = (const float*)d_in[7];
  const float* attD2 = (const float*)d_in[8];
  const float* b2    = (const float*)d_in[9];
  const float* tWqkv = (const float*)d_in[10];
  const float* tbqkv = (const float*)d_in[11];
  const float* tWo   = (const float*)d_in[12];
  const float* tbo   = (const float*)d_in[13];
  const float* tln1w = (const float*)d_in[14];
  const float* tln1b = (const float*)d_in[15];
  const float* tWff1 = (const float*)d_in[16];
  const float* tbff1 = (const float*)d_in[17];
  const float* tWff2 = (const float*)d_in[18];
  const float* tbff2 = (const float*)d_in[19];
  const float* tln2w = (const float*)d_in[20];
  const float* tln2b = (const float*)d_in[21];
  const float* Wh1   = (const float*)d_in[22];
  const float* bh1   = (const float*)d_in[23];
  const float* Wh2   = (const float*)d_in[24];
  const float* bh2   = (const float*)d_in[25];
  float* out = (float*)d_out;

  // floats: as1/ad1 NT*16 + as2/ad2 NT*2 + emb 320
  // ushorts (bf16): h1b NT*64 + gb NT*64 + out1b NT*64
  // ints: deg NT + rowptr NT+1 + bsum/boff 2048 + rank ET + csr ET
  auto need_bytes = [](int F) -> size_t {
    size_t NT = (size_t)F * NN_F, ET = (size_t)F * NE_F;
    size_t fl = NT * 18 + 320;
    size_t us = NT * 192;
    size_t it = NT * 2 + 1 + 2048 + ET * 2;
    return fl * 4 + us * 2 + it * 4;
  };
  const int F = (ws_size >= need_bytes(5)) ? 5 : 1;
  const int NT = F * NN_F, ET = F * NE_F;

  float* ws  = (float*)d_ws;
  float* as1 = ws;                          // NT*8
  float* ad1 = as1 + (size_t)NT * 8;        // NT*8
  float* as2 = ad1 + (size_t)NT * 8;        // NT
  float* ad2 = as2 + NT;                    // NT
  float* emb = ad2 + NT;                    // 320
  unsigned short* h1b   = (unsigned short*)(emb + 320);   // NT*64 bf16
  unsigned short* gb    = h1b + (size_t)NT * 64;          // NT*64 bf16
  unsigned short* out1b = gb + (size_t)NT * 64;           // NT*64 bf16
  int* deg    = (int*)(out1b + (size_t)NT * 64);          // NT
  int* rowptr = deg + NT;                   // NT+1
  int* bsum   = rowptr + NT + 1;            // <=1024
  int* boff   = bsum + 1024;                // <=1024
  int* rank   = boff + 1024;                // ET
  int* csr    = rank + ET;                  // ET

  (void)hipMemsetAsync(emb, 0, 320 * sizeof(float), stream);

  const int nblk = (NT + 255) / 256;
  const int edge4Blocks = ((ET >> 2) + 255) / 256;
  const int aggBlocks = (NT + 3) / 4;       // wave per node, 4 waves/block
  const int nodeBlocks = 2048;

  for (int f0 = 0; f0 < 5; f0 += F) {
    const float* xf = x + (size_t)f0 * NN_F * 13;
    const int* eif  = ei + (size_t)f0 * 2 * NE_F;

    (void)hipMemsetAsync(deg, 0, NT * sizeof(int), stream);
    k_rank<<<edge4Blocks, 256, 0, stream>>>(eif, deg, rank, F);
    k_scan1<<<nblk, 256, 0, stream>>>(deg, bsum, NT);
    k_scan2<<<1, 1024, 0, stream>>>(bsum, boff, nblk);
    k_scan3<<<nblk, 256, 0, stream>>>(deg, boff, rowptr, NT, ET);
    k_place<<<edge4Blocks, 256, 0, stream>>>(eif, rowptr, rank, csr, F);

    k_node1<<<nodeBlocks, 256, 0, stream>>>(xf, W1, attS1, attD1, h1b, as1, ad1, NT);
    k_agg1<<<aggBlocks, 256, 0, stream>>>(rowptr, csr, h1b, as1, ad1, out1b, NT);
    k_node2<<<nodeBlocks, 256, 0, stream>>>(out1b, b1, W2, attS2, attD2, gb, as2, ad2, NT);
    k_agg2mean<<<F * BPF, 256, 0, stream>>>(rowptr, csr, gb, as2, ad2, emb + f0 * 64);
  }

  k_transformer<<<1, 1024, 0, stream>>>(emb, b2, tWqkv, tbqkv, tWo, tbo, tln1w, tln1b,
                                        tWff1, tbff1, tWff2, tbff2, tln2w, tln2b,
                                        Wh1, bh1, Wh2, bh2, out);
}

// Round 10
// 427.484 us; speedup vs baseline: 4.7815x; 1.1901x over previous
//
#include <hip/hip_runtime.h>
#include <math.h>

#define NN_F 50000      // nodes per frame
#define NE_F 400000     // edges per frame
#define BPF  768        // blocks per frame for fused agg2+mean (32 groups/block)

__device__ __forceinline__ float lrelu02(float x) { return x > 0.f ? x : 0.2f * x; }
__device__ __forceinline__ float fexp(float x) { return __expf(x); }

// bf16 pack (RNE) / unpack helpers
__device__ __forceinline__ unsigned short f2bf(float f) {
  unsigned int u = __float_as_uint(f);
  u += 0x7fffu + ((u >> 16) & 1u);
  return (unsigned short)(u >> 16);
}
__device__ __forceinline__ float bf_lo(unsigned int u) { return __uint_as_float(u << 16); }
__device__ __forceinline__ float bf_hi(unsigned int u) { return __uint_as_float(u & 0xffff0000u); }
__device__ __forceinline__ unsigned int pack2(float a, float b) {
  return (unsigned int)f2bf(a) | ((unsigned int)f2bf(b) << 16);
}

// ---------------- GAT layer 1: wave per node, lane = output channel ----------------
__global__ void __launch_bounds__(256, 3)
k_node1(const float* __restrict__ x, const float* __restrict__ W1,
        const float* __restrict__ attS, const float* __restrict__ attD,
        unsigned short* __restrict__ h1b, float* __restrict__ as1, float* __restrict__ ad1,
        int nNodes) {
  __shared__ float xbuf[4][16];
  int l = threadIdx.x & 63;
  int w = threadIdx.x >> 6;
  int wid = (blockIdx.x * blockDim.x + threadIdx.x) >> 6;
  int nw = (gridDim.x * blockDim.x) >> 6;
  float4 wA = make_float4(W1[l * 13 + 0], W1[l * 13 + 1], W1[l * 13 + 2], W1[l * 13 + 3]);
  float4 wB = make_float4(W1[l * 13 + 4], W1[l * 13 + 5], W1[l * 13 + 6], W1[l * 13 + 7]);
  float4 wC = make_float4(W1[l * 13 + 8], W1[l * 13 + 9], W1[l * 13 + 10], W1[l * 13 + 11]);
  float4 wD = make_float4(W1[l * 13 + 12], 0.f, 0.f, 0.f);
  float aS = attS[l], aD = attD[l];
  const float4* xb = reinterpret_cast<const float4*>(xbuf[w]);
  for (int n = wid; n < nNodes; n += nw) {
    if (l < 16) xbuf[w][l] = (l < 13) ? x[(size_t)n * 13 + l] : 0.f;
    float4 x0 = xb[0], x1 = xb[1], x2 = xb[2], x3 = xb[3];
    float a0 = x0.x * wA.x, a1 = x0.y * wA.y, a2 = x0.z * wA.z, a3 = x0.w * wA.w;
    a0 = fmaf(x1.x, wB.x, a0); a1 = fmaf(x1.y, wB.y, a1);
    a2 = fmaf(x1.z, wB.z, a2); a3 = fmaf(x1.w, wB.w, a3);
    a0 = fmaf(x2.x, wC.x, a0); a1 = fmaf(x2.y, wC.y, a1);
    a2 = fmaf(x2.z, wC.z, a2); a3 = fmaf(x2.w, wC.w, a3);
    a0 = fmaf(x3.x, wD.x, a0);
    float acc = (a0 + a1) + (a2 + a3);
    h1b[(size_t)n * 64 + l] = f2bf(acc);
    float s = acc * aS, d = acc * aD;
#pragma unroll
    for (int off = 1; off < 8; off <<= 1) {
      s += __shfl_xor(s, off, 64);
      d += __shfl_xor(d, off, 64);
    }
    if ((l & 7) == 0) { as1[n * 8 + (l >> 3)] = s; ad1[n * 8 + (l >> 3)] = d; }
  }
}

// ---- CSR build pass A: per-edge rank via histogram atomic (4x ILP) ----
__global__ void k_rank(const int* __restrict__ ei, int* __restrict__ deg,
                       int* __restrict__ rank, int nFrames) {
  int tid = blockIdx.x * blockDim.x + threadIdx.x;
  int T = (nFrames * NE_F) >> 2;
  if (tid >= T) return;
  int gd[4];
#pragma unroll
  for (int i = 0; i < 4; i++) {
    int e = tid + i * T;
    int f = e / NE_F, idx = e - f * NE_F;
    gd[i] = f * NN_F + ei[(size_t)f * 2 * NE_F + NE_F + idx];
  }
  int r[4];
#pragma unroll
  for (int i = 0; i < 4; i++) r[i] = atomicAdd(&deg[gd[i]], 1);
#pragma unroll
  for (int i = 0; i < 4; i++) rank[tid + i * T] = r[i];
}

// ---------------- CSR build: per-block sums ----------------
__global__ void k_scan1(const int* __restrict__ deg, int* __restrict__ bsum, int nNodes) {
  __shared__ int part[256];
  int t = threadIdx.x;
  int i = blockIdx.x * 256 + t;
  part[t] = (i < nNodes) ? deg[i] : 0;
  __syncthreads();
  for (int off = 128; off > 0; off >>= 1) {
    if (t < off) part[t] += part[t + off];
    __syncthreads();
  }
  if (t == 0) bsum[blockIdx.x] = part[0];
}

// ---------------- CSR build: scan of block sums (single block, up to 1024) ----------------
__global__ void __launch_bounds__(1024)
k_scan2(const int* __restrict__ bsum, int* __restrict__ boff, int nblk) {
  __shared__ int part[1024];
  int t = threadIdx.x;
  part[t] = (t < nblk) ? bsum[t] : 0;
  __syncthreads();
  for (int off = 1; off < 1024; off <<= 1) {
    int v = (t >= off) ? part[t - off] : 0;
    __syncthreads();
    part[t] += v;
    __syncthreads();
  }
  if (t < nblk) boff[t] = part[t] - bsum[t];  // exclusive
}

// ---------------- CSR build: intra-block scan -> rowptr ----------------
__global__ void k_scan3(const int* __restrict__ deg, const int* __restrict__ boff,
                        int* __restrict__ rowptr, int nNodes, int nEdges) {
  __shared__ int part[256];
  int t = threadIdx.x;
  int i = blockIdx.x * 256 + t;
  int d = (i < nNodes) ? deg[i] : 0;
  part[t] = d;
  __syncthreads();
  for (int off = 1; off < 256; off <<= 1) {
    int v = (t >= off) ? part[t - off] : 0;
    __syncthreads();
    part[t] += v;
    __syncthreads();
  }
  if (i < nNodes) rowptr[i] = boff[blockIdx.x] + part[t] - d;  // exclusive prefix
  if (blockIdx.x == 0 && t == 0) rowptr[nNodes] = nEdges;
}

// ---- CSR build pass B: place srcs (NO atomics; 4x ILP) ----
__global__ void k_place(const int* __restrict__ ei, const int* __restrict__ rowptr,
                        const int* __restrict__ rank, int* __restrict__ csr, int nFrames) {
  int tid = blockIdx.x * blockDim.x + threadIdx.x;
  int T = (nFrames * NE_F) >> 2;
  if (tid >= T) return;
#pragma unroll
  for (int i = 0; i < 4; i++) {
    int e = tid + i * T;
    int f = e / NE_F, idx = e - f * NE_F;
    const int* base = ei + (size_t)f * 2 * NE_F;
    int src = base[idx], dst = base[NE_F + idx];
    csr[rowptr[f * NN_F + dst] + rank[e]] = f * NN_F + src;
  }
}

// ---- GAT layer 1 aggregation: GROUP(8 lanes)-PER-NODE; lane q = head q ----
// No cross-lane reduction at all: each lane owns head q's 8 channels + its own denominator.
__global__ void __launch_bounds__(256)
k_agg1(const int* __restrict__ rowptr, const int* __restrict__ csr,
       const unsigned short* __restrict__ h1b, const float* __restrict__ as1,
       const float* __restrict__ ad1, unsigned short* __restrict__ out1b, int nNodes) {
  int t = threadIdx.x;
  int l = t & 63;
  int grp = l >> 3, q = l & 7;
  int n = ((blockIdx.x * blockDim.x + t) >> 6) * 8 + grp;   // group -> node
  if (n >= nNodes) return;
  float adv = ad1[n * 8 + q];
  // self loop
  float e0 = fexp(lrelu02(as1[n * 8 + q] + adv));
  uint4 pv = *reinterpret_cast<const uint4*>(h1b + (size_t)n * 64 + q * 8);
  float a0 = e0 * bf_lo(pv.x), a1 = e0 * bf_hi(pv.x);
  float a2 = e0 * bf_lo(pv.y), a3 = e0 * bf_hi(pv.y);
  float a4 = e0 * bf_lo(pv.z), a5 = e0 * bf_hi(pv.z);
  float a6 = e0 * bf_lo(pv.w), a7 = e0 * bf_hi(pv.w);
  float den = e0;
  int s0 = rowptr[n], s1 = rowptr[n + 1];
  int i = s0;
  for (; i + 2 <= s1; i += 2) {   // 2-way unroll: 2 gathers in flight per group
    int src0 = csr[i], src1 = csr[i + 1];
    float ea = fexp(lrelu02(as1[src0 * 8 + q] + adv));
    float eb = fexp(lrelu02(as1[src1 * 8 + q] + adv));
    uint4 va = *reinterpret_cast<const uint4*>(h1b + (size_t)src0 * 64 + q * 8);
    uint4 vb = *reinterpret_cast<const uint4*>(h1b + (size_t)src1 * 64 + q * 8);
    a0 = fmaf(ea, bf_lo(va.x), a0); a1 = fmaf(ea, bf_hi(va.x), a1);
    a2 = fmaf(ea, bf_lo(va.y), a2); a3 = fmaf(ea, bf_hi(va.y), a3);
    a4 = fmaf(ea, bf_lo(va.z), a4); a5 = fmaf(ea, bf_hi(va.z), a5);
    a6 = fmaf(ea, bf_lo(va.w), a6); a7 = fmaf(ea, bf_hi(va.w), a7);
    a0 = fmaf(eb, bf_lo(vb.x), a0); a1 = fmaf(eb, bf_hi(vb.x), a1);
    a2 = fmaf(eb, bf_lo(vb.y), a2); a3 = fmaf(eb, bf_hi(vb.y), a3);
    a4 = fmaf(eb, bf_lo(vb.z), a4); a5 = fmaf(eb, bf_hi(vb.z), a5);
    a6 = fmaf(eb, bf_lo(vb.w), a6); a7 = fmaf(eb, bf_hi(vb.w), a7);
    den += ea + eb;
  }
  if (i < s1) {
    int src = csr[i];
    float e2 = fexp(lrelu02(as1[src * 8 + q] + adv));
    uint4 v = *reinterpret_cast<const uint4*>(h1b + (size_t)src * 64 + q * 8);
    a0 = fmaf(e2, bf_lo(v.x), a0); a1 = fmaf(e2, bf_hi(v.x), a1);
    a2 = fmaf(e2, bf_lo(v.y), a2); a3 = fmaf(e2, bf_hi(v.y), a3);
    a4 = fmaf(e2, bf_lo(v.z), a4); a5 = fmaf(e2, bf_hi(v.z), a5);
    a6 = fmaf(e2, bf_lo(v.w), a6); a7 = fmaf(e2, bf_hi(v.w), a7);
    den += e2;
  }
  float inv = 1.f / den;
  uint4 o;
  o.x = pack2(a0 * inv, a1 * inv);
  o.y = pack2(a2 * inv, a3 * inv);
  o.z = pack2(a4 * inv, a5 * inv);
  o.w = pack2(a6 * inv, a7 * inv);
  *reinterpret_cast<uint4*>(out1b + (size_t)n * 64 + q * 8) = o;
}

// ---------------- bias + ELU + GAT2 linear + att feats; bf16 in, bf16 out ----------------
__global__ void __launch_bounds__(256, 3)
k_node2(const unsigned short* __restrict__ out1b, const float* __restrict__ b1,
        const float* __restrict__ W2, const float* __restrict__ attS2,
        const float* __restrict__ attD2, unsigned short* __restrict__ gb,
        float* __restrict__ as2, float* __restrict__ ad2, int nNodes) {
  __shared__ float hbuf[4][64];
  int l = threadIdx.x & 63;
  int w = threadIdx.x >> 6;
  int wid = (blockIdx.x * blockDim.x + threadIdx.x) >> 6;
  int nw = (gridDim.x * blockDim.x) >> 6;
  const float4* W4 = reinterpret_cast<const float4*>(&W2[l * 64]);
  float4 w0 = W4[0],  w1 = W4[1],  w2 = W4[2],  w3 = W4[3];
  float4 w4 = W4[4],  w5 = W4[5],  w6 = W4[6],  w7 = W4[7];
  float4 w8 = W4[8],  w9 = W4[9],  w10 = W4[10], w11 = W4[11];
  float4 w12 = W4[12], w13 = W4[13], w14 = W4[14], w15 = W4[15];
  float aS = attS2[l], aD = attD2[l], bb = b1[l];
  const float4* hb = reinterpret_cast<const float4*>(hbuf[w]);
  for (int n = wid; n < nNodes; n += nw) {
    float v = __uint_as_float((unsigned int)out1b[(size_t)n * 64 + l] << 16) + bb;
    float hh = v > 0.f ? v : (fexp(v) - 1.f);
    hbuf[w][l] = hh;
    float a0 = 0.f, a1 = 0.f, a2 = 0.f, a3 = 0.f;
#define NSTEP(i, wv) { float4 hv = hb[i]; \
    a0 = fmaf(hv.x, wv.x, a0); a1 = fmaf(hv.y, wv.y, a1); \
    a2 = fmaf(hv.z, wv.z, a2); a3 = fmaf(hv.w, wv.w, a3); }
    NSTEP(0, w0)  NSTEP(1, w1)  NSTEP(2, w2)  NSTEP(3, w3)
    NSTEP(4, w4)  NSTEP(5, w5)  NSTEP(6, w6)  NSTEP(7, w7)
    NSTEP(8, w8)  NSTEP(9, w9)  NSTEP(10, w10) NSTEP(11, w11)
    NSTEP(12, w12) NSTEP(13, w13) NSTEP(14, w14) NSTEP(15, w15)
#undef NSTEP
    float acc = (a0 + a1) + (a2 + a3);
    gb[(size_t)n * 64 + l] = f2bf(acc);
    float s2 = acc * aS, d2 = acc * aD;
#pragma unroll
    for (int off = 32; off > 0; off >>= 1) {
      s2 += __shfl_xor(s2, off, 64);
      d2 += __shfl_xor(d2, off, 64);
    }
    if (l == 0) { as2[n] = s2; ad2[n] = d2; }
  }
}

// ---- GAT layer 2 aggregation + frame mean: GROUP(8 lanes)-PER-NODE ----
// Group accumulates mean partials in registers; one LDS cross-group reduce per block.
__global__ void __launch_bounds__(256)
k_agg2mean(const int* __restrict__ rowptr, const int* __restrict__ csr,
           const unsigned short* __restrict__ gtab, const float* __restrict__ as2,
           const float* __restrict__ ad2, float* __restrict__ emb) {
  __shared__ float part[32][64];
  int t = threadIdx.x;
  int w = t >> 6, l = t & 63;
  int grp = l >> 3, q = l & 7;
  int f = blockIdx.x / BPF;
  int gf = (blockIdx.x - f * BPF) * 32 + w * 8 + grp;   // group id within frame
  const int stride = BPF * 32;
  float m0 = 0.f, m1 = 0.f, m2 = 0.f, m3 = 0.f, m4 = 0.f, m5 = 0.f, m6 = 0.f, m7 = 0.f;
  for (int j = gf; j < NN_F; j += stride) {
    int n = f * NN_F + j;
    float adv = ad2[n];
    float e0 = fexp(lrelu02(as2[n] + adv));
    uint4 pv = *reinterpret_cast<const uint4*>(gtab + (size_t)n * 64 + q * 8);
    float a0 = e0 * bf_lo(pv.x), a1 = e0 * bf_hi(pv.x);
    float a2 = e0 * bf_lo(pv.y), a3 = e0 * bf_hi(pv.y);
    float a4 = e0 * bf_lo(pv.z), a5 = e0 * bf_hi(pv.z);
    float a6 = e0 * bf_lo(pv.w), a7 = e0 * bf_hi(pv.w);
    float den = e0;
    int s0 = rowptr[n], s1 = rowptr[n + 1];
    int i = s0;
    for (; i + 2 <= s1; i += 2) {
      int src0 = csr[i], src1 = csr[i + 1];
      float ea = fexp(lrelu02(as2[src0] + adv));
      float eb = fexp(lrelu02(as2[src1] + adv));
      uint4 va = *reinterpret_cast<const uint4*>(gtab + (size_t)src0 * 64 + q * 8);
      uint4 vb = *reinterpret_cast<const uint4*>(gtab + (size_t)src1 * 64 + q * 8);
      a0 = fmaf(ea, bf_lo(va.x), a0); a1 = fmaf(ea, bf_hi(va.x), a1);
      a2 = fmaf(ea, bf_lo(va.y), a2); a3 = fmaf(ea, bf_hi(va.y), a3);
      a4 = fmaf(ea, bf_lo(va.z), a4); a5 = fmaf(ea, bf_hi(va.z), a5);
      a6 = fmaf(ea, bf_lo(va.w), a6); a7 = fmaf(ea, bf_hi(va.w), a7);
      a0 = fmaf(eb, bf_lo(vb.x), a0); a1 = fmaf(eb, bf_hi(vb.x), a1);
      a2 = fmaf(eb, bf_lo(vb.y), a2); a3 = fmaf(eb, bf_hi(vb.y), a3);
      a4 = fmaf(eb, bf_lo(vb.z), a4); a5 = fmaf(eb, bf_hi(vb.z), a5);
      a6 = fmaf(eb, bf_lo(vb.w), a6); a7 = fmaf(eb, bf_hi(vb.w), a7);
      den += ea + eb;
    }
    if (i < s1) {
      int src = csr[i];
      float e2 = fexp(lrelu02(as2[src] + adv));
      uint4 v = *reinterpret_cast<const uint4*>(gtab + (size_t)src * 64 + q * 8);
      a0 = fmaf(e2, bf_lo(v.x), a0); a1 = fmaf(e2, bf_hi(v.x), a1);
      a2 = fmaf(e2, bf_lo(v.y), a2); a3 = fmaf(e2, bf_hi(v.y), a3);
      a4 = fmaf(e2, bf_lo(v.z), a4); a5 = fmaf(e2, bf_hi(v.z), a5);
      a6 = fmaf(e2, bf_lo(v.w), a6); a7 = fmaf(e2, bf_hi(v.w), a7);
      den += e2;
    }
    float inv = 1.f / den;
    m0 = fmaf(a0, inv, m0); m1 = fmaf(a1, inv, m1);
    m2 = fmaf(a2, inv, m2); m3 = fmaf(a3, inv, m3);
    m4 = fmaf(a4, inv, m4); m5 = fmaf(a5, inv, m5);
    m6 = fmaf(a6, inv, m6); m7 = fmaf(a7, inv, m7);
  }
  // cross-group reduce: each lane writes its 8-channel partial row
  float4* pr = reinterpret_cast<float4*>(&part[w * 8 + grp][q * 8]);
  pr[0] = make_float4(m0, m1, m2, m3);
  pr[1] = make_float4(m4, m5, m6, m7);
  __syncthreads();
  if (t < 64) {
    float s = 0.f;
#pragma unroll
    for (int r = 0; r < 32; r++) s += part[r][t];
    atomicAdd(&emb[f * 64 + t], s * (1.0f / NN_F));
  }
}

// ---------------- tiny transformer: 1024 threads, 16-lane-group shuffle GEMVs ----------
__device__ __forceinline__ float grp16_reduce(float p) {
#pragma unroll
  for (int off = 1; off < 16; off <<= 1) p += __shfl_xor(p, off, 64);
  return p;
}

__global__ void __launch_bounds__(1024)
k_transformer(const float* __restrict__ emb, const float* __restrict__ b2,
              const float* __restrict__ Wqkv, const float* __restrict__ bqkv,
              const float* __restrict__ Wo, const float* __restrict__ bo,
              const float* __restrict__ ln1w, const float* __restrict__ ln1b,
              const float* __restrict__ Wff1, const float* __restrict__ bff1,
              const float* __restrict__ Wff2, const float* __restrict__ bff2,
              const float* __restrict__ ln2w, const float* __restrict__ ln2b,
              const float* __restrict__ Wh1, const float* __restrict__ bh1,
              const float* __restrict__ Wh2, const float* __restrict__ bh2,
              float* __restrict__ out) {
  __shared__ float seq[5][64];
  __shared__ float qkv[5][192];
  __shared__ float att[4][5][5];
  __shared__ float aob[5][64];
  __shared__ float ffb[5][128];
  __shared__ float tmp[5][64];
  __shared__ float hid[32];
  int t = threadIdx.x;
  int l = t & 63, w = t >> 6;        // 16 waves
  int g = l >> 4, q = l & 15;        // 4 groups of 16 lanes

  if (t < 320) seq[t >> 6][t & 63] = emb[t] + b2[t & 63];
  __syncthreads();

  for (int ly = 0; ly < 3; ly++) {
    const float* Wq  = Wqkv + ly * 12288; const float* bq  = bqkv + ly * 192;
    const float* Wol = Wo   + ly * 4096;  const float* bol = bo   + ly * 64;
    const float* w1  = ln1w + ly * 64;    const float* bb1 = ln1b + ly * 64;
    const float* Wf1 = Wff1 + ly * 8192;  const float* bf1 = bff1 + ly * 128;
    const float* Wf2 = Wff2 + ly * 8192;  const float* bf2 = bff2 + ly * 64;
    const float* w2  = ln2w + ly * 64;    const float* bb2 = ln2b + ly * 64;

    for (int o = w * 4 + g; o < 960; o += 64) {
      int s = o / 192, j = o - s * 192;
      float4 wv = *reinterpret_cast<const float4*>(&Wq[j * 64 + q * 4]);
      float4 xv = *reinterpret_cast<const float4*>(&seq[s][q * 4]);
      float p = wv.x * xv.x + wv.y * xv.y + wv.z * xv.z + wv.w * xv.w;
      p = grp16_reduce(p);
      if (q == 0) qkv[s][j] = p + bq[j];
    }
    __syncthreads();

    if (t < 100) {
      int hh = t / 25, qs = (t / 5) % 5, ks = t % 5;
      float acc = 0.f;
      for (int d = 0; d < 16; d++)
        acc = fmaf(qkv[qs][hh * 16 + d], qkv[ks][64 + hh * 16 + d], acc);
      att[hh][qs][ks] = acc * 0.25f;
    }
    __syncthreads();
    if (t < 20) {
      int hh = t / 5, qs = t % 5;
      float m = att[hh][qs][0];
      for (int k2 = 1; k2 < 5; k2++) m = fmaxf(m, att[hh][qs][k2]);
      float ss = 0.f;
      for (int k2 = 0; k2 < 5; k2++) { float v = expf(att[hh][qs][k2] - m); att[hh][qs][k2] = v; ss += v; }
      float inv = 1.f / ss;
      for (int k2 = 0; k2 < 5; k2++) att[hh][qs][k2] *= inv;
    }
    __syncthreads();

    if (t < 320) {
      int s = t >> 6, j = t & 63, hh = j >> 4;
      float acc = 0.f;
      for (int k2 = 0; k2 < 5; k2++) acc = fmaf(att[hh][s][k2], qkv[k2][128 + j], acc);
      aob[s][j] = acc;
    }
    __syncthreads();

    for (int o = w * 4 + g; o < 320; o += 64) {
      int s = o >> 6, c = o & 63;
      float4 wv = *reinterpret_cast<const float4*>(&Wol[c * 64 + q * 4]);
      float4 xv = *reinterpret_cast<const float4*>(&aob[s][q * 4]);
      float p = wv.x * xv.x + wv.y * xv.y + wv.z * xv.z + wv.w * xv.w;
      p = grp16_reduce(p);
      if (q == 0) tmp[s][c] = seq[s][c] + p + bol[c];
    }
    __syncthreads();

    if (w < 5) {
      float v = tmp[w][l];
      float s1 = v, s2 = v * v;
#pragma unroll
      for (int off = 1; off < 64; off <<= 1) {
        s1 += __shfl_xor(s1, off, 64);
        s2 += __shfl_xor(s2, off, 64);
      }
      float m = s1 * (1.f / 64.f);
      float var = s2 * (1.f / 64.f) - m * m;
      float inv = 1.f / sqrtf(var + 1e-5f);
      seq[w][l] = (v - m) * inv * w1[l] + bb1[l];
    }
    __syncthreads();

    for (int o = w * 4 + g; o < 640; o += 64) {
      int s = o >> 7, j = o & 127;
      float4 wv = *reinterpret_cast<const float4*>(&Wf1[j * 64 + q * 4]);
      float4 xv = *reinterpret_cast<const float4*>(&seq[s][q * 4]);
      float p = wv.x * xv.x + wv.y * xv.y + wv.z * xv.z + wv.w * xv.w;
      p = grp16_reduce(p);
      if (q == 0) ffb[s][j] = fmaxf(p + bf1[j], 0.f);
    }
    __syncthreads();

    for (int o = w * 4 + g; o < 320; o += 64) {
      int s = o >> 6, c = o & 63;
      float4 wa = *reinterpret_cast<const float4*>(&Wf2[c * 128 + q * 8]);
      float4 wb = *reinterpret_cast<const float4*>(&Wf2[c * 128 + q * 8 + 4]);
      float4 xa = *reinterpret_cast<const float4*>(&ffb[s][q * 8]);
      float4 xb = *reinterpret_cast<const float4*>(&ffb[s][q * 8 + 4]);
      float p = wa.x * xa.x + wa.y * xa.y + wa.z * xa.z + wa.w * xa.w
              + wb.x * xb.x + wb.y * xb.y + wb.z * xb.z + wb.w * xb.w;
      p = grp16_reduce(p);
      if (q == 0) tmp[s][c] = seq[s][c] + p + bf2[c];
    }
    __syncthreads();

    if (w < 5) {
      float v = tmp[w][l];
      float s1 = v, s2 = v * v;
#pragma unroll
      for (int off = 1; off < 64; off <<= 1) {
        s1 += __shfl_xor(s1, off, 64);
        s2 += __shfl_xor(s2, off, 64);
      }
      float m = s1 * (1.f / 64.f);
      float var = s2 * (1.f / 64.f) - m * m;
      float inv = 1.f / sqrtf(var + 1e-5f);
      seq[w][l] = (v - m) * inv * w2[l] + bb2[l];
    }
    __syncthreads();
  }

  for (int o = w * 4 + g; o < 32; o += 64) {
    float4 wv = *reinterpret_cast<const float4*>(&Wh1[o * 64 + q * 4]);
    float4 xv = *reinterpret_cast<const float4*>(&seq[4][q * 4]);
    float p = wv.x * xv.x + wv.y * xv.y + wv.z * xv.z + wv.w * xv.w;
    p = grp16_reduce(p);
    if (q == 0) hid[o] = fmaxf(p + bh1[o], 0.f);
  }
  __syncthreads();
  if (t < 2) {
    float acc = bh2[t];
    for (int j = 0; j < 32; j++) acc = fmaf(hid[j], Wh2[t * 32 + j], acc);
    out[t] = acc;
  }
}

extern "C" void kernel_launch(void* const* d_in, const int* in_sizes, int n_in,
                              void* d_out, int out_size, void* d_ws, size_t ws_size,
                              hipStream_t stream) {
  const float* x     = (const float*)d_in[0];
  const int*   ei    = (const int*)d_in[1];
  const float* W1    = (const float*)d_in[2];
  const float* attS1 = (const float*)d_in[3];
  const float* attD1 = (const float*)d_in[4];
  const float* b1    = (const float*)d_in[5];
  const float* W2    = (const float*)d_in[6];
  const float* attS2 = (const float*)d_in[7];
  const float* attD2 = (const float*)d_in[8];
  const float* b2    = (const float*)d_in[9];
  const float* tWqkv = (const float*)d_in[10];
  const float* tbqkv = (const float*)d_in[11];
  const float* tWo   = (const float*)d_in[12];
  const float* tbo   = (const float*)d_in[13];
  const float* tln1w = (const float*)d_in[14];
  const float* tln1b = (const float*)d_in[15];
  const float* tWff1 = (const float*)d_in[16];
  const float* tbff1 = (const float*)d_in[17];
  const float* tWff2 = (const float*)d_in[18];
  const float* tbff2 = (const float*)d_in[19];
  const float* tln2w = (const float*)d_in[20];
  const float* tln2b = (const float*)d_in[21];
  const float* Wh1   = (const float*)d_in[22];
  const float* bh1   = (const float*)d_in[23];
  const float* Wh2   = (const float*)d_in[24];
  const float* bh2   = (const float*)d_in[25];
  float* out = (float*)d_out;

  auto need_bytes = [](int F) -> size_t {
    size_t NT = (size_t)F * NN_F, ET = (size_t)F * NE_F;
    size_t fl = NT * 18 + 320;
    size_t us = NT * 192;
    size_t it = NT * 2 + 1 + 2048 + ET * 2;
    return fl * 4 + us * 2 + it * 4;
  };
  const int F = (ws_size >= need_bytes(5)) ? 5 : 1;
  const int NT = F * NN_F, ET = F * NE_F;

  float* ws  = (float*)d_ws;
  float* as1 = ws;                          // NT*8
  float* ad1 = as1 + (size_t)NT * 8;        // NT*8
  float* as2 = ad1 + (size_t)NT * 8;        // NT
  float* ad2 = as2 + NT;                    // NT
  float* emb = ad2 + NT;                    // 320
  unsigned short* h1b   = (unsigned short*)(emb + 320);   // NT*64 bf16
  unsigned short* gb    = h1b + (size_t)NT * 64;          // NT*64 bf16
  unsigned short* out1b = gb + (size_t)NT * 64;           // NT*64 bf16
  int* deg    = (int*)(out1b + (size_t)NT * 64);          // NT
  int* rowptr = deg + NT;                   // NT+1
  int* bsum   = rowptr + NT + 1;            // <=1024
  int* boff   = bsum + 1024;                // <=1024
  int* rank   = boff + 1024;                // ET
  int* csr    = rank + ET;                  // ET

  (void)hipMemsetAsync(emb, 0, 320 * sizeof(float), stream);

  const int nblk = (NT + 255) / 256;
  const int edge4Blocks = ((ET >> 2) + 255) / 256;
  const int agg1Blocks = (NT / 8 + 3) / 4;  // group(8 lanes) per node, 32 groups/block
  const int nodeBlocks = 2048;

  for (int f0 = 0; f0 < 5; f0 += F) {
    const float* xf = x + (size_t)f0 * NN_F * 13;
    const int* eif  = ei + (size_t)f0 * 2 * NE_F;

    (void)hipMemsetAsync(deg, 0, NT * sizeof(int), stream);
    k_rank<<<edge4Blocks, 256, 0, stream>>>(eif, deg, rank, F);
    k_scan1<<<nblk, 256, 0, stream>>>(deg, bsum, NT);
    k_scan2<<<1, 1024, 0, stream>>>(bsum, boff, nblk);
    k_scan3<<<nblk, 256, 0, stream>>>(deg, boff, rowptr, NT, ET);
    k_place<<<edge4Blocks, 256, 0, stream>>>(eif, rowptr, rank, csr, F);

    k_node1<<<nodeBlocks, 256, 0, stream>>>(xf, W1, attS1, attD1, h1b, as1, ad1, NT);
    k_agg1<<<agg1Blocks, 256, 0, stream>>>(rowptr, csr, h1b, as1, ad1, out1b, NT);
    k_node2<<<nodeBlocks, 256, 0, stream>>>(out1b, b1, W2, attS2, attD2, gb, as2, ad2, NT);
    k_agg2mean<<<F * BPF, 256, 0, stream>>>(rowptr, csr, gb, as2, ad2, emb + f0 * 64);
  }

  k_transformer<<<1, 1024, 0, stream>>>(emb, b2, tWqkv, tbqkv, tWo, tbo, tln1w, tln1b,
                                        tWff1, tbff1, tWff2, tbff2, tln2w, tln2b,
                                        Wh1, bh1, Wh2, bh2, out);
}

// Round 11
// 366.086 us; speedup vs baseline: 5.5834x; 1.1677x over previous
//
#include <hip/hip_runtime.h>
#include <math.h>

#define NN_F 50000      // nodes per frame
#define NE_F 400000     // edges per frame
#define BPF  768        // blocks per frame for fused agg2+mean (32 groups/block)

__device__ __forceinline__ float lrelu02(float x) { return x > 0.f ? x : 0.2f * x; }
__device__ __forceinline__ float fexp(float x) { return __expf(x); }

// bf16 pack (RNE) / unpack helpers
__device__ __forceinline__ unsigned short f2bf(float f) {
  unsigned int u = __float_as_uint(f);
  u += 0x7fffu + ((u >> 16) & 1u);
  return (unsigned short)(u >> 16);
}
__device__ __forceinline__ float bf_lo(unsigned int u) { return __uint_as_float(u << 16); }
__device__ __forceinline__ float bf_hi(unsigned int u) { return __uint_as_float(u & 0xffff0000u); }
__device__ __forceinline__ unsigned int pack2(float a, float b) {
  return (unsigned int)f2bf(a) | ((unsigned int)f2bf(b) << 16);
}

typedef __attribute__((ext_vector_type(8))) short bfrag_t;   // 8 bf16 (4 VGPRs)
typedef __attribute__((ext_vector_type(4))) float facc_t;    // 4 fp32 acc

// ---------------- GAT layer 1: wave per node, lane = output channel ----------------
__global__ void __launch_bounds__(256, 3)
k_node1(const float* __restrict__ x, const float* __restrict__ W1,
        const float* __restrict__ attS, const float* __restrict__ attD,
        unsigned short* __restrict__ h1b, float* __restrict__ as1, float* __restrict__ ad1,
        int nNodes) {
  __shared__ float xbuf[4][16];
  int l = threadIdx.x & 63;
  int w = threadIdx.x >> 6;
  int wid = (blockIdx.x * blockDim.x + threadIdx.x) >> 6;
  int nw = (gridDim.x * blockDim.x) >> 6;
  float4 wA = make_float4(W1[l * 13 + 0], W1[l * 13 + 1], W1[l * 13 + 2], W1[l * 13 + 3]);
  float4 wB = make_float4(W1[l * 13 + 4], W1[l * 13 + 5], W1[l * 13 + 6], W1[l * 13 + 7]);
  float4 wC = make_float4(W1[l * 13 + 8], W1[l * 13 + 9], W1[l * 13 + 10], W1[l * 13 + 11]);
  float4 wD = make_float4(W1[l * 13 + 12], 0.f, 0.f, 0.f);
  float aS = attS[l], aD = attD[l];
  const float4* xb = reinterpret_cast<const float4*>(xbuf[w]);
  for (int n = wid; n < nNodes; n += nw) {
    if (l < 16) xbuf[w][l] = (l < 13) ? x[(size_t)n * 13 + l] : 0.f;
    float4 x0 = xb[0], x1 = xb[1], x2 = xb[2], x3 = xb[3];
    float a0 = x0.x * wA.x, a1 = x0.y * wA.y, a2 = x0.z * wA.z, a3 = x0.w * wA.w;
    a0 = fmaf(x1.x, wB.x, a0); a1 = fmaf(x1.y, wB.y, a1);
    a2 = fmaf(x1.z, wB.z, a2); a3 = fmaf(x1.w, wB.w, a3);
    a0 = fmaf(x2.x, wC.x, a0); a1 = fmaf(x2.y, wC.y, a1);
    a2 = fmaf(x2.z, wC.z, a2); a3 = fmaf(x2.w, wC.w, a3);
    a0 = fmaf(x3.x, wD.x, a0);
    float acc = (a0 + a1) + (a2 + a3);
    h1b[(size_t)n * 64 + l] = f2bf(acc);
    float s = acc * aS, d = acc * aD;
#pragma unroll
    for (int off = 1; off < 8; off <<= 1) {
      s += __shfl_xor(s, off, 64);
      d += __shfl_xor(d, off, 64);
    }
    if ((l & 7) == 0) { as1[n * 8 + (l >> 3)] = s; ad1[n * 8 + (l >> 3)] = d; }
  }
}

// ---- CSR build pass A: per-edge rank via histogram atomic (4x ILP) ----
__global__ void k_rank(const int* __restrict__ ei, int* __restrict__ deg,
                       int* __restrict__ rank, int nFrames) {
  int tid = blockIdx.x * blockDim.x + threadIdx.x;
  int T = (nFrames * NE_F) >> 2;
  if (tid >= T) return;
  int gd[4];
#pragma unroll
  for (int i = 0; i < 4; i++) {
    int e = tid + i * T;
    int f = e / NE_F, idx = e - f * NE_F;
    gd[i] = f * NN_F + ei[(size_t)f * 2 * NE_F + NE_F + idx];
  }
  int r[4];
#pragma unroll
  for (int i = 0; i < 4; i++) r[i] = atomicAdd(&deg[gd[i]], 1);
#pragma unroll
  for (int i = 0; i < 4; i++) rank[tid + i * T] = r[i];
}

// ---------------- CSR build: per-block sums ----------------
__global__ void k_scan1(const int* __restrict__ deg, int* __restrict__ bsum, int nNodes) {
  __shared__ int part[256];
  int t = threadIdx.x;
  int i = blockIdx.x * 256 + t;
  part[t] = (i < nNodes) ? deg[i] : 0;
  __syncthreads();
  for (int off = 128; off > 0; off >>= 1) {
    if (t < off) part[t] += part[t + off];
    __syncthreads();
  }
  if (t == 0) bsum[blockIdx.x] = part[0];
}

// ---------------- CSR build: scan of block sums (single block, up to 1024) ----------------
__global__ void __launch_bounds__(1024)
k_scan2(const int* __restrict__ bsum, int* __restrict__ boff, int nblk) {
  __shared__ int part[1024];
  int t = threadIdx.x;
  part[t] = (t < nblk) ? bsum[t] : 0;
  __syncthreads();
  for (int off = 1; off < 1024; off <<= 1) {
    int v = (t >= off) ? part[t - off] : 0;
    __syncthreads();
    part[t] += v;
    __syncthreads();
  }
  if (t < nblk) boff[t] = part[t] - bsum[t];  // exclusive
}

// ---------------- CSR build: intra-block scan -> rowptr ----------------
__global__ void k_scan3(const int* __restrict__ deg, const int* __restrict__ boff,
                        int* __restrict__ rowptr, int nNodes, int nEdges) {
  __shared__ int part[256];
  int t = threadIdx.x;
  int i = blockIdx.x * 256 + t;
  int d = (i < nNodes) ? deg[i] : 0;
  part[t] = d;
  __syncthreads();
  for (int off = 1; off < 256; off <<= 1) {
    int v = (t >= off) ? part[t - off] : 0;
    __syncthreads();
    part[t] += v;
    __syncthreads();
  }
  if (i < nNodes) rowptr[i] = boff[blockIdx.x] + part[t] - d;  // exclusive prefix
  if (blockIdx.x == 0 && t == 0) rowptr[nNodes] = nEdges;
}

// ---- CSR build pass B: place srcs (NO atomics; 4x ILP) ----
__global__ void k_place(const int* __restrict__ ei, const int* __restrict__ rowptr,
                        const int* __restrict__ rank, int* __restrict__ csr, int nFrames) {
  int tid = blockIdx.x * blockDim.x + threadIdx.x;
  int T = (nFrames * NE_F) >> 2;
  if (tid >= T) return;
#pragma unroll
  for (int i = 0; i < 4; i++) {
    int e = tid + i * T;
    int f = e / NE_F, idx = e - f * NE_F;
    const int* base = ei + (size_t)f * 2 * NE_F;
    int src = base[idx], dst = base[NE_F + idx];
    csr[rowptr[f * NN_F + dst] + rank[e]] = f * NN_F + src;
  }
}

// ---- GAT layer 1 aggregation: GROUP(8 lanes)-PER-NODE; lane q = head q ----
__global__ void __launch_bounds__(256)
k_agg1(const int* __restrict__ rowptr, const int* __restrict__ csr,
       const unsigned short* __restrict__ h1b, const float* __restrict__ as1,
       const float* __restrict__ ad1, unsigned short* __restrict__ out1b, int nNodes) {
  int t = threadIdx.x;
  int l = t & 63;
  int grp = l >> 3, q = l & 7;
  int n = ((blockIdx.x * blockDim.x + t) >> 6) * 8 + grp;   // group -> node
  if (n >= nNodes) return;
  float adv = ad1[n * 8 + q];
  float e0 = fexp(lrelu02(as1[n * 8 + q] + adv));
  uint4 pv = *reinterpret_cast<const uint4*>(h1b + (size_t)n * 64 + q * 8);
  float a0 = e0 * bf_lo(pv.x), a1 = e0 * bf_hi(pv.x);
  float a2 = e0 * bf_lo(pv.y), a3 = e0 * bf_hi(pv.y);
  float a4 = e0 * bf_lo(pv.z), a5 = e0 * bf_hi(pv.z);
  float a6 = e0 * bf_lo(pv.w), a7 = e0 * bf_hi(pv.w);
  float den = e0;
  int s0 = rowptr[n], s1 = rowptr[n + 1];
  int i = s0;
  for (; i + 2 <= s1; i += 2) {
    int src0 = csr[i], src1 = csr[i + 1];
    float ea = fexp(lrelu02(as1[src0 * 8 + q] + adv));
    float eb = fexp(lrelu02(as1[src1 * 8 + q] + adv));
    uint4 va = *reinterpret_cast<const uint4*>(h1b + (size_t)src0 * 64 + q * 8);
    uint4 vb = *reinterpret_cast<const uint4*>(h1b + (size_t)src1 * 64 + q * 8);
    a0 = fmaf(ea, bf_lo(va.x), a0); a1 = fmaf(ea, bf_hi(va.x), a1);
    a2 = fmaf(ea, bf_lo(va.y), a2); a3 = fmaf(ea, bf_hi(va.y), a3);
    a4 = fmaf(ea, bf_lo(va.z), a4); a5 = fmaf(ea, bf_hi(va.z), a5);
    a6 = fmaf(ea, bf_lo(va.w), a6); a7 = fmaf(ea, bf_hi(va.w), a7);
    a0 = fmaf(eb, bf_lo(vb.x), a0); a1 = fmaf(eb, bf_hi(vb.x), a1);
    a2 = fmaf(eb, bf_lo(vb.y), a2); a3 = fmaf(eb, bf_hi(vb.y), a3);
    a4 = fmaf(eb, bf_lo(vb.z), a4); a5 = fmaf(eb, bf_hi(vb.z), a5);
    a6 = fmaf(eb, bf_lo(vb.w), a6); a7 = fmaf(eb, bf_hi(vb.w), a7);
    den += ea + eb;
  }
  if (i < s1) {
    int src = csr[i];
    float e2 = fexp(lrelu02(as1[src * 8 + q] + adv));
    uint4 v = *reinterpret_cast<const uint4*>(h1b + (size_t)src * 64 + q * 8);
    a0 = fmaf(e2, bf_lo(v.x), a0); a1 = fmaf(e2, bf_hi(v.x), a1);
    a2 = fmaf(e2, bf_lo(v.y), a2); a3 = fmaf(e2, bf_hi(v.y), a3);
    a4 = fmaf(e2, bf_lo(v.z), a4); a5 = fmaf(e2, bf_hi(v.z), a5);
    a6 = fmaf(e2, bf_lo(v.w), a6); a7 = fmaf(e2, bf_hi(v.w), a7);
    den += e2;
  }
  float inv = 1.f / den;
  uint4 o;
  o.x = pack2(a0 * inv, a1 * inv);
  o.y = pack2(a2 * inv, a3 * inv);
  o.z = pack2(a4 * inv, a5 * inv);
  o.w = pack2(a6 * inv, a7 * inv);
  *reinterpret_cast<uint4*>(out1b + (size_t)n * 64 + q * 8) = o;
}

// ---------------- node2 via MFMA: wave = 16-node tile ----------------
// g = ELU(out1+b1) @ W2^T via mfma_f32_16x16x32_bf16 (4 col-tiles x 2 K-chunks).
// A frag: row = l&15, k-slots by (l>>4); B frag: col = l&15, same k-slot mapping
// (identical A/B k-mapping => any bijective slot-mapping error cancels).
// C layout (m89-verified): col = l&15, row = (l>>4)*4 + reg.
__global__ void __launch_bounds__(256)
k_node2(const unsigned short* __restrict__ out1b, const float* __restrict__ b1,
        const float* __restrict__ W2, const float* __restrict__ attS2,
        const float* __restrict__ attD2, unsigned short* __restrict__ gb,
        float* __restrict__ as2, float* __restrict__ ad2, int nNodes) {
  __shared__ unsigned short lg[4][16][72];   // per-wave 16x64 bf16, row stride 72 (16B-aligned)
  int t = threadIdx.x, l = t & 63, w = t >> 6;
  int r16 = l & 15, g4 = l >> 4;

  // B fragments: B[k][col] = W2[col-ch][k]; col = tile*16 + r16
  bfrag_t bfr[8];
#pragma unroll
  for (int tt = 0; tt < 4; tt++) {
    const float* wrow = W2 + (tt * 16 + r16) * 64;
#pragma unroll
    for (int kc = 0; kc < 2; kc++) {
      float4 lo = *reinterpret_cast<const float4*>(wrow + kc * 32 + 4 * g4);
      float4 hi = *reinterpret_cast<const float4*>(wrow + kc * 32 + 16 + 4 * g4);
      union { unsigned short u[8]; bfrag_t v; } pk;
      pk.u[0] = f2bf(lo.x); pk.u[1] = f2bf(lo.y); pk.u[2] = f2bf(lo.z); pk.u[3] = f2bf(lo.w);
      pk.u[4] = f2bf(hi.x); pk.u[5] = f2bf(hi.y); pk.u[6] = f2bf(hi.z); pk.u[7] = f2bf(hi.w);
      bfr[tt * 2 + kc] = pk.v;
    }
  }
  // bias for this lane's A channels: [kc][half] at kc*32 + half*16 + 4*g4
  float4 bias[2][2];
#pragma unroll
  for (int kc = 0; kc < 2; kc++)
#pragma unroll
    for (int h = 0; h < 2; h++)
      bias[kc][h] = *reinterpret_cast<const float4*>(b1 + kc * 32 + h * 16 + 4 * g4);
  float aSr0 = attS2[r16], aSr1 = attS2[16 + r16], aSr2 = attS2[32 + r16], aSr3 = attS2[48 + r16];
  float aDr0 = attD2[r16], aDr1 = attD2[16 + r16], aDr2 = attD2[32 + r16], aDr3 = attD2[48 + r16];

  int wid = (blockIdx.x * blockDim.x + t) >> 6;
  int nw = (gridDim.x * blockDim.x) >> 6;
  int ntiles = nNodes >> 4;
  for (int tile = wid; tile < ntiles; tile += nw) {
    int n0 = tile << 4;
    const unsigned short* arow = out1b + (size_t)(n0 + r16) * 64;
    facc_t acc0 = 0, acc1 = 0, acc2 = 0, acc3 = 0;
#pragma unroll
    for (int kc = 0; kc < 2; kc++) {
      union { unsigned short u[8]; bfrag_t v; } apk;
#pragma unroll
      for (int h = 0; h < 2; h++) {
        uint2 raw = *reinterpret_cast<const uint2*>(arow + kc * 32 + h * 16 + 4 * g4);
        float4 bb = bias[kc][h];
        float f0 = bf_lo(raw.x) + bb.x, f1 = bf_hi(raw.x) + bb.y;
        float f2 = bf_lo(raw.y) + bb.z, f3 = bf_hi(raw.y) + bb.w;
        f0 = f0 > 0.f ? f0 : (fexp(f0) - 1.f);
        f1 = f1 > 0.f ? f1 : (fexp(f1) - 1.f);
        f2 = f2 > 0.f ? f2 : (fexp(f2) - 1.f);
        f3 = f3 > 0.f ? f3 : (fexp(f3) - 1.f);
        apk.u[h * 4 + 0] = f2bf(f0); apk.u[h * 4 + 1] = f2bf(f1);
        apk.u[h * 4 + 2] = f2bf(f2); apk.u[h * 4 + 3] = f2bf(f3);
      }
      bfrag_t afr = apk.v;
      acc0 = __builtin_amdgcn_mfma_f32_16x16x32_bf16(afr, bfr[0 * 2 + kc], acc0, 0, 0, 0);
      acc1 = __builtin_amdgcn_mfma_f32_16x16x32_bf16(afr, bfr[1 * 2 + kc], acc1, 0, 0, 0);
      acc2 = __builtin_amdgcn_mfma_f32_16x16x32_bf16(afr, bfr[2 * 2 + kc], acc2, 0, 0, 0);
      acc3 = __builtin_amdgcn_mfma_f32_16x16x32_bf16(afr, bfr[3 * 2 + kc], acc3, 0, 0, 0);
    }
    // attention features: s[row] = sum_col g[row][col]*aS[col]; lane has col=r16 of 4 rows
    float ps0 = acc0[0] * aSr0 + acc1[0] * aSr1 + acc2[0] * aSr2 + acc3[0] * aSr3;
    float ps1 = acc0[1] * aSr0 + acc1[1] * aSr1 + acc2[1] * aSr2 + acc3[1] * aSr3;
    float ps2 = acc0[2] * aSr0 + acc1[2] * aSr1 + acc2[2] * aSr2 + acc3[2] * aSr3;
    float ps3 = acc0[3] * aSr0 + acc1[3] * aSr1 + acc2[3] * aSr2 + acc3[3] * aSr3;
    float pd0 = acc0[0] * aDr0 + acc1[0] * aDr1 + acc2[0] * aDr2 + acc3[0] * aDr3;
    float pd1 = acc0[1] * aDr0 + acc1[1] * aDr1 + acc2[1] * aDr2 + acc3[1] * aDr3;
    float pd2 = acc0[2] * aDr0 + acc1[2] * aDr1 + acc2[2] * aDr2 + acc3[2] * aDr3;
    float pd3 = acc0[3] * aDr0 + acc1[3] * aDr1 + acc2[3] * aDr2 + acc3[3] * aDr3;
#pragma unroll
    for (int off = 1; off < 16; off <<= 1) {
      ps0 += __shfl_xor(ps0, off, 64); ps1 += __shfl_xor(ps1, off, 64);
      ps2 += __shfl_xor(ps2, off, 64); ps3 += __shfl_xor(ps3, off, 64);
      pd0 += __shfl_xor(pd0, off, 64); pd1 += __shfl_xor(pd1, off, 64);
      pd2 += __shfl_xor(pd2, off, 64); pd3 += __shfl_xor(pd3, off, 64);
    }
    if (r16 == 0) {
      *reinterpret_cast<float4*>(as2 + n0 + g4 * 4) = make_float4(ps0, ps1, ps2, ps3);
      *reinterpret_cast<float4*>(ad2 + n0 + g4 * 4) = make_float4(pd0, pd1, pd2, pd3);
    }
    // g -> bf16 via LDS transpose, then coalesced uint4 stores
#pragma unroll
    for (int r = 0; r < 4; r++) {
      lg[w][g4 * 4 + r][0 * 16 + r16] = f2bf(acc0[r]);
      lg[w][g4 * 4 + r][1 * 16 + r16] = f2bf(acc1[r]);
      lg[w][g4 * 4 + r][2 * 16 + r16] = f2bf(acc2[r]);
      lg[w][g4 * 4 + r][3 * 16 + r16] = f2bf(acc3[r]);
    }
    asm volatile("s_waitcnt lgkmcnt(0)" ::: "memory");
    int row = l >> 3, c = l & 7;
    uint4 v0 = *reinterpret_cast<const uint4*>(&lg[w][row][c * 8]);
    uint4 v1 = *reinterpret_cast<const uint4*>(&lg[w][8 + row][c * 8]);
    *reinterpret_cast<uint4*>(gb + (size_t)(n0 + row) * 64 + c * 8) = v0;
    *reinterpret_cast<uint4*>(gb + (size_t)(n0 + 8 + row) * 64 + c * 8) = v1;
  }
}

// ---- GAT layer 2 aggregation + frame mean: GROUP(8 lanes)-PER-NODE ----
__global__ void __launch_bounds__(256)
k_agg2mean(const int* __restrict__ rowptr, const int* __restrict__ csr,
           const unsigned short* __restrict__ gtab, const float* __restrict__ as2,
           const float* __restrict__ ad2, float* __restrict__ emb) {
  __shared__ float part[32][64];
  int t = threadIdx.x;
  int w = t >> 6, l = t & 63;
  int grp = l >> 3, q = l & 7;
  int f = blockIdx.x / BPF;
  int gf = (blockIdx.x - f * BPF) * 32 + w * 8 + grp;   // group id within frame
  const int stride = BPF * 32;
  float m0 = 0.f, m1 = 0.f, m2 = 0.f, m3 = 0.f, m4 = 0.f, m5 = 0.f, m6 = 0.f, m7 = 0.f;
  for (int j = gf; j < NN_F; j += stride) {
    int n = f * NN_F + j;
    float adv = ad2[n];
    float e0 = fexp(lrelu02(as2[n] + adv));
    uint4 pv = *reinterpret_cast<const uint4*>(gtab + (size_t)n * 64 + q * 8);
    float a0 = e0 * bf_lo(pv.x), a1 = e0 * bf_hi(pv.x);
    float a2 = e0 * bf_lo(pv.y), a3 = e0 * bf_hi(pv.y);
    float a4 = e0 * bf_lo(pv.z), a5 = e0 * bf_hi(pv.z);
    float a6 = e0 * bf_lo(pv.w), a7 = e0 * bf_hi(pv.w);
    float den = e0;
    int s0 = rowptr[n], s1 = rowptr[n + 1];
    int i = s0;
    for (; i + 2 <= s1; i += 2) {
      int src0 = csr[i], src1 = csr[i + 1];
      float ea = fexp(lrelu02(as2[src0] + adv));
      float eb = fexp(lrelu02(as2[src1] + adv));
      uint4 va = *reinterpret_cast<const uint4*>(gtab + (size_t)src0 * 64 + q * 8);
      uint4 vb = *reinterpret_cast<const uint4*>(gtab + (size_t)src1 * 64 + q * 8);
      a0 = fmaf(ea, bf_lo(va.x), a0); a1 = fmaf(ea, bf_hi(va.x), a1);
      a2 = fmaf(ea, bf_lo(va.y), a2); a3 = fmaf(ea, bf_hi(va.y), a3);
      a4 = fmaf(ea, bf_lo(va.z), a4); a5 = fmaf(ea, bf_hi(va.z), a5);
      a6 = fmaf(ea, bf_lo(va.w), a6); a7 = fmaf(ea, bf_hi(va.w), a7);
      a0 = fmaf(eb, bf_lo(vb.x), a0); a1 = fmaf(eb, bf_hi(vb.x), a1);
      a2 = fmaf(eb, bf_lo(vb.y), a2); a3 = fmaf(eb, bf_hi(vb.y), a3);
      a4 = fmaf(eb, bf_lo(vb.z), a4); a5 = fmaf(eb, bf_hi(vb.z), a5);
      a6 = fmaf(eb, bf_lo(vb.w), a6); a7 = fmaf(eb, bf_hi(vb.w), a7);
      den += ea + eb;
    }
    if (i < s1) {
      int src = csr[i];
      float e2 = fexp(lrelu02(as2[src] + adv));
      uint4 v = *reinterpret_cast<const uint4*>(gtab + (size_t)src * 64 + q * 8);
      a0 = fmaf(e2, bf_lo(v.x), a0); a1 = fmaf(e2, bf_hi(v.x), a1);
      a2 = fmaf(e2, bf_lo(v.y), a2); a3 = fmaf(e2, bf_hi(v.y), a3);
      a4 = fmaf(e2, bf_lo(v.z), a4); a5 = fmaf(e2, bf_hi(v.z), a5);
      a6 = fmaf(e2, bf_lo(v.w), a6); a7 = fmaf(e2, bf_hi(v.w), a7);
      den += e2;
    }
    float inv = 1.f / den;
    m0 = fmaf(a0, inv, m0); m1 = fmaf(a1, inv, m1);
    m2 = fmaf(a2, inv, m2); m3 = fmaf(a3, inv, m3);
    m4 = fmaf(a4, inv, m4); m5 = fmaf(a5, inv, m5);
    m6 = fmaf(a6, inv, m6); m7 = fmaf(a7, inv, m7);
  }
  float4* pr = reinterpret_cast<float4*>(&part[w * 8 + grp][q * 8]);
  pr[0] = make_float4(m0, m1, m2, m3);
  pr[1] = make_float4(m4, m5, m6, m7);
  __syncthreads();
  if (t < 64) {
    float s = 0.f;
#pragma unroll
    for (int r = 0; r < 32; r++) s += part[r][t];
    atomicAdd(&emb[f * 64 + t], s * (1.0f / NN_F));
  }
}

// ---------------- tiny transformer: 1024 threads, 16-lane-group shuffle GEMVs ----------
__device__ __forceinline__ float grp16_reduce(float p) {
#pragma unroll
  for (int off = 1; off < 16; off <<= 1) p += __shfl_xor(p, off, 64);
  return p;
}

__global__ void __launch_bounds__(1024)
k_transformer(const float* __restrict__ emb, const float* __restrict__ b2,
              const float* __restrict__ Wqkv, const float* __restrict__ bqkv,
              const float* __restrict__ Wo, const float* __restrict__ bo,
              const float* __restrict__ ln1w, const float* __restrict__ ln1b,
              const float* __restrict__ Wff1, const float* __restrict__ bff1,
              const float* __restrict__ Wff2, const float* __restrict__ bff2,
              const float* __restrict__ ln2w, const float* __restrict__ ln2b,
              const float* __restrict__ Wh1, const float* __restrict__ bh1,
              const float* __restrict__ Wh2, const float* __restrict__ bh2,
              float* __restrict__ out) {
  __shared__ float seq[5][64];
  __shared__ float qkv[5][192];
  __shared__ float att[4][5][5];
  __shared__ float aob[5][64];
  __shared__ float ffb[5][128];
  __shared__ float tmp[5][64];
  __shared__ float hid[32];
  int t = threadIdx.x;
  int l = t & 63, w = t >> 6;        // 16 waves
  int g = l >> 4, q = l & 15;        // 4 groups of 16 lanes

  if (t < 320) seq[t >> 6][t & 63] = emb[t] + b2[t & 63];
  __syncthreads();

  for (int ly = 0; ly < 3; ly++) {
    const float* Wq  = Wqkv + ly * 12288; const float* bq  = bqkv + ly * 192;
    const float* Wol = Wo   + ly * 4096;  const float* bol = bo   + ly * 64;
    const float* w1  = ln1w + ly * 64;    const float* bb1 = ln1b + ly * 64;
    const float* Wf1 = Wff1 + ly * 8192;  const float* bf1 = bff1 + ly * 128;
    const float* Wf2 = Wff2 + ly * 8192;  const float* bf2 = bff2 + ly * 64;
    const float* w2  = ln2w + ly * 64;    const float* bb2 = ln2b + ly * 64;

    for (int o = w * 4 + g; o < 960; o += 64) {
      int s = o / 192, j = o - s * 192;
      float4 wv = *reinterpret_cast<const float4*>(&Wq[j * 64 + q * 4]);
      float4 xv = *reinterpret_cast<const float4*>(&seq[s][q * 4]);
      float p = wv.x * xv.x + wv.y * xv.y + wv.z * xv.z + wv.w * xv.w;
      p = grp16_reduce(p);
      if (q == 0) qkv[s][j] = p + bq[j];
    }
    __syncthreads();

    if (t < 100) {
      int hh = t / 25, qs = (t / 5) % 5, ks = t % 5;
      float acc = 0.f;
      for (int d = 0; d < 16; d++)
        acc = fmaf(qkv[qs][hh * 16 + d], qkv[ks][64 + hh * 16 + d], acc);
      att[hh][qs][ks] = acc * 0.25f;
    }
    __syncthreads();
    if (t < 20) {
      int hh = t / 5, qs = t % 5;
      float m = att[hh][qs][0];
      for (int k2 = 1; k2 < 5; k2++) m = fmaxf(m, att[hh][qs][k2]);
      float ss = 0.f;
      for (int k2 = 0; k2 < 5; k2++) { float v = expf(att[hh][qs][k2] - m); att[hh][qs][k2] = v; ss += v; }
      float inv = 1.f / ss;
      for (int k2 = 0; k2 < 5; k2++) att[hh][qs][k2] *= inv;
    }
    __syncthreads();

    if (t < 320) {
      int s = t >> 6, j = t & 63, hh = j >> 4;
      float acc = 0.f;
      for (int k2 = 0; k2 < 5; k2++) acc = fmaf(att[hh][s][k2], qkv[k2][128 + j], acc);
      aob[s][j] = acc;
    }
    __syncthreads();

    for (int o = w * 4 + g; o < 320; o += 64) {
      int s = o >> 6, c = o & 63;
      float4 wv = *reinterpret_cast<const float4*>(&Wol[c * 64 + q * 4]);
      float4 xv = *reinterpret_cast<const float4*>(&aob[s][q * 4]);
      float p = wv.x * xv.x + wv.y * xv.y + wv.z * xv.z + wv.w * xv.w;
      p = grp16_reduce(p);
      if (q == 0) tmp[s][c] = seq[s][c] + p + bol[c];
    }
    __syncthreads();

    if (w < 5) {
      float v = tmp[w][l];
      float s1 = v, s2 = v * v;
#pragma unroll
      for (int off = 1; off < 64; off <<= 1) {
        s1 += __shfl_xor(s1, off, 64);
        s2 += __shfl_xor(s2, off, 64);
      }
      float m = s1 * (1.f / 64.f);
      float var = s2 * (1.f / 64.f) - m * m;
      float inv = 1.f / sqrtf(var + 1e-5f);
      seq[w][l] = (v - m) * inv * w1[l] + bb1[l];
    }
    __syncthreads();

    for (int o = w * 4 + g; o < 640; o += 64) {
      int s = o >> 7, j = o & 127;
      float4 wv = *reinterpret_cast<const float4*>(&Wf1[j * 64 + q * 4]);
      float4 xv = *reinterpret_cast<const float4*>(&seq[s][q * 4]);
      float p = wv.x * xv.x + wv.y * xv.y + wv.z * xv.z + wv.w * xv.w;
      p = grp16_reduce(p);
      if (q == 0) ffb[s][j] = fmaxf(p + bf1[j], 0.f);
    }
    __syncthreads();

    for (int o = w * 4 + g; o < 320; o += 64) {
      int s = o >> 6, c = o & 63;
      float4 wa = *reinterpret_cast<const float4*>(&Wf2[c * 128 + q * 8]);
      float4 wb = *reinterpret_cast<const float4*>(&Wf2[c * 128 + q * 8 + 4]);
      float4 xa = *reinterpret_cast<const float4*>(&ffb[s][q * 8]);
      float4 xb = *reinterpret_cast<const float4*>(&ffb[s][q * 8 + 4]);
      float p = wa.x * xa.x + wa.y * xa.y + wa.z * xa.z + wa.w * xa.w
              + wb.x * xb.x + wb.y * xb.y + wb.z * xb.z + wb.w * xb.w;
      p = grp16_reduce(p);
      if (q == 0) tmp[s][c] = seq[s][c] + p + bf2[c];
    }
    __syncthreads();

    if (w < 5) {
      float v = tmp[w][l];
      float s1 = v, s2 = v * v;
#pragma unroll
      for (int off = 1; off < 64; off <<= 1) {
        s1 += __shfl_xor(s1, off, 64);
        s2 += __shfl_xor(s2, off, 64);
      }
      float m = s1 * (1.f / 64.f);
      float var = s2 * (1.f / 64.f) - m * m;
      float inv = 1.f / sqrtf(var + 1e-5f);
      seq[w][l] = (v - m) * inv * w2[l] + bb2[l];
    }
    __syncthreads();
  }

  for (int o = w * 4 + g; o < 32; o += 64) {
    float4 wv = *reinterpret_cast<const float4*>(&Wh1[o * 64 + q * 4]);
    float4 xv = *reinterpret_cast<const float4*>(&seq[4][q * 4]);
    float p = wv.x * xv.x + wv.y * xv.y + wv.z * xv.z + wv.w * xv.w;
    p = grp16_reduce(p);
    if (q == 0) hid[o] = fmaxf(p + bh1[o], 0.f);
  }
  __syncthreads();
  if (t < 2) {
    float acc = bh2[t];
    for (int j = 0; j < 32; j++) acc = fmaf(hid[j], Wh2[t * 32 + j], acc);
    out[t] = acc;
  }
}

extern "C" void kernel_launch(void* const* d_in, const int* in_sizes, int n_in,
                              void* d_out, int out_size, void* d_ws, size_t ws_size,
                              hipStream_t stream) {
  const float* x     = (const float*)d_in[0];
  const int*   ei    = (const int*)d_in[1];
  const float* W1    = (const float*)d_in[2];
  const float* attS1 = (const float*)d_in[3];
  const float* attD1 = (const float*)d_in[4];
  const float* b1    = (const float*)d_in[5];
  const float* W2    = (const float*)d_in[6];
  const float* attS2 = (const float*)d_in[7];
  const float* attD2 = (const float*)d_in[8];
  const float* b2    = (const float*)d_in[9];
  const float* tWqkv = (const float*)d_in[10];
  const float* tbqkv = (const float*)d_in[11];
  const float* tWo   = (const float*)d_in[12];
  const float* tbo   = (const float*)d_in[13];
  const float* tln1w = (const float*)d_in[14];
  const float* tln1b = (const float*)d_in[15];
  const float* tWff1 = (const float*)d_in[16];
  const float* tbff1 = (const float*)d_in[17];
  const float* tWff2 = (const float*)d_in[18];
  const float* tbff2 = (const float*)d_in[19];
  const float* tln2w = (const float*)d_in[20];
  const float* tln2b = (const float*)d_in[21];
  const float* Wh1   = (const float*)d_in[22];
  const float* bh1   = (const float*)d_in[23];
  const float* Wh2   = (const float*)d_in[24];
  const float* bh2   = (const float*)d_in[25];
  float* out = (float*)d_out;

  auto need_bytes = [](int F) -> size_t {
    size_t NT = (size_t)F * NN_F, ET = (size_t)F * NE_F;
    size_t fl = NT * 18 + 320;
    size_t us = NT * 192;
    size_t it = NT * 2 + 1 + 2048 + ET * 2;
    return fl * 4 + us * 2 + it * 4;
  };
  const int F = (ws_size >= need_bytes(5)) ? 5 : 1;
  const int NT = F * NN_F, ET = F * NE_F;

  float* ws  = (float*)d_ws;
  float* as1 = ws;                          // NT*8
  float* ad1 = as1 + (size_t)NT * 8;        // NT*8
  float* as2 = ad1 + (size_t)NT * 8;        // NT
  float* ad2 = as2 + NT;                    // NT
  float* emb = ad2 + NT;                    // 320
  unsigned short* h1b   = (unsigned short*)(emb + 320);   // NT*64 bf16
  unsigned short* gb    = h1b + (size_t)NT * 64;          // NT*64 bf16
  unsigned short* out1b = gb + (size_t)NT * 64;           // NT*64 bf16
  int* deg    = (int*)(out1b + (size_t)NT * 64);          // NT
  int* rowptr = deg + NT;                   // NT+1
  int* bsum   = rowptr + NT + 1;            // <=1024
  int* boff   = bsum + 1024;                // <=1024
  int* rank   = boff + 1024;                // ET
  int* csr    = rank + ET;                  // ET

  (void)hipMemsetAsync(emb, 0, 320 * sizeof(float), stream);

  const int nblk = (NT + 255) / 256;
  const int edge4Blocks = ((ET >> 2) + 255) / 256;
  const int agg1Blocks = (NT / 8 + 3) / 4;  // group(8 lanes) per node, 32 groups/block
  const int nodeBlocks = 2048;
  const int node2Blocks = 1024;             // wave = 16-node MFMA tile

  for (int f0 = 0; f0 < 5; f0 += F) {
    const float* xf = x + (size_t)f0 * NN_F * 13;
    const int* eif  = ei + (size_t)f0 * 2 * NE_F;

    (void)hipMemsetAsync(deg, 0, NT * sizeof(int), stream);
    k_rank<<<edge4Blocks, 256, 0, stream>>>(eif, deg, rank, F);
    k_scan1<<<nblk, 256, 0, stream>>>(deg, bsum, NT);
    k_scan2<<<1, 1024, 0, stream>>>(bsum, boff, nblk);
    k_scan3<<<nblk, 256, 0, stream>>>(deg, boff, rowptr, NT, ET);
    k_place<<<edge4Blocks, 256, 0, stream>>>(eif, rowptr, rank, csr, F);

    k_node1<<<nodeBlocks, 256, 0, stream>>>(xf, W1, attS1, attD1, h1b, as1, ad1, NT);
    k_agg1<<<agg1Blocks, 256, 0, stream>>>(rowptr, csr, h1b, as1, ad1, out1b, NT);
    k_node2<<<node2Blocks, 256, 0, stream>>>(out1b, b1, W2, attS2, attD2, gb, as2, ad2, NT);
    k_agg2mean<<<F * BPF, 256, 0, stream>>>(rowptr, csr, gb, as2, ad2, emb + f0 * 64);
  }

  k_transformer<<<1, 1024, 0, stream>>>(emb, b2, tWqkv, tbqkv, tWo, tbo, tln1w, tln1b,
                                        tWff1, tbff1, tWff2, tbff2, tln2w, tln2b,
                                        Wh1, bh1, Wh2, bh2, out);
}

// Round 12
// 360.532 us; speedup vs baseline: 5.6694x; 1.0154x over previous
//
#include <hip/hip_runtime.h>
#include <math.h>

#define NN_F 50000      // nodes per frame
#define NE_F 400000     // edges per frame
#define BPF  768        // blocks per frame for fused agg2+mean (32 groups/block)

__device__ __forceinline__ float lrelu02(float x) { return x > 0.f ? x : 0.2f * x; }
__device__ __forceinline__ float fexp(float x) { return __expf(x); }

// bf16 pack (RNE) / unpack helpers
__device__ __forceinline__ unsigned short f2bf(float f) {
  unsigned int u = __float_as_uint(f);
  u += 0x7fffu + ((u >> 16) & 1u);
  return (unsigned short)(u >> 16);
}
__device__ __forceinline__ float bf_lo(unsigned int u) { return __uint_as_float(u << 16); }
__device__ __forceinline__ float bf_hi(unsigned int u) { return __uint_as_float(u & 0xffff0000u); }
__device__ __forceinline__ unsigned int pack2(float a, float b) {
  return (unsigned int)f2bf(a) | ((unsigned int)f2bf(b) << 16);
}

typedef __attribute__((ext_vector_type(8))) short bfrag_t;   // 8 bf16 (4 VGPRs)
typedef __attribute__((ext_vector_type(4))) float facc_t;    // 4 fp32 acc

// ---- FUSED: CSR rank pass (atomic-bound) ∥ GAT1 node linear (VALU-bound) ----
// blocks [0, rankBlocks): per-edge rank via histogram atomic (4x ILP)
// blocks [rankBlocks, rankBlocks+node1Blocks): wave-per-node GAT1 linear
__global__ void __launch_bounds__(256, 3)
k_rank_node1(const int* __restrict__ ei, int* __restrict__ deg,
             unsigned short* __restrict__ rank, int nFrames, int rankBlocks,
             const float* __restrict__ x, const float* __restrict__ W1,
             const float* __restrict__ attS, const float* __restrict__ attD,
             unsigned short* __restrict__ h1b, float* __restrict__ as1,
             float* __restrict__ ad1, int nNodes, int node1Blocks) {
  __shared__ float xbuf[4][16];
  if (blockIdx.x < rankBlocks) {
    // ---- rank role ----
    int tid = blockIdx.x * blockDim.x + threadIdx.x;
    int T = (nFrames * NE_F) >> 2;
    if (tid >= T) return;
    int gd[4];
#pragma unroll
    for (int i = 0; i < 4; i++) {
      int e = tid + i * T;
      int f = e / NE_F, idx = e - f * NE_F;
      gd[i] = f * NN_F + ei[(size_t)f * 2 * NE_F + NE_F + idx];
    }
    int r[4];
#pragma unroll
    for (int i = 0; i < 4; i++) r[i] = atomicAdd(&deg[gd[i]], 1);
#pragma unroll
    for (int i = 0; i < 4; i++) rank[tid + i * T] = (unsigned short)r[i];
    return;
  }
  // ---- node1 role ----
  int bid = blockIdx.x - rankBlocks;
  int l = threadIdx.x & 63;
  int w = threadIdx.x >> 6;
  int wid = (bid * blockDim.x + threadIdx.x) >> 6;
  int nw = (node1Blocks * blockDim.x) >> 6;
  float4 wA = make_float4(W1[l * 13 + 0], W1[l * 13 + 1], W1[l * 13 + 2], W1[l * 13 + 3]);
  float4 wB = make_float4(W1[l * 13 + 4], W1[l * 13 + 5], W1[l * 13 + 6], W1[l * 13 + 7]);
  float4 wC = make_float4(W1[l * 13 + 8], W1[l * 13 + 9], W1[l * 13 + 10], W1[l * 13 + 11]);
  float4 wD = make_float4(W1[l * 13 + 12], 0.f, 0.f, 0.f);
  float aS = attS[l], aD = attD[l];
  const float4* xb = reinterpret_cast<const float4*>(xbuf[w]);
  for (int n = wid; n < nNodes; n += nw) {
    if (l < 16) xbuf[w][l] = (l < 13) ? x[(size_t)n * 13 + l] : 0.f;
    float4 x0 = xb[0], x1 = xb[1], x2 = xb[2], x3 = xb[3];
    float a0 = x0.x * wA.x, a1 = x0.y * wA.y, a2 = x0.z * wA.z, a3 = x0.w * wA.w;
    a0 = fmaf(x1.x, wB.x, a0); a1 = fmaf(x1.y, wB.y, a1);
    a2 = fmaf(x1.z, wB.z, a2); a3 = fmaf(x1.w, wB.w, a3);
    a0 = fmaf(x2.x, wC.x, a0); a1 = fmaf(x2.y, wC.y, a1);
    a2 = fmaf(x2.z, wC.z, a2); a3 = fmaf(x2.w, wC.w, a3);
    a0 = fmaf(x3.x, wD.x, a0);
    float acc = (a0 + a1) + (a2 + a3);
    h1b[(size_t)n * 64 + l] = f2bf(acc);
    float s = acc * aS, d = acc * aD;
#pragma unroll
    for (int off = 1; off < 8; off <<= 1) {
      s += __shfl_xor(s, off, 64);
      d += __shfl_xor(d, off, 64);
    }
    if ((l & 7) == 0) { as1[n * 8 + (l >> 3)] = s; ad1[n * 8 + (l >> 3)] = d; }
  }
}

// ---------------- CSR build: per-block sums ----------------
__global__ void k_scan1(const int* __restrict__ deg, int* __restrict__ bsum, int nNodes) {
  __shared__ int part[256];
  int t = threadIdx.x;
  int i = blockIdx.x * 256 + t;
  part[t] = (i < nNodes) ? deg[i] : 0;
  __syncthreads();
  for (int off = 128; off > 0; off >>= 1) {
    if (t < off) part[t] += part[t + off];
    __syncthreads();
  }
  if (t == 0) bsum[blockIdx.x] = part[0];
}

// ---------------- CSR build: scan of block sums (single block, up to 1024) ----------------
__global__ void __launch_bounds__(1024)
k_scan2(const int* __restrict__ bsum, int* __restrict__ boff, int nblk) {
  __shared__ int part[1024];
  int t = threadIdx.x;
  part[t] = (t < nblk) ? bsum[t] : 0;
  __syncthreads();
  for (int off = 1; off < 1024; off <<= 1) {
    int v = (t >= off) ? part[t - off] : 0;
    __syncthreads();
    part[t] += v;
    __syncthreads();
  }
  if (t < nblk) boff[t] = part[t] - bsum[t];  // exclusive
}

// ---------------- CSR build: intra-block scan -> rowptr ----------------
__global__ void k_scan3(const int* __restrict__ deg, const int* __restrict__ boff,
                        int* __restrict__ rowptr, int nNodes, int nEdges) {
  __shared__ int part[256];
  int t = threadIdx.x;
  int i = blockIdx.x * 256 + t;
  int d = (i < nNodes) ? deg[i] : 0;
  part[t] = d;
  __syncthreads();
  for (int off = 1; off < 256; off <<= 1) {
    int v = (t >= off) ? part[t - off] : 0;
    __syncthreads();
    part[t] += v;
    __syncthreads();
  }
  if (i < nNodes) rowptr[i] = boff[blockIdx.x] + part[t] - d;  // exclusive prefix
  if (blockIdx.x == 0 && t == 0) rowptr[nNodes] = nEdges;
}

// ---- CSR build pass B: place srcs (NO atomics; 4x ILP) ----
__global__ void k_place(const int* __restrict__ ei, const int* __restrict__ rowptr,
                        const unsigned short* __restrict__ rank, int* __restrict__ csr,
                        int nFrames) {
  int tid = blockIdx.x * blockDim.x + threadIdx.x;
  int T = (nFrames * NE_F) >> 2;
  if (tid >= T) return;
#pragma unroll
  for (int i = 0; i < 4; i++) {
    int e = tid + i * T;
    int f = e / NE_F, idx = e - f * NE_F;
    const int* base = ei + (size_t)f * 2 * NE_F;
    int src = base[idx], dst = base[NE_F + idx];
    csr[rowptr[f * NN_F + dst] + (int)rank[e]] = f * NN_F + src;
  }
}

// ---- GAT layer 1 aggregation: GROUP(8 lanes)-PER-NODE; lane q = head q ----
__global__ void __launch_bounds__(256)
k_agg1(const int* __restrict__ rowptr, const int* __restrict__ csr,
       const unsigned short* __restrict__ h1b, const float* __restrict__ as1,
       const float* __restrict__ ad1, unsigned short* __restrict__ out1b, int nNodes) {
  int t = threadIdx.x;
  int l = t & 63;
  int grp = l >> 3, q = l & 7;
  int n = ((blockIdx.x * blockDim.x + t) >> 6) * 8 + grp;   // group -> node
  if (n >= nNodes) return;
  float adv = ad1[n * 8 + q];
  float e0 = fexp(lrelu02(as1[n * 8 + q] + adv));
  uint4 pv = *reinterpret_cast<const uint4*>(h1b + (size_t)n * 64 + q * 8);
  float a0 = e0 * bf_lo(pv.x), a1 = e0 * bf_hi(pv.x);
  float a2 = e0 * bf_lo(pv.y), a3 = e0 * bf_hi(pv.y);
  float a4 = e0 * bf_lo(pv.z), a5 = e0 * bf_hi(pv.z);
  float a6 = e0 * bf_lo(pv.w), a7 = e0 * bf_hi(pv.w);
  float den = e0;
  int s0 = rowptr[n], s1 = rowptr[n + 1];
  int i = s0;
  for (; i + 2 <= s1; i += 2) {
    int src0 = csr[i], src1 = csr[i + 1];
    float ea = fexp(lrelu02(as1[src0 * 8 + q] + adv));
    float eb = fexp(lrelu02(as1[src1 * 8 + q] + adv));
    uint4 va = *reinterpret_cast<const uint4*>(h1b + (size_t)src0 * 64 + q * 8);
    uint4 vb = *reinterpret_cast<const uint4*>(h1b + (size_t)src1 * 64 + q * 8);
    a0 = fmaf(ea, bf_lo(va.x), a0); a1 = fmaf(ea, bf_hi(va.x), a1);
    a2 = fmaf(ea, bf_lo(va.y), a2); a3 = fmaf(ea, bf_hi(va.y), a3);
    a4 = fmaf(ea, bf_lo(va.z), a4); a5 = fmaf(ea, bf_hi(va.z), a5);
    a6 = fmaf(ea, bf_lo(va.w), a6); a7 = fmaf(ea, bf_hi(va.w), a7);
    a0 = fmaf(eb, bf_lo(vb.x), a0); a1 = fmaf(eb, bf_hi(vb.x), a1);
    a2 = fmaf(eb, bf_lo(vb.y), a2); a3 = fmaf(eb, bf_hi(vb.y), a3);
    a4 = fmaf(eb, bf_lo(vb.z), a4); a5 = fmaf(eb, bf_hi(vb.z), a5);
    a6 = fmaf(eb, bf_lo(vb.w), a6); a7 = fmaf(eb, bf_hi(vb.w), a7);
    den += ea + eb;
  }
  if (i < s1) {
    int src = csr[i];
    float e2 = fexp(lrelu02(as1[src * 8 + q] + adv));
    uint4 v = *reinterpret_cast<const uint4*>(h1b + (size_t)src * 64 + q * 8);
    a0 = fmaf(e2, bf_lo(v.x), a0); a1 = fmaf(e2, bf_hi(v.x), a1);
    a2 = fmaf(e2, bf_lo(v.y), a2); a3 = fmaf(e2, bf_hi(v.y), a3);
    a4 = fmaf(e2, bf_lo(v.z), a4); a5 = fmaf(e2, bf_hi(v.z), a5);
    a6 = fmaf(e2, bf_lo(v.w), a6); a7 = fmaf(e2, bf_hi(v.w), a7);
    den += e2;
  }
  float inv = 1.f / den;
  uint4 o;
  o.x = pack2(a0 * inv, a1 * inv);
  o.y = pack2(a2 * inv, a3 * inv);
  o.z = pack2(a4 * inv, a5 * inv);
  o.w = pack2(a6 * inv, a7 * inv);
  *reinterpret_cast<uint4*>(out1b + (size_t)n * 64 + q * 8) = o;
}

// ---------------- node2 via MFMA: wave = 16-node tile ----------------
__global__ void __launch_bounds__(256)
k_node2(const unsigned short* __restrict__ out1b, const float* __restrict__ b1,
        const float* __restrict__ W2, const float* __restrict__ attS2,
        const float* __restrict__ attD2, unsigned short* __restrict__ gb,
        float* __restrict__ as2, float* __restrict__ ad2, int nNodes) {
  __shared__ unsigned short lg[4][16][72];   // per-wave 16x64 bf16, row stride 72 (16B-aligned)
  int t = threadIdx.x, l = t & 63, w = t >> 6;
  int r16 = l & 15, g4 = l >> 4;

  bfrag_t bfr[8];
#pragma unroll
  for (int tt = 0; tt < 4; tt++) {
    const float* wrow = W2 + (tt * 16 + r16) * 64;
#pragma unroll
    for (int kc = 0; kc < 2; kc++) {
      float4 lo = *reinterpret_cast<const float4*>(wrow + kc * 32 + 4 * g4);
      float4 hi = *reinterpret_cast<const float4*>(wrow + kc * 32 + 16 + 4 * g4);
      union { unsigned short u[8]; bfrag_t v; } pk;
      pk.u[0] = f2bf(lo.x); pk.u[1] = f2bf(lo.y); pk.u[2] = f2bf(lo.z); pk.u[3] = f2bf(lo.w);
      pk.u[4] = f2bf(hi.x); pk.u[5] = f2bf(hi.y); pk.u[6] = f2bf(hi.z); pk.u[7] = f2bf(hi.w);
      bfr[tt * 2 + kc] = pk.v;
    }
  }
  float4 bias[2][2];
#pragma unroll
  for (int kc = 0; kc < 2; kc++)
#pragma unroll
    for (int h = 0; h < 2; h++)
      bias[kc][h] = *reinterpret_cast<const float4*>(b1 + kc * 32 + h * 16 + 4 * g4);
  float aSr0 = attS2[r16], aSr1 = attS2[16 + r16], aSr2 = attS2[32 + r16], aSr3 = attS2[48 + r16];
  float aDr0 = attD2[r16], aDr1 = attD2[16 + r16], aDr2 = attD2[32 + r16], aDr3 = attD2[48 + r16];

  int wid = (blockIdx.x * blockDim.x + t) >> 6;
  int nw = (gridDim.x * blockDim.x) >> 6;
  int ntiles = nNodes >> 4;
  for (int tile = wid; tile < ntiles; tile += nw) {
    int n0 = tile << 4;
    const unsigned short* arow = out1b + (size_t)(n0 + r16) * 64;
    facc_t acc0 = 0, acc1 = 0, acc2 = 0, acc3 = 0;
#pragma unroll
    for (int kc = 0; kc < 2; kc++) {
      union { unsigned short u[8]; bfrag_t v; } apk;
#pragma unroll
      for (int h = 0; h < 2; h++) {
        uint2 raw = *reinterpret_cast<const uint2*>(arow + kc * 32 + h * 16 + 4 * g4);
        float4 bb = bias[kc][h];
        float f0 = bf_lo(raw.x) + bb.x, f1 = bf_hi(raw.x) + bb.y;
        float f2 = bf_lo(raw.y) + bb.z, f3 = bf_hi(raw.y) + bb.w;
        f0 = f0 > 0.f ? f0 : (fexp(f0) - 1.f);
        f1 = f1 > 0.f ? f1 : (fexp(f1) - 1.f);
        f2 = f2 > 0.f ? f2 : (fexp(f2) - 1.f);
        f3 = f3 > 0.f ? f3 : (fexp(f3) - 1.f);
        apk.u[h * 4 + 0] = f2bf(f0); apk.u[h * 4 + 1] = f2bf(f1);
        apk.u[h * 4 + 2] = f2bf(f2); apk.u[h * 4 + 3] = f2bf(f3);
      }
      bfrag_t afr = apk.v;
      acc0 = __builtin_amdgcn_mfma_f32_16x16x32_bf16(afr, bfr[0 * 2 + kc], acc0, 0, 0, 0);
      acc1 = __builtin_amdgcn_mfma_f32_16x16x32_bf16(afr, bfr[1 * 2 + kc], acc1, 0, 0, 0);
      acc2 = __builtin_amdgcn_mfma_f32_16x16x32_bf16(afr, bfr[2 * 2 + kc], acc2, 0, 0, 0);
      acc3 = __builtin_amdgcn_mfma_f32_16x16x32_bf16(afr, bfr[3 * 2 + kc], acc3, 0, 0, 0);
    }
    float ps0 = acc0[0] * aSr0 + acc1[0] * aSr1 + acc2[0] * aSr2 + acc3[0] * aSr3;
    float ps1 = acc0[1] * aSr0 + acc1[1] * aSr1 + acc2[1] * aSr2 + acc3[1] * aSr3;
    float ps2 = acc0[2] * aSr0 + acc1[2] * aSr1 + acc2[2] * aSr2 + acc3[2] * aSr3;
    float ps3 = acc0[3] * aSr0 + acc1[3] * aSr1 + acc2[3] * aSr2 + acc3[3] * aSr3;
    float pd0 = acc0[0] * aDr0 + acc1[0] * aDr1 + acc2[0] * aDr2 + acc3[0] * aDr3;
    float pd1 = acc0[1] * aDr0 + acc1[1] * aDr1 + acc2[1] * aDr2 + acc3[1] * aDr3;
    float pd2 = acc0[2] * aDr0 + acc1[2] * aDr1 + acc2[2] * aDr2 + acc3[2] * aDr3;
    float pd3 = acc0[3] * aDr0 + acc1[3] * aDr1 + acc2[3] * aDr2 + acc3[3] * aDr3;
#pragma unroll
    for (int off = 1; off < 16; off <<= 1) {
      ps0 += __shfl_xor(ps0, off, 64); ps1 += __shfl_xor(ps1, off, 64);
      ps2 += __shfl_xor(ps2, off, 64); ps3 += __shfl_xor(ps3, off, 64);
      pd0 += __shfl_xor(pd0, off, 64); pd1 += __shfl_xor(pd1, off, 64);
      pd2 += __shfl_xor(pd2, off, 64); pd3 += __shfl_xor(pd3, off, 64);
    }
    if (r16 == 0) {
      *reinterpret_cast<float4*>(as2 + n0 + g4 * 4) = make_float4(ps0, ps1, ps2, ps3);
      *reinterpret_cast<float4*>(ad2 + n0 + g4 * 4) = make_float4(pd0, pd1, pd2, pd3);
    }
#pragma unroll
    for (int r = 0; r < 4; r++) {
      lg[w][g4 * 4 + r][0 * 16 + r16] = f2bf(acc0[r]);
      lg[w][g4 * 4 + r][1 * 16 + r16] = f2bf(acc1[r]);
      lg[w][g4 * 4 + r][2 * 16 + r16] = f2bf(acc2[r]);
      lg[w][g4 * 4 + r][3 * 16 + r16] = f2bf(acc3[r]);
    }
    asm volatile("s_waitcnt lgkmcnt(0)" ::: "memory");
    int row = l >> 3, c = l & 7;
    uint4 v0 = *reinterpret_cast<const uint4*>(&lg[w][row][c * 8]);
    uint4 v1 = *reinterpret_cast<const uint4*>(&lg[w][8 + row][c * 8]);
    *reinterpret_cast<uint4*>(gb + (size_t)(n0 + row) * 64 + c * 8) = v0;
    *reinterpret_cast<uint4*>(gb + (size_t)(n0 + 8 + row) * 64 + c * 8) = v1;
  }
}

// ---- GAT layer 2 aggregation + frame mean: GROUP(8 lanes)-PER-NODE ----
__global__ void __launch_bounds__(256)
k_agg2mean(const int* __restrict__ rowptr, const int* __restrict__ csr,
           const unsigned short* __restrict__ gtab, const float* __restrict__ as2,
           const float* __restrict__ ad2, float* __restrict__ emb) {
  __shared__ float part[32][64];
  int t = threadIdx.x;
  int w = t >> 6, l = t & 63;
  int grp = l >> 3, q = l & 7;
  int f = blockIdx.x / BPF;
  int gf = (blockIdx.x - f * BPF) * 32 + w * 8 + grp;   // group id within frame
  const int stride = BPF * 32;
  float m0 = 0.f, m1 = 0.f, m2 = 0.f, m3 = 0.f, m4 = 0.f, m5 = 0.f, m6 = 0.f, m7 = 0.f;
  for (int j = gf; j < NN_F; j += stride) {
    int n = f * NN_F + j;
    float adv = ad2[n];
    float e0 = fexp(lrelu02(as2[n] + adv));
    uint4 pv = *reinterpret_cast<const uint4*>(gtab + (size_t)n * 64 + q * 8);
    float a0 = e0 * bf_lo(pv.x), a1 = e0 * bf_hi(pv.x);
    float a2 = e0 * bf_lo(pv.y), a3 = e0 * bf_hi(pv.y);
    float a4 = e0 * bf_lo(pv.z), a5 = e0 * bf_hi(pv.z);
    float a6 = e0 * bf_lo(pv.w), a7 = e0 * bf_hi(pv.w);
    float den = e0;
    int s0 = rowptr[n], s1 = rowptr[n + 1];
    int i = s0;
    for (; i + 2 <= s1; i += 2) {
      int src0 = csr[i], src1 = csr[i + 1];
      float ea = fexp(lrelu02(as2[src0] + adv));
      float eb = fexp(lrelu02(as2[src1] + adv));
      uint4 va = *reinterpret_cast<const uint4*>(gtab + (size_t)src0 * 64 + q * 8);
      uint4 vb = *reinterpret_cast<const uint4*>(gtab + (size_t)src1 * 64 + q * 8);
      a0 = fmaf(ea, bf_lo(va.x), a0); a1 = fmaf(ea, bf_hi(va.x), a1);
      a2 = fmaf(ea, bf_lo(va.y), a2); a3 = fmaf(ea, bf_hi(va.y), a3);
      a4 = fmaf(ea, bf_lo(va.z), a4); a5 = fmaf(ea, bf_hi(va.z), a5);
      a6 = fmaf(ea, bf_lo(va.w), a6); a7 = fmaf(ea, bf_hi(va.w), a7);
      a0 = fmaf(eb, bf_lo(vb.x), a0); a1 = fmaf(eb, bf_hi(vb.x), a1);
      a2 = fmaf(eb, bf_lo(vb.y), a2); a3 = fmaf(eb, bf_hi(vb.y), a3);
      a4 = fmaf(eb, bf_lo(vb.z), a4); a5 = fmaf(eb, bf_hi(vb.z), a5);
      a6 = fmaf(eb, bf_lo(vb.w), a6); a7 = fmaf(eb, bf_hi(vb.w), a7);
      den += ea + eb;
    }
    if (i < s1) {
      int src = csr[i];
      float e2 = fexp(lrelu02(as2[src] + adv));
      uint4 v = *reinterpret_cast<const uint4*>(gtab + (size_t)src * 64 + q * 8);
      a0 = fmaf(e2, bf_lo(v.x), a0); a1 = fmaf(e2, bf_hi(v.x), a1);
      a2 = fmaf(e2, bf_lo(v.y), a2); a3 = fmaf(e2, bf_hi(v.y), a3);
      a4 = fmaf(e2, bf_lo(v.z), a4); a5 = fmaf(e2, bf_hi(v.z), a5);
      a6 = fmaf(e2, bf_lo(v.w), a6); a7 = fmaf(e2, bf_hi(v.w), a7);
      den += e2;
    }
    float inv = 1.f / den;
    m0 = fmaf(a0, inv, m0); m1 = fmaf(a1, inv, m1);
    m2 = fmaf(a2, inv, m2); m3 = fmaf(a3, inv, m3);
    m4 = fmaf(a4, inv, m4); m5 = fmaf(a5, inv, m5);
    m6 = fmaf(a6, inv, m6); m7 = fmaf(a7, inv, m7);
  }
  float4* pr = reinterpret_cast<float4*>(&part[w * 8 + grp][q * 8]);
  pr[0] = make_float4(m0, m1, m2, m3);
  pr[1] = make_float4(m4, m5, m6, m7);
  __syncthreads();
  if (t < 64) {
    float s = 0.f;
#pragma unroll
    for (int r = 0; r < 32; r++) s += part[r][t];
    atomicAdd(&emb[f * 64 + t], s * (1.0f / NN_F));
  }
}

// ---------------- tiny transformer: 1024 threads, 16-lane-group shuffle GEMVs ----------
__device__ __forceinline__ float grp16_reduce(float p) {
#pragma unroll
  for (int off = 1; off < 16; off <<= 1) p += __shfl_xor(p, off, 64);
  return p;
}

__global__ void __launch_bounds__(1024)
k_transformer(const float* __restrict__ emb, const float* __restrict__ b2,
              const float* __restrict__ Wqkv, const float* __restrict__ bqkv,
              const float* __restrict__ Wo, const float* __restrict__ bo,
              const float* __restrict__ ln1w, const float* __restrict__ ln1b,
              const float* __restrict__ Wff1, const float* __restrict__ bff1,
              const float* __restrict__ Wff2, const float* __restrict__ bff2,
              const float* __restrict__ ln2w, const float* __restrict__ ln2b,
              const float* __restrict__ Wh1, const float* __restrict__ bh1,
              const float* __restrict__ Wh2, const float* __restrict__ bh2,
              float* __restrict__ out) {
  __shared__ float seq[5][64];
  __shared__ float qkv[5][192];
  __shared__ float att[4][5][5];
  __shared__ float aob[5][64];
  __shared__ float ffb[5][128];
  __shared__ float tmp[5][64];
  __shared__ float hid[32];
  int t = threadIdx.x;
  int l = t & 63, w = t >> 6;        // 16 waves
  int g = l >> 4, q = l & 15;        // 4 groups of 16 lanes

  if (t < 320) seq[t >> 6][t & 63] = emb[t] + b2[t & 63];
  __syncthreads();

  for (int ly = 0; ly < 3; ly++) {
    const float* Wq  = Wqkv + ly * 12288; const float* bq  = bqkv + ly * 192;
    const float* Wol = Wo   + ly * 4096;  const float* bol = bo   + ly * 64;
    const float* w1  = ln1w + ly * 64;    const float* bb1 = ln1b + ly * 64;
    const float* Wf1 = Wff1 + ly * 8192;  const float* bf1 = bff1 + ly * 128;
    const float* Wf2 = Wff2 + ly * 8192;  const float* bf2 = bff2 + ly * 64;
    const float* w2  = ln2w + ly * 64;    const float* bb2 = ln2b + ly * 64;

    for (int o = w * 4 + g; o < 960; o += 64) {
      int s = o / 192, j = o - s * 192;
      float4 wv = *reinterpret_cast<const float4*>(&Wq[j * 64 + q * 4]);
      float4 xv = *reinterpret_cast<const float4*>(&seq[s][q * 4]);
      float p = wv.x * xv.x + wv.y * xv.y + wv.z * xv.z + wv.w * xv.w;
      p = grp16_reduce(p);
      if (q == 0) qkv[s][j] = p + bq[j];
    }
    __syncthreads();

    if (t < 100) {
      int hh = t / 25, qs = (t / 5) % 5, ks = t % 5;
      float acc = 0.f;
      for (int d = 0; d < 16; d++)
        acc = fmaf(qkv[qs][hh * 16 + d], qkv[ks][64 + hh * 16 + d], acc);
      att[hh][qs][ks] = acc * 0.25f;
    }
    __syncthreads();
    if (t < 20) {
      int hh = t / 5, qs = t % 5;
      float m = att[hh][qs][0];
      for (int k2 = 1; k2 < 5; k2++) m = fmaxf(m, att[hh][qs][k2]);
      float ss = 0.f;
      for (int k2 = 0; k2 < 5; k2++) { float v = expf(att[hh][qs][k2] - m); att[hh][qs][k2] = v; ss += v; }
      float inv = 1.f / ss;
      for (int k2 = 0; k2 < 5; k2++) att[hh][qs][k2] *= inv;
    }
    __syncthreads();

    if (t < 320) {
      int s = t >> 6, j = t & 63, hh = j >> 4;
      float acc = 0.f;
      for (int k2 = 0; k2 < 5; k2++) acc = fmaf(att[hh][s][k2], qkv[k2][128 + j], acc);
      aob[s][j] = acc;
    }
    __syncthreads();

    for (int o = w * 4 + g; o < 320; o += 64) {
      int s = o >> 6, c = o & 63;
      float4 wv = *reinterpret_cast<const float4*>(&Wol[c * 64 + q * 4]);
      float4 xv = *reinterpret_cast<const float4*>(&aob[s][q * 4]);
      float p = wv.x * xv.x + wv.y * xv.y + wv.z * xv.z + wv.w * xv.w;
      p = grp16_reduce(p);
      if (q == 0) tmp[s][c] = seq[s][c] + p + bol[c];
    }
    __syncthreads();

    if (w < 5) {
      float v = tmp[w][l];
      float s1 = v, s2 = v * v;
#pragma unroll
      for (int off = 1; off < 64; off <<= 1) {
        s1 += __shfl_xor(s1, off, 64);
        s2 += __shfl_xor(s2, off, 64);
      }
      float m = s1 * (1.f / 64.f);
      float var = s2 * (1.f / 64.f) - m * m;
      float inv = 1.f / sqrtf(var + 1e-5f);
      seq[w][l] = (v - m) * inv * w1[l] + bb1[l];
    }
    __syncthreads();

    for (int o = w * 4 + g; o < 640; o += 64) {
      int s = o >> 7, j = o & 127;
      float4 wv = *reinterpret_cast<const float4*>(&Wf1[j * 64 + q * 4]);
      float4 xv = *reinterpret_cast<const float4*>(&seq[s][q * 4]);
      float p = wv.x * xv.x + wv.y * xv.y + wv.z * xv.z + wv.w * xv.w;
      p = grp16_reduce(p);
      if (q == 0) ffb[s][j] = fmaxf(p + bf1[j], 0.f);
    }
    __syncthreads();

    for (int o = w * 4 + g; o < 320; o += 64) {
      int s = o >> 6, c = o & 63;
      float4 wa = *reinterpret_cast<const float4*>(&Wf2[c * 128 + q * 8]);
      float4 wb = *reinterpret_cast<const float4*>(&Wf2[c * 128 + q * 8 + 4]);
      float4 xa = *reinterpret_cast<const float4*>(&ffb[s][q * 8]);
      float4 xb = *reinterpret_cast<const float4*>(&ffb[s][q * 8 + 4]);
      float p = wa.x * xa.x + wa.y * xa.y + wa.z * xa.z + wa.w * xa.w
              + wb.x * xb.x + wb.y * xb.y + wb.z * xb.z + wb.w * xb.w;
      p = grp16_reduce(p);
      if (q == 0) tmp[s][c] = seq[s][c] + p + bf2[c];
    }
    __syncthreads();

    if (w < 5) {
      float v = tmp[w][l];
      float s1 = v, s2 = v * v;
#pragma unroll
      for (int off = 1; off < 64; off <<= 1) {
        s1 += __shfl_xor(s1, off, 64);
        s2 += __shfl_xor(s2, off, 64);
      }
      float m = s1 * (1.f / 64.f);
      float var = s2 * (1.f / 64.f) - m * m;
      float inv = 1.f / sqrtf(var + 1e-5f);
      seq[w][l] = (v - m) * inv * w2[l] + bb2[l];
    }
    __syncthreads();
  }

  for (int o = w * 4 + g; o < 32; o += 64) {
    float4 wv = *reinterpret_cast<const float4*>(&Wh1[o * 64 + q * 4]);
    float4 xv = *reinterpret_cast<const float4*>(&seq[4][q * 4]);
    float p = wv.x * xv.x + wv.y * xv.y + wv.z * xv.z + wv.w * xv.w;
    p = grp16_reduce(p);
    if (q == 0) hid[o] = fmaxf(p + bh1[o], 0.f);
  }
  __syncthreads();
  if (t < 2) {
    float acc = bh2[t];
    for (int j = 0; j < 32; j++) acc = fmaf(hid[j], Wh2[t * 32 + j], acc);
    out[t] = acc;
  }
}

extern "C" void kernel_launch(void* const* d_in, const int* in_sizes, int n_in,
                              void* d_out, int out_size, void* d_ws, size_t ws_size,
                              hipStream_t stream) {
  const float* x     = (const float*)d_in[0];
  const int*   ei    = (const int*)d_in[1];
  const float* W1    = (const float*)d_in[2];
  const float* attS1 = (const float*)d_in[3];
  const float* attD1 = (const float*)d_in[4];
  const float* b1    = (const float*)d_in[5];
  const float* W2    = (const float*)d_in[6];
  const float* attS2 = (const float*)d_in[7];
  const float* attD2 = (const float*)d_in[8];
  const float* b2    = (const float*)d_in[9];
  const float* tWqkv = (const float*)d_in[10];
  const float* tbqkv = (const float*)d_in[11];
  const float* tWo   = (const float*)d_in[12];
  const float* tbo   = (const float*)d_in[13];
  const float* tln1w = (const float*)d_in[14];
  const float* tln1b = (const float*)d_in[15];
  const float* tWff1 = (const float*)d_in[16];
  const float* tbff1 = (const float*)d_in[17];
  const float* tWff2 = (const float*)d_in[18];
  const float* tbff2 = (const float*)d_in[19];
  const float* tln2w = (const float*)d_in[20];
  const float* tln2b = (const float*)d_in[21];
  const float* Wh1   = (const float*)d_in[22];
  const float* bh1   = (const float*)d_in[23];
  const float* Wh2   = (const float*)d_in[24];
  const float* bh2   = (const float*)d_in[25];
  float* out = (float*)d_out;

  // floats: as1/ad1 NT*16 + as2/ad2 NT*2 + emb 320
  // ushorts: h1b/gb/out1b NT*64 each (bf16) + rank ET
  // ints: deg NT + rowptr NT+1 + bsum/boff 2048 + csr ET
  auto need_bytes = [](int F) -> size_t {
    size_t NT = (size_t)F * NN_F, ET = (size_t)F * NE_F;
    return (NT * 18 + 320) * 4 + (NT * 192 + ET) * 2 + (NT * 2 + 1 + 2048 + ET) * 4;
  };
  const int F = (ws_size >= need_bytes(5)) ? 5 : 1;
  const int NT = F * NN_F, ET = F * NE_F;

  float* ws  = (float*)d_ws;
  float* as1 = ws;                          // NT*8
  float* ad1 = as1 + (size_t)NT * 8;        // NT*8
  float* as2 = ad1 + (size_t)NT * 8;        // NT
  float* ad2 = as2 + NT;                    // NT
  float* emb = ad2 + NT;                    // 320
  unsigned short* h1b   = (unsigned short*)(emb + 320);   // NT*64 bf16
  unsigned short* gb    = h1b + (size_t)NT * 64;          // NT*64 bf16
  unsigned short* out1b = gb + (size_t)NT * 64;           // NT*64 bf16
  int* deg    = (int*)(out1b + (size_t)NT * 64);          // NT
  int* rowptr = deg + NT;                   // NT+1
  int* bsum   = rowptr + NT + 1;            // <=1024
  int* boff   = bsum + 1024;                // <=1024
  unsigned short* rank = (unsigned short*)(boff + 1024);  // ET (ushort)
  int* csr    = (int*)(rank + ET);          // ET

  (void)hipMemsetAsync(emb, 0, 320 * sizeof(float), stream);

  const int nblk = (NT + 255) / 256;
  const int edge4Blocks = ((ET >> 2) + 255) / 256;
  const int agg1Blocks = (NT / 8 + 3) / 4;  // group(8 lanes) per node, 32 groups/block
  const int node1Blocks = 2048;
  const int node2Blocks = 1024;             // wave = 16-node MFMA tile

  for (int f0 = 0; f0 < 5; f0 += F) {
    const float* xf = x + (size_t)f0 * NN_F * 13;
    const int* eif  = ei + (size_t)f0 * 2 * NE_F;

    (void)hipMemsetAsync(deg, 0, NT * sizeof(int), stream);
    // fused: CSR rank pass (atomic-bound) runs concurrently with node1 (VALU-bound)
    k_rank_node1<<<edge4Blocks + node1Blocks, 256, 0, stream>>>(
        eif, deg, rank, F, edge4Blocks,
        xf, W1, attS1, attD1, h1b, as1, ad1, NT, node1Blocks);
    k_scan1<<<nblk, 256, 0, stream>>>(deg, bsum, NT);
    k_scan2<<<1, 1024, 0, stream>>>(bsum, boff, nblk);
    k_scan3<<<nblk, 256, 0, stream>>>(deg, boff, rowptr, NT, ET);
    k_place<<<edge4Blocks, 256, 0, stream>>>(eif, rowptr, rank, csr, F);

    k_agg1<<<agg1Blocks, 256, 0, stream>>>(rowptr, csr, h1b, as1, ad1, out1b, NT);
    k_node2<<<node2Blocks, 256, 0, stream>>>(out1b, b1, W2, attS2, attD2, gb, as2, ad2, NT);
    k_agg2mean<<<F * BPF, 256, 0, stream>>>(rowptr, csr, gb, as2, ad2, emb + f0 * 64);
  }

  k_transformer<<<1, 1024, 0, stream>>>(emb, b2, tWqkv, tbqkv, tWo, tbo, tln1w, tln1b,
                                        tWff1, tbff1, tWff2, tbff2, tln2w, tln2b,
                                        Wh1, bh1, Wh2, bh2, out);
}

// Round 13
// 355.133 us; speedup vs baseline: 5.7556x; 1.0152x over previous
//
#include <hip/hip_runtime.h>
#include <math.h>

#define NN_F 50000      // nodes per frame
#define NE_F 400000     // edges per frame
#define BPF  768        // blocks per frame for fused agg2+mean (32 groups/block)

__device__ __forceinline__ float lrelu02(float x) { return x > 0.f ? x : 0.2f * x; }
__device__ __forceinline__ float fexp(float x) { return __expf(x); }
#define PIN(v) asm volatile("" : "+v"(v))

// bf16 pack (RNE) / unpack helpers
__device__ __forceinline__ unsigned short f2bf(float f) {
  unsigned int u = __float_as_uint(f);
  u += 0x7fffu + ((u >> 16) & 1u);
  return (unsigned short)(u >> 16);
}
__device__ __forceinline__ float bf_lo(unsigned int u) { return __uint_as_float(u << 16); }
__device__ __forceinline__ float bf_hi(unsigned int u) { return __uint_as_float(u & 0xffff0000u); }
__device__ __forceinline__ unsigned int pack2(float a, float b) {
  return (unsigned int)f2bf(a) | ((unsigned int)f2bf(b) << 16);
}

typedef __attribute__((ext_vector_type(8))) short bfrag_t;   // 8 bf16 (4 VGPRs)
typedef __attribute__((ext_vector_type(4))) float facc_t;    // 4 fp32 acc

// ---- FUSED: CSR rank pass (atomic-bound) ∥ GAT1 node linear (VALU-bound) ----
// Register pinning (PIN) prevents the allocator from rematerializing node1's
// loop-invariant weights (round-12 pathology: shared 24-VGPR allocation).
__global__ void __launch_bounds__(256, 3)
k_rank_node1(const int* __restrict__ ei, int* __restrict__ deg,
             unsigned short* __restrict__ rank, int nFrames, int rankBlocks,
             const float* __restrict__ x, const float* __restrict__ W1,
             const float* __restrict__ attS, const float* __restrict__ attD,
             unsigned short* __restrict__ h1b, float* __restrict__ as1,
             float* __restrict__ ad1, int nNodes, int node1Blocks) {
  __shared__ float xbuf[4][16];
  if (blockIdx.x < rankBlocks) {
    // ---- rank role ----
    int tid = blockIdx.x * blockDim.x + threadIdx.x;
    int T = (nFrames * NE_F) >> 2;
    if (tid >= T) return;
    int gd[4];
#pragma unroll
    for (int i = 0; i < 4; i++) {
      int e = tid + i * T;
      int f = e / NE_F, idx = e - f * NE_F;
      gd[i] = f * NN_F + ei[(size_t)f * 2 * NE_F + NE_F + idx];
    }
    int r[4];
#pragma unroll
    for (int i = 0; i < 4; i++) r[i] = atomicAdd(&deg[gd[i]], 1);
#pragma unroll
    for (int i = 0; i < 4; i++) rank[tid + i * T] = (unsigned short)r[i];
    return;
  }
  // ---- node1 role ----
  int bid = blockIdx.x - rankBlocks;
  int l = threadIdx.x & 63;
  int w = threadIdx.x >> 6;
  int wid = (bid * blockDim.x + threadIdx.x) >> 6;
  int nw = (node1Blocks * blockDim.x) >> 6;
  float w0 = W1[l * 13 + 0], w1 = W1[l * 13 + 1], w2 = W1[l * 13 + 2], w3 = W1[l * 13 + 3];
  float w4 = W1[l * 13 + 4], w5 = W1[l * 13 + 5], w6 = W1[l * 13 + 6], w7 = W1[l * 13 + 7];
  float w8 = W1[l * 13 + 8], w9 = W1[l * 13 + 9], w10 = W1[l * 13 + 10], w11 = W1[l * 13 + 11];
  float w12 = W1[l * 13 + 12];
  float aS = attS[l], aD = attD[l];
  // pin: forbid rematerialization of these 15 loads inside the node loop
  PIN(w0); PIN(w1); PIN(w2); PIN(w3); PIN(w4); PIN(w5); PIN(w6); PIN(w7);
  PIN(w8); PIN(w9); PIN(w10); PIN(w11); PIN(w12); PIN(aS); PIN(aD);
  const float4* xb = reinterpret_cast<const float4*>(xbuf[w]);
  for (int n = wid; n < nNodes; n += nw) {
    if (l < 16) xbuf[w][l] = (l < 13) ? x[(size_t)n * 13 + l] : 0.f;
    float4 x0 = xb[0], x1 = xb[1], x2 = xb[2], x3 = xb[3];
    float a0 = x0.x * w0, a1 = x0.y * w1, a2 = x0.z * w2, a3 = x0.w * w3;
    a0 = fmaf(x1.x, w4, a0); a1 = fmaf(x1.y, w5, a1);
    a2 = fmaf(x1.z, w6, a2); a3 = fmaf(x1.w, w7, a3);
    a0 = fmaf(x2.x, w8, a0); a1 = fmaf(x2.y, w9, a1);
    a2 = fmaf(x2.z, w10, a2); a3 = fmaf(x2.w, w11, a3);
    a0 = fmaf(x3.x, w12, a0);
    float acc = (a0 + a1) + (a2 + a3);
    h1b[(size_t)n * 64 + l] = f2bf(acc);
    float s = acc * aS, d = acc * aD;
#pragma unroll
    for (int off = 1; off < 8; off <<= 1) {
      s += __shfl_xor(s, off, 64);
      d += __shfl_xor(d, off, 64);
    }
    if ((l & 7) == 0) { as1[n * 8 + (l >> 3)] = s; ad1[n * 8 + (l >> 3)] = d; }
  }
}

// ---------------- CSR build: per-block sums ----------------
__global__ void k_scan1(const int* __restrict__ deg, int* __restrict__ bsum, int nNodes) {
  __shared__ int part[256];
  int t = threadIdx.x;
  int i = blockIdx.x * 256 + t;
  part[t] = (i < nNodes) ? deg[i] : 0;
  __syncthreads();
  for (int off = 128; off > 0; off >>= 1) {
    if (t < off) part[t] += part[t + off];
    __syncthreads();
  }
  if (t == 0) bsum[blockIdx.x] = part[0];
}

// ---------------- CSR build: scan of block sums (single block, up to 1024) ----------------
__global__ void __launch_bounds__(1024)
k_scan2(const int* __restrict__ bsum, int* __restrict__ boff, int nblk) {
  __shared__ int part[1024];
  int t = threadIdx.x;
  part[t] = (t < nblk) ? bsum[t] : 0;
  __syncthreads();
  for (int off = 1; off < 1024; off <<= 1) {
    int v = (t >= off) ? part[t - off] : 0;
    __syncthreads();
    part[t] += v;
    __syncthreads();
  }
  if (t < nblk) boff[t] = part[t] - bsum[t];  // exclusive
}

// ---------------- CSR build: intra-block scan -> rowptr ----------------
__global__ void k_scan3(const int* __restrict__ deg, const int* __restrict__ boff,
                        int* __restrict__ rowptr, int nNodes, int nEdges) {
  __shared__ int part[256];
  int t = threadIdx.x;
  int i = blockIdx.x * 256 + t;
  int d = (i < nNodes) ? deg[i] : 0;
  part[t] = d;
  __syncthreads();
  for (int off = 1; off < 256; off <<= 1) {
    int v = (t >= off) ? part[t - off] : 0;
    __syncthreads();
    part[t] += v;
    __syncthreads();
  }
  if (i < nNodes) rowptr[i] = boff[blockIdx.x] + part[t] - d;  // exclusive prefix
  if (blockIdx.x == 0 && t == 0) rowptr[nNodes] = nEdges;
}

// ---- CSR build pass B: place srcs (NO atomics; 4x ILP) ----
__global__ void k_place(const int* __restrict__ ei, const int* __restrict__ rowptr,
                        const unsigned short* __restrict__ rank, int* __restrict__ csr,
                        int nFrames) {
  int tid = blockIdx.x * blockDim.x + threadIdx.x;
  int T = (nFrames * NE_F) >> 2;
  if (tid >= T) return;
#pragma unroll
  for (int i = 0; i < 4; i++) {
    int e = tid + i * T;
    int f = e / NE_F, idx = e - f * NE_F;
    const int* base = ei + (size_t)f * 2 * NE_F;
    int src = base[idx], dst = base[NE_F + idx];
    csr[rowptr[f * NN_F + dst] + (int)rank[e]] = f * NN_F + src;
  }
}

// single-edge accumulate helper (bf16 gather)
#define EDGE_ACC(tab, srcv, attarr, attidx)                          \
  {                                                                  \
    float e2 = fexp(lrelu02(attarr[attidx] + adv));                  \
    uint4 v = *reinterpret_cast<const uint4*>(tab + (size_t)(srcv) * 64 + q * 8); \
    a0 = fmaf(e2, bf_lo(v.x), a0); a1 = fmaf(e2, bf_hi(v.x), a1);    \
    a2 = fmaf(e2, bf_lo(v.y), a2); a3 = fmaf(e2, bf_hi(v.y), a3);    \
    a4 = fmaf(e2, bf_lo(v.z), a4); a5 = fmaf(e2, bf_hi(v.z), a5);    \
    a6 = fmaf(e2, bf_lo(v.w), a6); a7 = fmaf(e2, bf_hi(v.w), a7);    \
    den += e2;                                                       \
  }

// ---- GAT layer 1 aggregation: GROUP(8 lanes)-PER-NODE; lane q = head q ----
__global__ void __launch_bounds__(256)
k_agg1(const int* __restrict__ rowptr, const int* __restrict__ csr,
       const unsigned short* __restrict__ h1b, const float* __restrict__ as1,
       const float* __restrict__ ad1, unsigned short* __restrict__ out1b, int nNodes) {
  int t = threadIdx.x;
  int l = t & 63;
  int grp = l >> 3, q = l & 7;
  int n = ((blockIdx.x * blockDim.x + t) >> 6) * 8 + grp;   // group -> node
  if (n >= nNodes) return;
  float adv = ad1[n * 8 + q];
  float e0 = fexp(lrelu02(as1[n * 8 + q] + adv));
  uint4 pv = *reinterpret_cast<const uint4*>(h1b + (size_t)n * 64 + q * 8);
  float a0 = e0 * bf_lo(pv.x), a1 = e0 * bf_hi(pv.x);
  float a2 = e0 * bf_lo(pv.y), a3 = e0 * bf_hi(pv.y);
  float a4 = e0 * bf_lo(pv.z), a5 = e0 * bf_hi(pv.z);
  float a6 = e0 * bf_lo(pv.w), a7 = e0 * bf_hi(pv.w);
  float den = e0;
  int s0 = rowptr[n], s1 = rowptr[n + 1];
  int i = s0;
  for (; i + 4 <= s1; i += 4) {   // 4-way unroll: 4 gather chains in flight per group
    int sa = csr[i], sb = csr[i + 1], sc = csr[i + 2], sd = csr[i + 3];
    float ea = fexp(lrelu02(as1[sa * 8 + q] + adv));
    float eb = fexp(lrelu02(as1[sb * 8 + q] + adv));
    float ec = fexp(lrelu02(as1[sc * 8 + q] + adv));
    float ed = fexp(lrelu02(as1[sd * 8 + q] + adv));
    uint4 va = *reinterpret_cast<const uint4*>(h1b + (size_t)sa * 64 + q * 8);
    uint4 vb = *reinterpret_cast<const uint4*>(h1b + (size_t)sb * 64 + q * 8);
    uint4 vc = *reinterpret_cast<const uint4*>(h1b + (size_t)sc * 64 + q * 8);
    uint4 vd = *reinterpret_cast<const uint4*>(h1b + (size_t)sd * 64 + q * 8);
    a0 = fmaf(ea, bf_lo(va.x), a0); a1 = fmaf(ea, bf_hi(va.x), a1);
    a2 = fmaf(ea, bf_lo(va.y), a2); a3 = fmaf(ea, bf_hi(va.y), a3);
    a4 = fmaf(ea, bf_lo(va.z), a4); a5 = fmaf(ea, bf_hi(va.z), a5);
    a6 = fmaf(ea, bf_lo(va.w), a6); a7 = fmaf(ea, bf_hi(va.w), a7);
    a0 = fmaf(eb, bf_lo(vb.x), a0); a1 = fmaf(eb, bf_hi(vb.x), a1);
    a2 = fmaf(eb, bf_lo(vb.y), a2); a3 = fmaf(eb, bf_hi(vb.y), a3);
    a4 = fmaf(eb, bf_lo(vb.z), a4); a5 = fmaf(eb, bf_hi(vb.z), a5);
    a6 = fmaf(eb, bf_lo(vb.w), a6); a7 = fmaf(eb, bf_hi(vb.w), a7);
    a0 = fmaf(ec, bf_lo(vc.x), a0); a1 = fmaf(ec, bf_hi(vc.x), a1);
    a2 = fmaf(ec, bf_lo(vc.y), a2); a3 = fmaf(ec, bf_hi(vc.y), a3);
    a4 = fmaf(ec, bf_lo(vc.z), a4); a5 = fmaf(ec, bf_hi(vc.z), a5);
    a6 = fmaf(ec, bf_lo(vc.w), a6); a7 = fmaf(ec, bf_hi(vc.w), a7);
    a0 = fmaf(ed, bf_lo(vd.x), a0); a1 = fmaf(ed, bf_hi(vd.x), a1);
    a2 = fmaf(ed, bf_lo(vd.y), a2); a3 = fmaf(ed, bf_hi(vd.y), a3);
    a4 = fmaf(ed, bf_lo(vd.z), a4); a5 = fmaf(ed, bf_hi(vd.z), a5);
    a6 = fmaf(ed, bf_lo(vd.w), a6); a7 = fmaf(ed, bf_hi(vd.w), a7);
    den += (ea + eb) + (ec + ed);
  }
  for (; i < s1; i++) {
    int src = csr[i];
    EDGE_ACC(h1b, src, as1, src * 8 + q)
  }
  float inv = 1.f / den;
  uint4 o;
  o.x = pack2(a0 * inv, a1 * inv);
  o.y = pack2(a2 * inv, a3 * inv);
  o.z = pack2(a4 * inv, a5 * inv);
  o.w = pack2(a6 * inv, a7 * inv);
  *reinterpret_cast<uint4*>(out1b + (size_t)n * 64 + q * 8) = o;
}

// ---------------- node2 via MFMA: wave = 16-node tile ----------------
__global__ void __launch_bounds__(256)
k_node2(const unsigned short* __restrict__ out1b, const float* __restrict__ b1,
        const float* __restrict__ W2, const float* __restrict__ attS2,
        const float* __restrict__ attD2, unsigned short* __restrict__ gb,
        float* __restrict__ as2, float* __restrict__ ad2, int nNodes) {
  __shared__ unsigned short lg[4][16][72];   // per-wave 16x64 bf16, row stride 72 (16B-aligned)
  int t = threadIdx.x, l = t & 63, w = t >> 6;
  int r16 = l & 15, g4 = l >> 4;

  bfrag_t bfr[8];
#pragma unroll
  for (int tt = 0; tt < 4; tt++) {
    const float* wrow = W2 + (tt * 16 + r16) * 64;
#pragma unroll
    for (int kc = 0; kc < 2; kc++) {
      float4 lo = *reinterpret_cast<const float4*>(wrow + kc * 32 + 4 * g4);
      float4 hi = *reinterpret_cast<const float4*>(wrow + kc * 32 + 16 + 4 * g4);
      union { unsigned short u[8]; bfrag_t v; } pk;
      pk.u[0] = f2bf(lo.x); pk.u[1] = f2bf(lo.y); pk.u[2] = f2bf(lo.z); pk.u[3] = f2bf(lo.w);
      pk.u[4] = f2bf(hi.x); pk.u[5] = f2bf(hi.y); pk.u[6] = f2bf(hi.z); pk.u[7] = f2bf(hi.w);
      bfr[tt * 2 + kc] = pk.v;
    }
  }
  float4 bias[2][2];
#pragma unroll
  for (int kc = 0; kc < 2; kc++)
#pragma unroll
    for (int h = 0; h < 2; h++)
      bias[kc][h] = *reinterpret_cast<const float4*>(b1 + kc * 32 + h * 16 + 4 * g4);
  float aSr0 = attS2[r16], aSr1 = attS2[16 + r16], aSr2 = attS2[32 + r16], aSr3 = attS2[48 + r16];
  float aDr0 = attD2[r16], aDr1 = attD2[16 + r16], aDr2 = attD2[32 + r16], aDr3 = attD2[48 + r16];

  int wid = (blockIdx.x * blockDim.x + t) >> 6;
  int nw = (gridDim.x * blockDim.x) >> 6;
  int ntiles = nNodes >> 4;
  for (int tile = wid; tile < ntiles; tile += nw) {
    int n0 = tile << 4;
    const unsigned short* arow = out1b + (size_t)(n0 + r16) * 64;
    facc_t acc0 = 0, acc1 = 0, acc2 = 0, acc3 = 0;
#pragma unroll
    for (int kc = 0; kc < 2; kc++) {
      union { unsigned short u[8]; bfrag_t v; } apk;
#pragma unroll
      for (int h = 0; h < 2; h++) {
        uint2 raw = *reinterpret_cast<const uint2*>(arow + kc * 32 + h * 16 + 4 * g4);
        float4 bb = bias[kc][h];
        float f0 = bf_lo(raw.x) + bb.x, f1 = bf_hi(raw.x) + bb.y;
        float f2 = bf_lo(raw.y) + bb.z, f3 = bf_hi(raw.y) + bb.w;
        f0 = f0 > 0.f ? f0 : (fexp(f0) - 1.f);
        f1 = f1 > 0.f ? f1 : (fexp(f1) - 1.f);
        f2 = f2 > 0.f ? f2 : (fexp(f2) - 1.f);
        f3 = f3 > 0.f ? f3 : (fexp(f3) - 1.f);
        apk.u[h * 4 + 0] = f2bf(f0); apk.u[h * 4 + 1] = f2bf(f1);
        apk.u[h * 4 + 2] = f2bf(f2); apk.u[h * 4 + 3] = f2bf(f3);
      }
      bfrag_t afr = apk.v;
      acc0 = __builtin_amdgcn_mfma_f32_16x16x32_bf16(afr, bfr[0 * 2 + kc], acc0, 0, 0, 0);
      acc1 = __builtin_amdgcn_mfma_f32_16x16x32_bf16(afr, bfr[1 * 2 + kc], acc1, 0, 0, 0);
      acc2 = __builtin_amdgcn_mfma_f32_16x16x32_bf16(afr, bfr[2 * 2 + kc], acc2, 0, 0, 0);
      acc3 = __builtin_amdgcn_mfma_f32_16x16x32_bf16(afr, bfr[3 * 2 + kc], acc3, 0, 0, 0);
    }
    float ps0 = acc0[0] * aSr0 + acc1[0] * aSr1 + acc2[0] * aSr2 + acc3[0] * aSr3;
    float ps1 = acc0[1] * aSr0 + acc1[1] * aSr1 + acc2[1] * aSr2 + acc3[1] * aSr3;
    float ps2 = acc0[2] * aSr0 + acc1[2] * aSr1 + acc2[2] * aSr2 + acc3[2] * aSr3;
    float ps3 = acc0[3] * aSr0 + acc1[3] * aSr1 + acc2[3] * aSr2 + acc3[3] * aSr3;
    float pd0 = acc0[0] * aDr0 + acc1[0] * aDr1 + acc2[0] * aDr2 + acc3[0] * aDr3;
    float pd1 = acc0[1] * aDr0 + acc1[1] * aDr1 + acc2[1] * aDr2 + acc3[1] * aDr3;
    float pd2 = acc0[2] * aDr0 + acc1[2] * aDr1 + acc2[2] * aDr2 + acc3[2] * aDr3;
    float pd3 = acc0[3] * aDr0 + acc1[3] * aDr1 + acc2[3] * aDr2 + acc3[3] * aDr3;
#pragma unroll
    for (int off = 1; off < 16; off <<= 1) {
      ps0 += __shfl_xor(ps0, off, 64); ps1 += __shfl_xor(ps1, off, 64);
      ps2 += __shfl_xor(ps2, off, 64); ps3 += __shfl_xor(ps3, off, 64);
      pd0 += __shfl_xor(pd0, off, 64); pd1 += __shfl_xor(pd1, off, 64);
      pd2 += __shfl_xor(pd2, off, 64); pd3 += __shfl_xor(pd3, off, 64);
    }
    if (r16 == 0) {
      *reinterpret_cast<float4*>(as2 + n0 + g4 * 4) = make_float4(ps0, ps1, ps2, ps3);
      *reinterpret_cast<float4*>(ad2 + n0 + g4 * 4) = make_float4(pd0, pd1, pd2, pd3);
    }
#pragma unroll
    for (int r = 0; r < 4; r++) {
      lg[w][g4 * 4 + r][0 * 16 + r16] = f2bf(acc0[r]);
      lg[w][g4 * 4 + r][1 * 16 + r16] = f2bf(acc1[r]);
      lg[w][g4 * 4 + r][2 * 16 + r16] = f2bf(acc2[r]);
      lg[w][g4 * 4 + r][3 * 16 + r16] = f2bf(acc3[r]);
    }
    asm volatile("s_waitcnt lgkmcnt(0)" ::: "memory");
    int row = l >> 3, c = l & 7;
    uint4 v0 = *reinterpret_cast<const uint4*>(&lg[w][row][c * 8]);
    uint4 v1 = *reinterpret_cast<const uint4*>(&lg[w][8 + row][c * 8]);
    *reinterpret_cast<uint4*>(gb + (size_t)(n0 + row) * 64 + c * 8) = v0;
    *reinterpret_cast<uint4*>(gb + (size_t)(n0 + 8 + row) * 64 + c * 8) = v1;
  }
}

// ---- GAT layer 2 aggregation + frame mean: GROUP(8 lanes)-PER-NODE ----
__global__ void __launch_bounds__(256)
k_agg2mean(const int* __restrict__ rowptr, const int* __restrict__ csr,
           const unsigned short* __restrict__ gtab, const float* __restrict__ as2,
           const float* __restrict__ ad2, float* __restrict__ emb) {
  __shared__ float part[32][64];
  int t = threadIdx.x;
  int w = t >> 6, l = t & 63;
  int grp = l >> 3, q = l & 7;
  int f = blockIdx.x / BPF;
  int gf = (blockIdx.x - f * BPF) * 32 + w * 8 + grp;   // group id within frame
  const int stride = BPF * 32;
  float m0 = 0.f, m1 = 0.f, m2 = 0.f, m3 = 0.f, m4 = 0.f, m5 = 0.f, m6 = 0.f, m7 = 0.f;
  for (int j = gf; j < NN_F; j += stride) {
    int n = f * NN_F + j;
    float adv = ad2[n];
    float e0 = fexp(lrelu02(as2[n] + adv));
    uint4 pv = *reinterpret_cast<const uint4*>(gtab + (size_t)n * 64 + q * 8);
    float a0 = e0 * bf_lo(pv.x), a1 = e0 * bf_hi(pv.x);
    float a2 = e0 * bf_lo(pv.y), a3 = e0 * bf_hi(pv.y);
    float a4 = e0 * bf_lo(pv.z), a5 = e0 * bf_hi(pv.z);
    float a6 = e0 * bf_lo(pv.w), a7 = e0 * bf_hi(pv.w);
    float den = e0;
    int s0 = rowptr[n], s1 = rowptr[n + 1];
    int i = s0;
    for (; i + 4 <= s1; i += 4) {   // 4-way unroll
      int sa = csr[i], sb = csr[i + 1], sc = csr[i + 2], sd = csr[i + 3];
      float ea = fexp(lrelu02(as2[sa] + adv));
      float eb = fexp(lrelu02(as2[sb] + adv));
      float ec = fexp(lrelu02(as2[sc] + adv));
      float ed = fexp(lrelu02(as2[sd] + adv));
      uint4 va = *reinterpret_cast<const uint4*>(gtab + (size_t)sa * 64 + q * 8);
      uint4 vb = *reinterpret_cast<const uint4*>(gtab + (size_t)sb * 64 + q * 8);
      uint4 vc = *reinterpret_cast<const uint4*>(gtab + (size_t)sc * 64 + q * 8);
      uint4 vd = *reinterpret_cast<const uint4*>(gtab + (size_t)sd * 64 + q * 8);
      a0 = fmaf(ea, bf_lo(va.x), a0); a1 = fmaf(ea, bf_hi(va.x), a1);
      a2 = fmaf(ea, bf_lo(va.y), a2); a3 = fmaf(ea, bf_hi(va.y), a3);
      a4 = fmaf(ea, bf_lo(va.z), a4); a5 = fmaf(ea, bf_hi(va.z), a5);
      a6 = fmaf(ea, bf_lo(va.w), a6); a7 = fmaf(ea, bf_hi(va.w), a7);
      a0 = fmaf(eb, bf_lo(vb.x), a0); a1 = fmaf(eb, bf_hi(vb.x), a1);
      a2 = fmaf(eb, bf_lo(vb.y), a2); a3 = fmaf(eb, bf_hi(vb.y), a3);
      a4 = fmaf(eb, bf_lo(vb.z), a4); a5 = fmaf(eb, bf_hi(vb.z), a5);
      a6 = fmaf(eb, bf_lo(vb.w), a6); a7 = fmaf(eb, bf_hi(vb.w), a7);
      a0 = fmaf(ec, bf_lo(vc.x), a0); a1 = fmaf(ec, bf_hi(vc.x), a1);
      a2 = fmaf(ec, bf_lo(vc.y), a2); a3 = fmaf(ec, bf_hi(vc.y), a3);
      a4 = fmaf(ec, bf_lo(vc.z), a4); a5 = fmaf(ec, bf_hi(vc.z), a5);
      a6 = fmaf(ec, bf_lo(vc.w), a6); a7 = fmaf(ec, bf_hi(vc.w), a7);
      a0 = fmaf(ed, bf_lo(vd.x), a0); a1 = fmaf(ed, bf_hi(vd.x), a1);
      a2 = fmaf(ed, bf_lo(vd.y), a2); a3 = fmaf(ed, bf_hi(vd.y), a3);
      a4 = fmaf(ed, bf_lo(vd.z), a4); a5 = fmaf(ed, bf_hi(vd.z), a5);
      a6 = fmaf(ed, bf_lo(vd.w), a6); a7 = fmaf(ed, bf_hi(vd.w), a7);
      den += (ea + eb) + (ec + ed);
    }
    for (; i < s1; i++) {
      int src = csr[i];
      EDGE_ACC(gtab, src, as2, src)
    }
    float inv = 1.f / den;
    m0 = fmaf(a0, inv, m0); m1 = fmaf(a1, inv, m1);
    m2 = fmaf(a2, inv, m2); m3 = fmaf(a3, inv, m3);
    m4 = fmaf(a4, inv, m4); m5 = fmaf(a5, inv, m5);
    m6 = fmaf(a6, inv, m6); m7 = fmaf(a7, inv, m7);
  }
  float4* pr = reinterpret_cast<float4*>(&part[w * 8 + grp][q * 8]);
  pr[0] = make_float4(m0, m1, m2, m3);
  pr[1] = make_float4(m4, m5, m6, m7);
  __syncthreads();
  if (t < 64) {
    float s = 0.f;
#pragma unroll
    for (int r = 0; r < 32; r++) s += part[r][t];
    atomicAdd(&emb[f * 64 + t], s * (1.0f / NN_F));
  }
}

// ---------------- tiny transformer: 1024 threads, 16-lane-group shuffle GEMVs ----------
__device__ __forceinline__ float grp16_reduce(float p) {
#pragma unroll
  for (int off = 1; off < 16; off <<= 1) p += __shfl_xor(p, off, 64);
  return p;
}

__global__ void __launch_bounds__(1024)
k_transformer(const float* __restrict__ emb, const float* __restrict__ b2,
              const float* __restrict__ Wqkv, const float* __restrict__ bqkv,
              const float* __restrict__ Wo, const float* __restrict__ bo,
              const float* __restrict__ ln1w, const float* __restrict__ ln1b,
              const float* __restrict__ Wff1, const float* __restrict__ bff1,
              const float* __restrict__ Wff2, const float* __restrict__ bff2,
              const float* __restrict__ ln2w, const float* __restrict__ ln2b,
              const float* __restrict__ Wh1, const float* __restrict__ bh1,
              const float* __restrict__ Wh2, const float* __restrict__ bh2,
              float* __restrict__ out) {
  __shared__ float seq[5][64];
  __shared__ float qkv[5][192];
  __shared__ float att[4][5][5];
  __shared__ float aob[5][64];
  __shared__ float ffb[5][128];
  __shared__ float tmp[5][64];
  __shared__ float hid[32];
  int t = threadIdx.x;
  int l = t & 63, w = t >> 6;        // 16 waves
  int g = l >> 4, q = l & 15;        // 4 groups of 16 lanes

  if (t < 320) seq[t >> 6][t & 63] = emb[t] + b2[t & 63];
  __syncthreads();

  for (int ly = 0; ly < 3; ly++) {
    const float* Wq  = Wqkv + ly * 12288; const float* bq  = bqkv + ly * 192;
    const float* Wol = Wo   + ly * 4096;  const float* bol = bo   + ly * 64;
    const float* w1  = ln1w + ly * 64;    const float* bb1 = ln1b + ly * 64;
    const float* Wf1 = Wff1 + ly * 8192;  const float* bf1 = bff1 + ly * 128;
    const float* Wf2 = Wff2 + ly * 8192;  const float* bf2 = bff2 + ly * 64;
    const float* w2  = ln2w + ly * 64;    const float* bb2 = ln2b + ly * 64;

    for (int o = w * 4 + g; o < 960; o += 64) {
      int s = o / 192, j = o - s * 192;
      float4 wv = *reinterpret_cast<const float4*>(&Wq[j * 64 + q * 4]);
      float4 xv = *reinterpret_cast<const float4*>(&seq[s][q * 4]);
      float p = wv.x * xv.x + wv.y * xv.y + wv.z * xv.z + wv.w * xv.w;
      p = grp16_reduce(p);
      if (q == 0) qkv[s][j] = p + bq[j];
    }
    __syncthreads();

    if (t < 100) {
      int hh = t / 25, qs = (t / 5) % 5, ks = t % 5;
      float acc = 0.f;
      for (int d = 0; d < 16; d++)
        acc = fmaf(qkv[qs][hh * 16 + d], qkv[ks][64 + hh * 16 + d], acc);
      att[hh][qs][ks] = acc * 0.25f;
    }
    __syncthreads();
    if (t < 20) {
      int hh = t / 5, qs = t % 5;
      float m = att[hh][qs][0];
      for (int k2 = 1; k2 < 5; k2++) m = fmaxf(m, att[hh][qs][k2]);
      float ss = 0.f;
      for (int k2 = 0; k2 < 5; k2++) { float v = expf(att[hh][qs][k2] - m); att[hh][qs][k2] = v; ss += v; }
      float inv = 1.f / ss;
      for (int k2 = 0; k2 < 5; k2++) att[hh][qs][k2] *= inv;
    }
    __syncthreads();

    if (t < 320) {
      int s = t >> 6, j = t & 63, hh = j >> 4;
      float acc = 0.f;
      for (int k2 = 0; k2 < 5; k2++) acc = fmaf(att[hh][s][k2], qkv[k2][128 + j], acc);
      aob[s][j] = acc;
    }
    __syncthreads();

    for (int o = w * 4 + g; o < 320; o += 64) {
      int s = o >> 6, c = o & 63;
      float4 wv = *reinterpret_cast<const float4*>(&Wol[c * 64 + q * 4]);
      float4 xv = *reinterpret_cast<const float4*>(&aob[s][q * 4]);
      float p = wv.x * xv.x + wv.y * xv.y + wv.z * xv.z + wv.w * xv.w;
      p = grp16_reduce(p);
      if (q == 0) tmp[s][c] = seq[s][c] + p + bol[c];
    }
    __syncthreads();

    if (w < 5) {
      float v = tmp[w][l];
      float s1 = v, s2 = v * v;
#pragma unroll
      for (int off = 1; off < 64; off <<= 1) {
        s1 += __shfl_xor(s1, off, 64);
        s2 += __shfl_xor(s2, off, 64);
      }
      float m = s1 * (1.f / 64.f);
      float var = s2 * (1.f / 64.f) - m * m;
      float inv = 1.f / sqrtf(var + 1e-5f);
      seq[w][l] = (v - m) * inv * w1[l] + bb1[l];
    }
    __syncthreads();

    for (int o = w * 4 + g; o < 640; o += 64) {
      int s = o >> 7, j = o & 127;
      float4 wv = *reinterpret_cast<const float4*>(&Wf1[j * 64 + q * 4]);
      float4 xv = *reinterpret_cast<const float4*>(&seq[s][q * 4]);
      float p = wv.x * xv.x + wv.y * xv.y + wv.z * xv.z + wv.w * xv.w;
      p = grp16_reduce(p);
      if (q == 0) ffb[s][j] = fmaxf(p + bf1[j], 0.f);
    }
    __syncthreads();

    for (int o = w * 4 + g; o < 320; o += 64) {
      int s = o >> 6, c = o & 63;
      float4 wa = *reinterpret_cast<const float4*>(&Wf2[c * 128 + q * 8]);
      float4 wb = *reinterpret_cast<const float4*>(&Wf2[c * 128 + q * 8 + 4]);
      float4 xa = *reinterpret_cast<const float4*>(&ffb[s][q * 8]);
      float4 xb = *reinterpret_cast<const float4*>(&ffb[s][q * 8 + 4]);
      float p = wa.x * xa.x + wa.y * xa.y + wa.z * xa.z + wa.w * xa.w
              + wb.x * xb.x + wb.y * xb.y + wb.z * xb.z + wb.w * xb.w;
      p = grp16_reduce(p);
      if (q == 0) tmp[s][c] = seq[s][c] + p + bf2[c];
    }
    __syncthreads();

    if (w < 5) {
      float v = tmp[w][l];
      float s1 = v, s2 = v * v;
#pragma unroll
      for (int off = 1; off < 64; off <<= 1) {
        s1 += __shfl_xor(s1, off, 64);
        s2 += __shfl_xor(s2, off, 64);
      }
      float m = s1 * (1.f / 64.f);
      float var = s2 * (1.f / 64.f) - m * m;
      float inv = 1.f / sqrtf(var + 1e-5f);
      seq[w][l] = (v - m) * inv * w2[l] + bb2[l];
    }
    __syncthreads();
  }

  for (int o = w * 4 + g; o < 32; o += 64) {
    float4 wv = *reinterpret_cast<const float4*>(&Wh1[o * 64 + q * 4]);
    float4 xv = *reinterpret_cast<const float4*>(&seq[4][q * 4]);
    float p = wv.x * xv.x + wv.y * xv.y + wv.z * xv.z + wv.w * xv.w;
    p = grp16_reduce(p);
    if (q == 0) hid[o] = fmaxf(p + bh1[o], 0.f);
  }
  __syncthreads();
  if (t < 2) {
    float acc = bh2[t];
    for (int j = 0; j < 32; j++) acc = fmaf(hid[j], Wh2[t * 32 + j], acc);
    out[t] = acc;
  }
}

extern "C" void kernel_launch(void* const* d_in, const int* in_sizes, int n_in,
                              void* d_out, int out_size, void* d_ws, size_t ws_size,
                              hipStream_t stream) {
  const float* x     = (const float*)d_in[0];
  const int*   ei    = (const int*)d_in[1];
  const float* W1    = (const float*)d_in[2];
  const float* attS1 = (const float*)d_in[3];
  const float* attD1 = (const float*)d_in[4];
  const float* b1    = (const float*)d_in[5];
  const float* W2    = (const float*)d_in[6];
  const float* attS2 = (const float*)d_in[7];
  const float* attD2 = (const float*)d_in[8];
  const float* b2    = (const float*)d_in[9];
  const float* tWqkv = (const float*)d_in[10];
  const float* tbqkv = (const float*)d_in[11];
  const float* tWo   = (const float*)d_in[12];
  const float* tbo   = (const float*)d_in[13];
  const float* tln1w = (const float*)d_in[14];
  const float* tln1b = (const float*)d_in[15];
  const float* tWff1 = (const float*)d_in[16];
  const float* tbff1 = (const float*)d_in[17];
  const float* tWff2 = (const float*)d_in[18];
  const float* tbff2 = (const float*)d_in[19];
  const float* tln2w = (const float*)d_in[20];
  const float* tln2b = (const float*)d_in[21];
  const float* Wh1   = (const float*)d_in[22];
  const float* bh1   = (const float*)d_in[23];
  const float* Wh2   = (const float*)d_in[24];
  const float* bh2   = (const float*)d_in[25];
  float* out = (float*)d_out;

  auto need_bytes = [](int F) -> size_t {
    size_t NT = (size_t)F * NN_F, ET = (size_t)F * NE_F;
    return (NT * 18 + 320) * 4 + (NT * 192 + ET) * 2 + (NT * 2 + 1 + 2048 + ET) * 4;
  };
  const int F = (ws_size >= need_bytes(5)) ? 5 : 1;
  const int NT = F * NN_F, ET = F * NE_F;

  float* ws  = (float*)d_ws;
  float* as1 = ws;                          // NT*8
  float* ad1 = as1 + (size_t)NT * 8;        // NT*8
  float* as2 = ad1 + (size_t)NT * 8;        // NT
  float* ad2 = as2 + NT;                    // NT
  float* emb = ad2 + NT;                    // 320
  unsigned short* h1b   = (unsigned short*)(emb + 320);   // NT*64 bf16
  unsigned short* gb    = h1b + (size_t)NT * 64;          // NT*64 bf16
  unsigned short* out1b = gb + (size_t)NT * 64;           // NT*64 bf16
  int* deg    = (int*)(out1b + (size_t)NT * 64);          // NT
  int* rowptr = deg + NT;                   // NT+1
  int* bsum   = rowptr + NT + 1;            // <=1024
  int* boff   = bsum + 1024;                // <=1024
  unsigned short* rank = (unsigned short*)(boff + 1024);  // ET (ushort)
  int* csr    = (int*)(rank + ET);          // ET

  (void)hipMemsetAsync(emb, 0, 320 * sizeof(float), stream);

  const int nblk = (NT + 255) / 256;
  const int edge4Blocks = ((ET >> 2) + 255) / 256;
  const int agg1Blocks = (NT / 8 + 3) / 4;  // group(8 lanes) per node, 32 groups/block
  const int node1Blocks = 2048;
  const int node2Blocks = 1024;             // wave = 16-node MFMA tile

  for (int f0 = 0; f0 < 5; f0 += F) {
    const float* xf = x + (size_t)f0 * NN_F * 13;
    const int* eif  = ei + (size_t)f0 * 2 * NE_F;

    (void)hipMemsetAsync(deg, 0, NT * sizeof(int), stream);
    // fused: CSR rank pass (atomic-bound) runs concurrently with node1 (VALU-bound)
    k_rank_node1<<<edge4Blocks + node1Blocks, 256, 0, stream>>>(
        eif, deg, rank, F, edge4Blocks,
        xf, W1, attS1, attD1, h1b, as1, ad1, NT, node1Blocks);
    k_scan1<<<nblk, 256, 0, stream>>>(deg, bsum, NT);
    k_scan2<<<1, 1024, 0, stream>>>(bsum, boff, nblk);
    k_scan3<<<nblk, 256, 0, stream>>>(deg, boff, rowptr, NT, ET);
    k_place<<<edge4Blocks, 256, 0, stream>>>(eif, rowptr, rank, csr, F);

    k_agg1<<<agg1Blocks, 256, 0, stream>>>(rowptr, csr, h1b, as1, ad1, out1b, NT);
    k_node2<<<node2Blocks, 256, 0, stream>>>(out1b, b1, W2, attS2, attD2, gb, as2, ad2, NT);
    k_agg2mean<<<F * BPF, 256, 0, stream>>>(rowptr, csr, gb, as2, ad2, emb + f0 * 64);
  }

  k_transformer<<<1, 1024, 0, stream>>>(emb, b2, tWqkv, tbqkv, tWo, tbo, tln1w, tln1b,
                                        tWff1, tbff1, tWff2, tbff2, tln2w, tln2b,
                                        Wh1, bh1, Wh2, bh2, out);
}